// Round 1
// baseline (404.147 us; speedup 1.0000x reference)
//
#include <hip/hip_runtime.h>

typedef __attribute__((ext_vector_type(8))) short short8;
typedef __attribute__((ext_vector_type(4))) float f32x4;
typedef __attribute__((ext_vector_type(4))) unsigned int uint4v;

#define HW 32
#define L 1024        // HW*HW
#define C_IN 256
#define KP 2304       // C_IN*9
#define BATCH 8

static __device__ __forceinline__ unsigned short f2bf(float f){
  unsigned int u = __float_as_uint(f);
  unsigned int r = (u + 0x7FFFu + ((u >> 16) & 1u)) >> 16;   // RNE (no NaN inputs)
  return (unsigned short)r;
}
static __device__ __forceinline__ float bf2f(unsigned short h){
  return __uint_as_float(((unsigned int)h) << 16);
}

// ---------------- P0: per-patch 1/||.|| (includes the +1e-7 on every element) ----
__global__ __launch_bounds__(256) void norm_kernel(const float* __restrict__ bgd,
                                                   const float* __restrict__ mask,
                                                   float* __restrict__ rnorm){
  int gid = blockIdx.x * 4 + (threadIdx.x >> 6);   // b*1024 + l
  int lane = threadIdx.x & 63;
  int b = gid >> 10, l = gid & 1023;
  int h = l >> 5, w = l & 31;
  const float* bg = bgd + (size_t)b * (C_IN * L);
  float acc = 0.f;
  for (int idx = lane; idx < KP; idx += 64){
    int c = idx / 9, s = idx - c * 9;
    int dy = s / 3, dx = s - dy * 3;
    int y = h + dy - 1, x = w + dx - 1;
    float v = 0.f;
    if ((unsigned)y < HW && (unsigned)x < HW)
      v = bg[c * L + y * HW + x] * (1.f - mask[y * HW + x]);
    float e = v + 1e-7f;
    acc += e * e;
  }
  #pragma unroll
  for (int off = 32; off; off >>= 1) acc += __shfl_xor(acc, off);
  if (lane == 0) rnorm[gid] = 1.f / sqrtf(acc);
}

// ---------------- P1: Kn[b][l][k] bf16 (normalized bg patches, k-contig) --------
__global__ __launch_bounds__(256) void write_kn(const float* __restrict__ bgd,
                                                const float* __restrict__ mask,
                                                const float* __restrict__ rnorm,
                                                unsigned short* __restrict__ Kn){
  int gid = blockIdx.x;            // b*1024 + l
  int b = gid >> 10, l = gid & 1023;
  int h = l >> 5, w = l & 31;
  const float* bg = bgd + (size_t)b * (C_IN * L);
  float rn = rnorm[gid];
  unsigned short* out = Kn + (size_t)gid * KP;
  for (int k = threadIdx.x; k < KP; k += 256){
    int c = k / 9, s = k - c * 9;
    int dy = s / 3, dx = s - dy * 3;
    int y = h + dy - 1, x = w + dx - 1;
    float v = 0.f;
    if ((unsigned)y < HW && (unsigned)x < HW)
      v = bg[c * L + y * HW + x] * (1.f - mask[y * HW + x]);
    out[k] = f2bf((v + 1e-7f) * rn);
  }
}

// ---------------- P2: Knt[b][q][l] bf16 (transposed kernels, l-contig) ----------
__global__ __launch_bounds__(256) void write_knt(const float* __restrict__ bgd,
                                                 const float* __restrict__ mask,
                                                 const float* __restrict__ rnorm,
                                                 unsigned short* __restrict__ Knt){
  int gid = blockIdx.x;            // b*2304 + q
  int b = gid / KP, q = gid - b * KP;
  int c = q / 9, s = q - c * 9;
  int dy = s / 3 - 1, dx = s - (s / 3) * 3 - 1;
  const float* bg = bgd + (size_t)b * (C_IN * L) + c * L;
  const float* rn = rnorm + b * L;
  unsigned short* out = Knt + (size_t)gid * L;
  for (int l = threadIdx.x; l < L; l += 256){
    int h = l >> 5, w = l & 31;
    int y = h + dy, x = w + dx;
    float v = 0.f;
    if ((unsigned)y < HW && (unsigned)x < HW)
      v = bg[y * HW + x] * (1.f - mask[y * HW + x]);
    out[l] = f2bf((v + 1e-7f) * rn[l]);
  }
}

// ---------------- P3: FgP[b][p][k] bf16 (foreground patches, raw) ---------------
__global__ __launch_bounds__(256) void write_fgp(const float* __restrict__ fg,
                                                 unsigned short* __restrict__ FgP){
  int gid = blockIdx.x;            // b*1024 + p
  int b = gid >> 10, p = gid & 1023;
  int h = p >> 5, w = p & 31;
  const float* f = fg + (size_t)b * (C_IN * L);
  unsigned short* out = FgP + (size_t)gid * KP;
  for (int k = threadIdx.x; k < KP; k += 256){
    int c = k / 9, s = k - c * 9;
    int dy = s / 3, dx = s - dy * 3;
    int y = h + dy - 1, x = w + dx - 1;
    float v = 0.f;
    if ((unsigned)y < HW && (unsigned)x < HW) v = f[c * L + y * HW + x];
    out[k] = f2bf(v);
  }
}

// ---------------- P4: Wr[g][s][n][c] bf16 (reordered conv weights) --------------
__global__ __launch_bounds__(256) void wr_prep(const float* __restrict__ conv_w,
                                               unsigned short* __restrict__ Wr){
  int idx = blockIdx.x * 256 + threadIdx.x;   // ((g*9+s)*64+n)*256+c ; total 589824
  int c = idx & 255;
  int rest = idx >> 8;
  int n = rest & 63;
  int sg = rest >> 6;            // g*9+s
  int s = sg % 9, g = sg / 9;
  float v = conv_w[(((size_t)(g * 64 + n)) * C_IN + c) * 9 + s];
  Wr[idx] = f2bf(v);
}

// ---------------- GEMM: C[m][n] = sum_k A[m][k]*B[n][k], bf16 in, 128x128 tile --
template<int OUT_BF16>
__global__ __launch_bounds__(256) void gemm_bt(const unsigned short* __restrict__ A,
                                               const unsigned short* __restrict__ B,
                                               void* __restrict__ Cv,
                                               int K, int N,
                                               long strideA, long strideB, long strideC)
{
  __shared__ unsigned short As[128][40];   // +8 pad: 2-way-max bank aliasing
  __shared__ unsigned short Bs[128][40];
  int bz = blockIdx.z;
  const unsigned short* Ab = A + (size_t)bz * strideA + (size_t)blockIdx.y * 128 * K;
  const unsigned short* Bb = B + (size_t)bz * strideB + (size_t)blockIdx.x * 128 * K;
  int tid = threadIdx.x, lane = tid & 63, wv = tid >> 6;
  int wm = (wv & 1) * 64, wn = (wv >> 1) * 64;
  int rsel = lane & 15, ksel = (lane >> 4) * 8;
  f32x4 acc[4][4] = {};
  int r0 = tid >> 2, kc0 = (tid & 3) * 8;    // r0 in [0,64)
  for (int kt = 0; kt < K; kt += 32){
    *(uint4v*)&As[r0     ][kc0] = *(const uint4v*)&Ab[(size_t)(r0     ) * K + kt + kc0];
    *(uint4v*)&As[r0 + 64][kc0] = *(const uint4v*)&Ab[(size_t)(r0 + 64) * K + kt + kc0];
    *(uint4v*)&Bs[r0     ][kc0] = *(const uint4v*)&Bb[(size_t)(r0     ) * K + kt + kc0];
    *(uint4v*)&Bs[r0 + 64][kc0] = *(const uint4v*)&Bb[(size_t)(r0 + 64) * K + kt + kc0];
    __syncthreads();
    short8 af[4], bf[4];
    #pragma unroll
    for (int i = 0; i < 4; i++){
      af[i] = *(const short8*)&As[wm + i * 16 + rsel][ksel];
      bf[i] = *(const short8*)&Bs[wn + i * 16 + rsel][ksel];
    }
    #pragma unroll
    for (int i = 0; i < 4; i++)
      #pragma unroll
      for (int j = 0; j < 4; j++)
        acc[i][j] = __builtin_amdgcn_mfma_f32_16x16x32_bf16(af[i], bf[j], acc[i][j], 0, 0, 0);
    __syncthreads();
  }
  int m0 = blockIdx.y * 128, n0 = blockIdx.x * 128;
  int rowb = (lane >> 4) * 4, col = lane & 15;
  if (OUT_BF16){
    unsigned short* Cb = (unsigned short*)Cv + (size_t)bz * strideC;
    #pragma unroll
    for (int i = 0; i < 4; i++)
      #pragma unroll
      for (int j = 0; j < 4; j++)
        #pragma unroll
        for (int r = 0; r < 4; r++)
          Cb[(size_t)(m0 + wm + i * 16 + rowb + r) * N + (n0 + wn + j * 16 + col)] = f2bf(acc[i][j][r]);
  } else {
    float* Cb = (float*)Cv + (size_t)bz * strideC;
    #pragma unroll
    for (int i = 0; i < 4; i++)
      #pragma unroll
      for (int j = 0; j < 4; j++)
        #pragma unroll
        for (int r = 0; r < 4; r++)
          Cb[(size_t)(m0 + wm + i * 16 + rowb + r) * N + (n0 + wn + j * 16 + col)] = acc[i][j][r];
  }
}

// ---------------- K2: 3x3 window-sum over (h,w) + softmax over l, bf16 out ------
__global__ __launch_bounds__(256) void prop_softmax(const float* __restrict__ scores,
                                                    unsigned short* __restrict__ attn){
  int bp = blockIdx.x;                 // b*1024 + p
  int b = bp >> 10, p = bp & 1023;
  int h = p >> 5, w = p & 31;
  const float* S = scores + ((size_t)b << 20);
  int tid = threadIdx.x;
  float s0 = 0, s1 = 0, s2 = 0, s3 = 0;
  for (int dy = -1; dy <= 1; dy++){
    int y = h + dy; if ((unsigned)y >= HW) continue;
    for (int dx = -1; dx <= 1; dx++){
      int x = w + dx; if ((unsigned)x >= HW) continue;
      const float4* row = (const float4*)(S + ((size_t)(y * HW + x) << 10));
      float4 v = row[tid];
      s0 += v.x; s1 += v.y; s2 += v.z; s3 += v.w;
    }
  }
  float m = fmaxf(fmaxf(s0, s1), fmaxf(s2, s3));
  #pragma unroll
  for (int off = 32; off; off >>= 1) m = fmaxf(m, __shfl_xor(m, off));
  __shared__ float redm[4], reds[4];
  if ((tid & 63) == 0) redm[tid >> 6] = m;
  __syncthreads();
  m = fmaxf(fmaxf(redm[0], redm[1]), fmaxf(redm[2], redm[3]));
  float e0 = __expf(s0 - m), e1 = __expf(s1 - m), e2 = __expf(s2 - m), e3 = __expf(s3 - m);
  float t = e0 + e1 + e2 + e3;
  #pragma unroll
  for (int off = 32; off; off >>= 1) t += __shfl_xor(t, off);
  if ((tid & 63) == 0) reds[tid >> 6] = t;
  __syncthreads();
  t = reds[0] + reds[1] + reds[2] + reds[3];
  float inv = 1.f / t;
  ushort4 o;
  o.x = f2bf(e0 * inv); o.y = f2bf(e1 * inv); o.z = f2bf(e2 * inv); o.w = f2bf(e3 * inv);
  *(ushort4*)&attn[((size_t)bp << 10) + tid * 4] = o;
}

// ---------------- K3: fold Rt -> finalT[b][p][c] bf16 ---------------------------
__global__ __launch_bounds__(256) void fold_final(const unsigned short* __restrict__ Rt,
                                                  const float* __restrict__ fg,
                                                  const float* __restrict__ mask,
                                                  unsigned short* __restrict__ finalT){
  int bp = blockIdx.x;                 // b*1024 + p
  int b = bp >> 10, p = bp & 1023;
  int h = p >> 5, w = p & 31;
  int c = threadIdx.x;
  float val;
  if (mask[p] != 0.f){
    const unsigned short* R = Rt + (size_t)b * L * KP;
    float sum = 0.f;
    #pragma unroll
    for (int u = 0; u < 3; u++){
      int y = h + 1 - u; if ((unsigned)y >= HW) continue;
      #pragma unroll
      for (int v = 0; v < 3; v++){
        int x = w + 1 - v; if ((unsigned)x >= HW) continue;
        sum += bf2f(R[(size_t)(y * HW + x) * KP + c * 9 + u * 3 + v]);
      }
    }
    val = sum / 9.0f;
  } else {
    val = fg[((size_t)b * C_IN + c) * L + p];
  }
  finalT[(size_t)bp * C_IN + c] = f2bf(val);
}

// ---------------- K4: 4 dilated conv branches as 9-shifted register GEMMs -------
__global__ __launch_bounds__(256) void branch_conv(const unsigned short* __restrict__ finalT,
                                                   const unsigned short* __restrict__ Wr,
                                                   const float* __restrict__ conv_b,
                                                   float* __restrict__ out){
  int mt = blockIdx.x;                 // 0..15 -> p0
  int bg_ = blockIdx.y;                // b*4+g
  int b = bg_ >> 2, g = bg_ & 3;
  int rate = 1 << g;
  int p0 = mt * 64;
  int tid = threadIdx.x, lane = tid & 63, wv = tid >> 6;
  int wm = (wv & 1) * 32, wn = (wv >> 1) * 32;
  int rsel = lane & 15, ksel = (lane >> 4) * 8;
  const unsigned short* FT = finalT + (size_t)b * L * C_IN;
  const unsigned short* WG = Wr + (size_t)g * 9 * 64 * C_IN;
  int hh[2], ww[2], nn[2];
  #pragma unroll
  for (int mi = 0; mi < 2; mi++){
    int p = p0 + wm + mi * 16 + rsel; hh[mi] = p >> 5; ww[mi] = p & 31;
  }
  #pragma unroll
  for (int ni = 0; ni < 2; ni++) nn[ni] = wn + ni * 16 + rsel;
  f32x4 acc[2][2] = {};
  for (int s = 0; s < 9; s++){
    int dy = s / 3 - 1, dx = s - (s / 3) * 3 - 1;
    int abase[2];
    #pragma unroll
    for (int mi = 0; mi < 2; mi++){
      int y = hh[mi] + rate * dy, x = ww[mi] + rate * dx;
      bool ok = ((unsigned)y < HW) && ((unsigned)x < HW);
      abase[mi] = ok ? ((y * HW + x) * C_IN + ksel) : -1;
    }
    int bbase[2];
    #pragma unroll
    for (int ni = 0; ni < 2; ni++) bbase[ni] = (s * 64 + nn[ni]) * C_IN + ksel;
    #pragma unroll
    for (int cc = 0; cc < 8; cc++){
      int c0 = cc * 32;
      short8 a[2], bb[2];
      short8 z = {0, 0, 0, 0, 0, 0, 0, 0};
      #pragma unroll
      for (int mi = 0; mi < 2; mi++)
        a[mi] = (abase[mi] >= 0) ? *(const short8*)&FT[abase[mi] + c0] : z;
      #pragma unroll
      for (int ni = 0; ni < 2; ni++)
        bb[ni] = *(const short8*)&WG[bbase[ni] + c0];
      #pragma unroll
      for (int mi = 0; mi < 2; mi++)
        #pragma unroll
        for (int ni = 0; ni < 2; ni++)
          acc[mi][ni] = __builtin_amdgcn_mfma_f32_16x16x32_bf16(a[mi], bb[ni], acc[mi][ni], 0, 0, 0);
    }
  }
  int rowb = (lane >> 4) * 4, col = lane & 15;
  float* O = out + (size_t)(b * 256 + g * 64) * L;
  #pragma unroll
  for (int mi = 0; mi < 2; mi++)
    #pragma unroll
    for (int ni = 0; ni < 2; ni++){
      int n = wn + ni * 16 + col;
      float bias = conv_b[g * 64 + n];
      #pragma unroll
      for (int r2 = 0; r2 < 4; r2++){
        int p = p0 + wm + mi * 16 + rowb + r2;
        O[(size_t)n * L + p] = fmaxf(acc[mi][ni][r2] + bias, 0.f);
      }
    }
}

// ---------------- workspace layout (bytes) --------------------------------------
// [0, 37748736)           : Kn   (8*1024*2304 bf16)   -> reused as Knt after GEMM1
// [37748736, 75497472)    : FgP  (8*1024*2304 bf16)   -> reused as Rt after GEMM1
// [75497472, 109051904)   : scores (8*1024*1024 f32)  -> reused as finalT after softmax
// [109051904, 125829120)  : attn (8*1024*1024 bf16)
// [125829120, 125861888)  : rnorm (8*1024 f32)
// [125861888, 127041536)  : Wr (4*9*64*256 bf16)
// total: 127,041,536 B (~121 MiB)

extern "C" void kernel_launch(void* const* d_in, const int* in_sizes, int n_in,
                              void* d_out, int out_size, void* d_ws, size_t ws_size,
                              hipStream_t stream){
  const float* fg     = (const float*)d_in[0];
  const float* mask   = (const float*)d_in[1];
  const float* bgd    = (const float*)d_in[2];
  const float* conv_w = (const float*)d_in[3];
  const float* conv_b = (const float*)d_in[4];

  char* ws = (char*)d_ws;
  unsigned short* Kn     = (unsigned short*)(ws + 0);
  unsigned short* Knt    = Kn;                                  // reuse after GEMM1
  unsigned short* FgP    = (unsigned short*)(ws + 37748736);
  unsigned short* Rt     = FgP;                                 // reuse after GEMM1
  float*          scores = (float*)(ws + 75497472);
  unsigned short* finalT = (unsigned short*)scores;             // reuse after softmax
  unsigned short* attn   = (unsigned short*)(ws + 109051904);
  float*          rnorm  = (float*)(ws + 125829120);
  unsigned short* Wr     = (unsigned short*)(ws + 125861888);
  float* out = (float*)d_out;

  norm_kernel<<<2048, 256, 0, stream>>>(bgd, mask, rnorm);
  write_kn  <<<8192, 256, 0, stream>>>(bgd, mask, rnorm, Kn);
  write_fgp <<<8192, 256, 0, stream>>>(fg, FgP);
  wr_prep   <<<2304, 256, 0, stream>>>(conv_w, Wr);

  // GEMM1: scores[p][l] = FgP[p][:] . Kn[l][:]   (M=N=1024, K=2304)
  gemm_bt<0><<<dim3(8, 8, 8), 256, 0, stream>>>(FgP, Kn, scores, 2304, 1024,
      (long)1024 * 2304, (long)1024 * 2304, (long)1024 * 1024);

  prop_softmax<<<8192, 256, 0, stream>>>(scores, attn);

  // Knt written into Kn's region (Kn dead after GEMM1)
  write_knt<<<18432, 256, 0, stream>>>(bgd, mask, rnorm, Knt);

  // GEMM2: Rt[p][q] = attn[p][:] . Knt[q][:]    (M=1024, N=2304, K=1024)
  gemm_bt<1><<<dim3(18, 8, 8), 256, 0, stream>>>(attn, Knt, Rt, 1024, 2304,
      (long)1024 * 1024, (long)2304 * 1024, (long)1024 * 2304);

  fold_final<<<8192, 256, 0, stream>>>(Rt, fg, mask, finalT);

  branch_conv<<<dim3(16, 32), 256, 0, stream>>>(finalT, Wr, conv_b, out);
}

// Round 2
// 300.741 us; speedup vs baseline: 1.3438x; 1.3438x over previous
//
#include <hip/hip_runtime.h>

typedef __attribute__((ext_vector_type(8))) short short8;
typedef __attribute__((ext_vector_type(4))) float f32x4;

#define HW 32
#define L 1024        // HW*HW
#define C_IN 256
#define KP 2304       // C_IN*9
#define BATCH 8

static __device__ __forceinline__ unsigned short f2bf(float f){
  unsigned int u = __float_as_uint(f);
  unsigned int r = (u + 0x7FFFu + ((u >> 16) & 1u)) >> 16;   // RNE (no NaN inputs)
  return (unsigned short)r;
}
static __device__ __forceinline__ float bf2f(unsigned short h){
  return __uint_as_float(((unsigned int)h) << 16);
}

#define GLDS16(g, l) __builtin_amdgcn_global_load_lds(                          \
    (const __attribute__((address_space(1))) void*)(g),                         \
    (__attribute__((address_space(3))) void*)(l), 16, 0, 0)

// ---------------- P0: channel-last transposes: fgT[b][p][c], mbgT[b][p][c] ------
__global__ __launch_bounds__(256) void transpose_pack(const float* __restrict__ fg,
                                                      const float* __restrict__ bgd,
                                                      const float* __restrict__ mask,
                                                      unsigned short* __restrict__ fgT,
                                                      unsigned short* __restrict__ mbgT){
  __shared__ float T[64][65];
  int p0 = blockIdx.x * 64, c0 = blockIdx.y * 64, b = blockIdx.z;
  int tx = threadIdx.x & 63, ty = threadIdx.x >> 6;
  const float* F = fg  + ((size_t)b * C_IN + c0) * L + p0;
  const float* G = bgd + ((size_t)b * C_IN + c0) * L + p0;
  // pass 1: fg
  for (int cc = ty; cc < 64; cc += 4) T[cc][tx] = F[(size_t)cc * L + tx];
  __syncthreads();
  for (int pp = ty; pp < 64; pp += 4)
    fgT[(size_t)(b * L + p0 + pp) * C_IN + c0 + tx] = f2bf(T[tx][pp]);
  __syncthreads();
  // pass 2: bg * (1-mask)
  float mm = 1.f - mask[p0 + tx];
  for (int cc = ty; cc < 64; cc += 4) T[cc][tx] = G[(size_t)cc * L + tx] * mm;
  __syncthreads();
  for (int pp = ty; pp < 64; pp += 4)
    mbgT[(size_t)(b * L + p0 + pp) * C_IN + c0 + tx] = f2bf(T[tx][pp]);
}

// ---------------- P1: fused norm + Kn'[b][l][s*256+c] bf16 ----------------------
__global__ __launch_bounds__(256) void kn_norm(const unsigned short* __restrict__ mbgT,
                                               unsigned short* __restrict__ Kn,
                                               float* __restrict__ rnorm){
  int bl = blockIdx.x;                 // b*1024 + l
  int b = bl >> 10, l = bl & 1023;
  int h = l >> 5, w = l & 31;
  int c = threadIdx.x;
  const unsigned short* M = mbgT + (size_t)b * L * C_IN;
  float v[9]; float acc = 0.f;
  #pragma unroll
  for (int s = 0; s < 9; s++){
    int y = h + s / 3 - 1, x = w + s % 3 - 1;
    float val = 0.f;
    if ((unsigned)y < HW && (unsigned)x < HW) val = bf2f(M[(size_t)(y * HW + x) * C_IN + c]);
    v[s] = val + 1e-7f;
    acc += v[s] * v[s];
  }
  #pragma unroll
  for (int off = 32; off; off >>= 1) acc += __shfl_xor(acc, off);
  __shared__ float red[4];
  if ((c & 63) == 0) red[c >> 6] = acc;
  __syncthreads();
  float rn = 1.f / sqrtf(red[0] + red[1] + red[2] + red[3]);
  if (c == 0) rnorm[bl] = rn;
  unsigned short* O = Kn + (size_t)bl * KP;
  #pragma unroll
  for (int s = 0; s < 9; s++) O[s * 256 + c] = f2bf(v[s] * rn);
}

// ---------------- P2: FgP'[b][p][s*256+c] bf16 (raw fg patches) -----------------
__global__ __launch_bounds__(256) void fgp_pack(const unsigned short* __restrict__ fgT,
                                                unsigned short* __restrict__ FgP){
  int bp = blockIdx.x;                 // b*1024 + p
  int b = bp >> 10, p = bp & 1023;
  int h = p >> 5, w = p & 31;
  int c = threadIdx.x;
  const unsigned short* F = fgT + (size_t)b * L * C_IN;
  unsigned short* O = FgP + (size_t)bp * KP;
  #pragma unroll
  for (int s = 0; s < 9; s++){
    int y = h + s / 3 - 1, x = w + s % 3 - 1;
    unsigned short val = 0;
    if ((unsigned)y < HW && (unsigned)x < HW) val = F[(size_t)(y * HW + x) * C_IN + c];
    O[s * 256 + c] = val;
  }
}

// ---------------- P3: Knt'[b][s*256+c][l] bf16 (transposed kernels) -------------
__global__ __launch_bounds__(256) void write_knt(const float* __restrict__ bgd,
                                                 const float* __restrict__ mask,
                                                 const float* __restrict__ rnorm,
                                                 unsigned short* __restrict__ Knt){
  int gid = blockIdx.x;                // b*2304 + q',  q' = s*256+c
  int b = gid / KP, q = gid - b * KP;
  int s = q >> 8, c = q & 255;
  int dy = s / 3 - 1, dx = s % 3 - 1;
  const float* bg = bgd + ((size_t)b * C_IN + c) * L;
  const float* rn = rnorm + b * L;
  unsigned short* out = Knt + (size_t)gid * L;
  for (int l = threadIdx.x; l < L; l += 256){
    int y = (l >> 5) + dy, x = (l & 31) + dx;
    float v = 0.f;
    if ((unsigned)y < HW && (unsigned)x < HW)
      v = bg[y * HW + x] * (1.f - mask[y * HW + x]);
    out[l] = f2bf((v + 1e-7f) * rn[l]);
  }
}

// ---------------- P4: Wr[g][s][n][c] bf16 (reordered conv weights) --------------
__global__ __launch_bounds__(256) void wr_prep(const float* __restrict__ conv_w,
                                               unsigned short* __restrict__ Wr){
  int idx = blockIdx.x * 256 + threadIdx.x;   // ((g*9+s)*64+n)*256+c
  int c = idx & 255;
  int rest = idx >> 8;
  int n = rest & 63;
  int sg = rest >> 6;
  int s = sg % 9, g = sg / 9;
  Wr[idx] = f2bf(conv_w[(((size_t)(g * 64 + n)) * C_IN + c) * 9 + s]);
}

// ---------------- GEMM (m97 structure): C[m][n] = sum_k A[m][k]*B[n][k] ---------
template<int OUT_BF16>
__global__ __launch_bounds__(256) void gemm_bt(const unsigned short* __restrict__ A,
                                               const unsigned short* __restrict__ B,
                                               void* __restrict__ Cv,
                                               int K, int N,
                                               long strideA, long strideB, long strideC)
{
  __shared__ unsigned short As[128][32];   // linear: required by global_load_lds
  __shared__ unsigned short Bs[128][32];
  int bz = blockIdx.z;
  const unsigned short* Ab = A + (size_t)bz * strideA + (size_t)blockIdx.y * 128 * K;
  const unsigned short* Bb = B + (size_t)bz * strideB + (size_t)blockIdx.x * 128 * K;
  int tid = threadIdx.x, lane = tid & 63, wv = tid >> 6;
  int wm = (wv & 1) * 64, wn = (wv >> 1) * 64;
  int rsel = lane & 15, ksel = (lane >> 4) * 8;
  int lrow = lane >> 2, lcol = (lane & 3) * 8;   // wave-load: 16 rows x 32 k
  const unsigned short* Ag = Ab + (size_t)(wv * 32 + lrow) * K + lcol;
  const unsigned short* Bg = Bb + (size_t)(wv * 32 + lrow) * K + lcol;
  unsigned short* As0 = &As[wv * 32][0];
  unsigned short* As1 = &As[wv * 32 + 16][0];
  unsigned short* Bs0 = &Bs[wv * 32][0];
  unsigned short* Bs1 = &Bs[wv * 32 + 16][0];
  f32x4 acc[4][4] = {};
  for (int kt = 0; kt < K; kt += 32){
    GLDS16(Ag + kt,                 As0);
    GLDS16(Ag + kt + (size_t)16 * K, As1);
    GLDS16(Bg + kt,                 Bs0);
    GLDS16(Bg + kt + (size_t)16 * K, Bs1);
    __syncthreads();
    short8 af[4], bf[4];
    #pragma unroll
    for (int i = 0; i < 4; i++){
      af[i] = *(const short8*)&As[wm + i * 16 + rsel][ksel];
      bf[i] = *(const short8*)&Bs[wn + i * 16 + rsel][ksel];
    }
    #pragma unroll
    for (int i = 0; i < 4; i++)
      #pragma unroll
      for (int j = 0; j < 4; j++)
        acc[i][j] = __builtin_amdgcn_mfma_f32_16x16x32_bf16(af[i], bf[j], acc[i][j], 0, 0, 0);
    __syncthreads();
  }
  int m0 = blockIdx.y * 128, n0 = blockIdx.x * 128;
  int rowb = (lane >> 4) * 4, col = lane & 15;
  if (OUT_BF16){
    unsigned short* Cb = (unsigned short*)Cv + (size_t)bz * strideC;
    #pragma unroll
    for (int i = 0; i < 4; i++)
      #pragma unroll
      for (int j = 0; j < 4; j++)
        #pragma unroll
        for (int r = 0; r < 4; r++)
          Cb[(size_t)(m0 + wm + i * 16 + rowb + r) * N + (n0 + wn + j * 16 + col)] = f2bf(acc[i][j][r]);
  } else {
    float* Cb = (float*)Cv + (size_t)bz * strideC;
    #pragma unroll
    for (int i = 0; i < 4; i++)
      #pragma unroll
      for (int j = 0; j < 4; j++)
        #pragma unroll
        for (int r = 0; r < 4; r++)
          Cb[(size_t)(m0 + wm + i * 16 + rowb + r) * N + (n0 + wn + j * 16 + col)] = acc[i][j][r];
  }
}

// ---------------- K2: 3x3 window-sum over (h,w) + softmax over l, bf16 out ------
__global__ __launch_bounds__(256) void prop_softmax(const float* __restrict__ scores,
                                                    unsigned short* __restrict__ attn){
  int bp = blockIdx.x;                 // b*1024 + p
  int b = bp >> 10, p = bp & 1023;
  int h = p >> 5, w = p & 31;
  const float* S = scores + ((size_t)b << 20);
  int tid = threadIdx.x;
  float s0 = 0, s1 = 0, s2 = 0, s3 = 0;
  for (int dy = -1; dy <= 1; dy++){
    int y = h + dy; if ((unsigned)y >= HW) continue;
    for (int dx = -1; dx <= 1; dx++){
      int x = w + dx; if ((unsigned)x >= HW) continue;
      const float4* row = (const float4*)(S + ((size_t)(y * HW + x) << 10));
      float4 v = row[tid];
      s0 += v.x; s1 += v.y; s2 += v.z; s3 += v.w;
    }
  }
  float m = fmaxf(fmaxf(s0, s1), fmaxf(s2, s3));
  #pragma unroll
  for (int off = 32; off; off >>= 1) m = fmaxf(m, __shfl_xor(m, off));
  __shared__ float redm[4], reds[4];
  if ((tid & 63) == 0) redm[tid >> 6] = m;
  __syncthreads();
  m = fmaxf(fmaxf(redm[0], redm[1]), fmaxf(redm[2], redm[3]));
  float e0 = __expf(s0 - m), e1 = __expf(s1 - m), e2 = __expf(s2 - m), e3 = __expf(s3 - m);
  float t = e0 + e1 + e2 + e3;
  #pragma unroll
  for (int off = 32; off; off >>= 1) t += __shfl_xor(t, off);
  if ((tid & 63) == 0) reds[tid >> 6] = t;
  __syncthreads();
  t = reds[0] + reds[1] + reds[2] + reds[3];
  float inv = 1.f / t;
  ushort4 o;
  o.x = f2bf(e0 * inv); o.y = f2bf(e1 * inv); o.z = f2bf(e2 * inv); o.w = f2bf(e3 * inv);
  *(ushort4*)&attn[((size_t)bp << 10) + tid * 4] = o;
}

// ---------------- K3: fold Rt[p][s*256+c] -> finalT[b][p][c] bf16 ---------------
__global__ __launch_bounds__(256) void fold_final(const unsigned short* __restrict__ Rt,
                                                  const unsigned short* __restrict__ fgT,
                                                  const float* __restrict__ mask,
                                                  unsigned short* __restrict__ finalT){
  int bp = blockIdx.x;                 // b*1024 + p
  int b = bp >> 10, p = bp & 1023;
  int h = p >> 5, w = p & 31;
  int c = threadIdx.x;
  float val;
  if (mask[p] != 0.f){
    const unsigned short* R = Rt + (size_t)b * L * KP;
    float sum = 0.f;
    #pragma unroll
    for (int u = 0; u < 3; u++){
      int y = h + 1 - u; if ((unsigned)y >= HW) continue;
      #pragma unroll
      for (int v = 0; v < 3; v++){
        int x = w + 1 - v; if ((unsigned)x >= HW) continue;
        sum += bf2f(R[(size_t)(y * HW + x) * KP + (u * 3 + v) * 256 + c]);
      }
    }
    val = sum / 9.0f;
  } else {
    val = bf2f(fgT[(size_t)bp * C_IN + c]);
  }
  finalT[(size_t)bp * C_IN + c] = f2bf(val);
}

// ---------------- K4: 4 dilated conv branches as 9-shifted register GEMMs -------
__global__ __launch_bounds__(256) void branch_conv(const unsigned short* __restrict__ finalT,
                                                   const unsigned short* __restrict__ Wr,
                                                   const float* __restrict__ conv_b,
                                                   float* __restrict__ out){
  int mt = blockIdx.x;                 // 0..15 -> p0
  int bg_ = blockIdx.y;                // b*4+g
  int b = bg_ >> 2, g = bg_ & 3;
  int rate = 1 << g;
  int p0 = mt * 64;
  int tid = threadIdx.x, lane = tid & 63, wv = tid >> 6;
  int wm = (wv & 1) * 32, wn = (wv >> 1) * 32;
  int rsel = lane & 15, ksel = (lane >> 4) * 8;
  const unsigned short* FT = finalT + (size_t)b * L * C_IN;
  const unsigned short* WG = Wr + (size_t)g * 9 * 64 * C_IN;
  int hh[2], ww[2], nn[2];
  #pragma unroll
  for (int mi = 0; mi < 2; mi++){
    int p = p0 + wm + mi * 16 + rsel; hh[mi] = p >> 5; ww[mi] = p & 31;
  }
  #pragma unroll
  for (int ni = 0; ni < 2; ni++) nn[ni] = wn + ni * 16 + rsel;
  f32x4 acc[2][2] = {};
  for (int s = 0; s < 9; s++){
    int dy = s / 3 - 1, dx = s - (s / 3) * 3 - 1;
    int abase[2];
    #pragma unroll
    for (int mi = 0; mi < 2; mi++){
      int y = hh[mi] + rate * dy, x = ww[mi] + rate * dx;
      bool ok = ((unsigned)y < HW) && ((unsigned)x < HW);
      abase[mi] = ok ? ((y * HW + x) * C_IN + ksel) : -1;
    }
    int bbase[2];
    #pragma unroll
    for (int ni = 0; ni < 2; ni++) bbase[ni] = (s * 64 + nn[ni]) * C_IN + ksel;
    #pragma unroll
    for (int cc = 0; cc < 8; cc++){
      int c0 = cc * 32;
      short8 a[2], bb[2];
      short8 z = {0, 0, 0, 0, 0, 0, 0, 0};
      #pragma unroll
      for (int mi = 0; mi < 2; mi++)
        a[mi] = (abase[mi] >= 0) ? *(const short8*)&FT[abase[mi] + c0] : z;
      #pragma unroll
      for (int ni = 0; ni < 2; ni++)
        bb[ni] = *(const short8*)&WG[bbase[ni] + c0];
      #pragma unroll
      for (int mi = 0; mi < 2; mi++)
        #pragma unroll
        for (int ni = 0; ni < 2; ni++)
          acc[mi][ni] = __builtin_amdgcn_mfma_f32_16x16x32_bf16(a[mi], bb[ni], acc[mi][ni], 0, 0, 0);
    }
  }
  int rowb = (lane >> 4) * 4, col = lane & 15;
  float* O = out + (size_t)(b * 256 + g * 64) * L;
  #pragma unroll
  for (int mi = 0; mi < 2; mi++)
    #pragma unroll
    for (int ni = 0; ni < 2; ni++){
      int n = wn + ni * 16 + col;
      float bias = conv_b[g * 64 + n];
      #pragma unroll
      for (int r2 = 0; r2 < 4; r2++){
        int p = p0 + wm + mi * 16 + rowb + r2;
        O[(size_t)n * L + p] = fmaxf(acc[mi][ni][r2] + bias, 0.f);
      }
    }
}

// ---------------- workspace layout (bytes) --------------------------------------
// [0, 37748736)           : Kn'  (8*1024*2304 bf16)  -> reused as Knt' after GEMM1
// [37748736, 75497472)    : FgP' (8*1024*2304 bf16)  -> reused as Rt after GEMM1
// [75497472, 109051904)   : mbgT (8*1024*256 bf16, dead after kn_norm)
//                           -> scores (8*1024*1024 f32) -> finalT after softmax
// [109051904, 125829120)  : attn (8*1024*1024 bf16)
// [125829120, 125861888)  : rnorm (8*1024 f32)
// [125861888, 127041536)  : Wr (4*9*64*256 bf16)
// fgT lives in d_out[0 .. 4.2MB) (d_out only written by branch_conv at the end)
// total ws: 127,041,536 B (same as round 1)

extern "C" void kernel_launch(void* const* d_in, const int* in_sizes, int n_in,
                              void* d_out, int out_size, void* d_ws, size_t ws_size,
                              hipStream_t stream){
  const float* fg     = (const float*)d_in[0];
  const float* mask   = (const float*)d_in[1];
  const float* bgd    = (const float*)d_in[2];
  const float* conv_w = (const float*)d_in[3];
  const float* conv_b = (const float*)d_in[4];

  char* ws = (char*)d_ws;
  unsigned short* Kn     = (unsigned short*)(ws + 0);
  unsigned short* Knt    = Kn;                                  // reuse after GEMM1
  unsigned short* FgP    = (unsigned short*)(ws + 37748736);
  unsigned short* Rt     = FgP;                                 // reuse after GEMM1
  unsigned short* mbgT   = (unsigned short*)(ws + 75497472);    // dead before GEMM1
  float*          scores = (float*)(ws + 75497472);
  unsigned short* finalT = (unsigned short*)scores;             // reuse after softmax
  unsigned short* attn   = (unsigned short*)(ws + 109051904);
  float*          rnorm  = (float*)(ws + 125829120);
  unsigned short* Wr     = (unsigned short*)(ws + 125861888);
  unsigned short* fgT    = (unsigned short*)d_out;              // first 4.2MB of d_out
  float* out = (float*)d_out;

  transpose_pack<<<dim3(16, 4, 8), 256, 0, stream>>>(fg, bgd, mask, fgT, mbgT);
  kn_norm <<<8192, 256, 0, stream>>>(mbgT, Kn, rnorm);
  fgp_pack<<<8192, 256, 0, stream>>>(fgT, FgP);
  wr_prep <<<2304, 256, 0, stream>>>(conv_w, Wr);

  // GEMM1: scores[p][l] = FgP'[p][:] . Kn'[l][:]   (M=N=1024, K=2304)
  gemm_bt<0><<<dim3(8, 8, 8), 256, 0, stream>>>(FgP, Kn, scores, 2304, 1024,
      (long)1024 * 2304, (long)1024 * 2304, (long)1024 * 1024);

  prop_softmax<<<8192, 256, 0, stream>>>(scores, attn);

  // Knt' written into Kn's region (Kn dead after GEMM1)
  write_knt<<<18432, 256, 0, stream>>>(bgd, mask, rnorm, Knt);

  // GEMM2: Rt[p][q'] = attn[p][:] . Knt'[q'][:]    (M=1024, N=2304, K=1024)
  gemm_bt<1><<<dim3(18, 8, 8), 256, 0, stream>>>(attn, Knt, Rt, 1024, 2304,
      (long)1024 * 1024, (long)2304 * 1024, (long)1024 * 2304);

  fold_final<<<8192, 256, 0, stream>>>(Rt, fgT, mask, finalT);

  branch_conv<<<dim3(16, 32), 256, 0, stream>>>(finalT, Wr, conv_b, out);
}

// Round 3
// 265.408 us; speedup vs baseline: 1.5227x; 1.1331x over previous
//
#include <hip/hip_runtime.h>

typedef __attribute__((ext_vector_type(8))) short short8;
typedef __attribute__((ext_vector_type(4))) float f32x4;

#define HW 32
#define L 1024        // HW*HW
#define C_IN 256
#define KP 2304       // C_IN*9
#define BATCH 8

static __device__ __forceinline__ unsigned short f2bf(float f){
  unsigned int u = __float_as_uint(f);
  unsigned int r = (u + 0x7FFFu + ((u >> 16) & 1u)) >> 16;   // RNE (no NaN inputs)
  return (unsigned short)r;
}
static __device__ __forceinline__ float bf2f(unsigned short h){
  return __uint_as_float(((unsigned int)h) << 16);
}

#define GLDS16(g, l) __builtin_amdgcn_global_load_lds(                          \
    (const __attribute__((address_space(1))) void*)(g),                         \
    (__attribute__((address_space(3))) void*)(l), 16, 0, 0)

// ---------------- P0: channel-last transposes: fgT[b][p][c], mbgT[b][p][c] ------
__global__ __launch_bounds__(256) void transpose_pack(const float* __restrict__ fg,
                                                      const float* __restrict__ bgd,
                                                      const float* __restrict__ mask,
                                                      unsigned short* __restrict__ fgT,
                                                      unsigned short* __restrict__ mbgT){
  __shared__ float T[64][65];
  int p0 = blockIdx.x * 64, c0 = blockIdx.y * 64, b = blockIdx.z;
  int tx = threadIdx.x & 63, ty = threadIdx.x >> 6;
  const float* F = fg  + ((size_t)b * C_IN + c0) * L + p0;
  const float* G = bgd + ((size_t)b * C_IN + c0) * L + p0;
  for (int cc = ty; cc < 64; cc += 4) T[cc][tx] = F[(size_t)cc * L + tx];
  __syncthreads();
  for (int pp = ty; pp < 64; pp += 4)
    fgT[(size_t)(b * L + p0 + pp) * C_IN + c0 + tx] = f2bf(T[tx][pp]);
  __syncthreads();
  float mm = 1.f - mask[p0 + tx];
  for (int cc = ty; cc < 64; cc += 4) T[cc][tx] = G[(size_t)cc * L + tx] * mm;
  __syncthreads();
  for (int pp = ty; pp < 64; pp += 4)
    mbgT[(size_t)(b * L + p0 + pp) * C_IN + c0 + tx] = f2bf(T[tx][pp]);
}

// ---------------- P1: fused norm + Kn'[b][l][s*256+c] bf16 ----------------------
__global__ __launch_bounds__(256) void kn_norm(const unsigned short* __restrict__ mbgT,
                                               unsigned short* __restrict__ Kn,
                                               float* __restrict__ rnorm){
  int bl = blockIdx.x;
  int b = bl >> 10, l = bl & 1023;
  int h = l >> 5, w = l & 31;
  int c = threadIdx.x;
  const unsigned short* M = mbgT + (size_t)b * L * C_IN;
  float v[9]; float acc = 0.f;
  #pragma unroll
  for (int s = 0; s < 9; s++){
    int y = h + s / 3 - 1, x = w + s % 3 - 1;
    float val = 0.f;
    if ((unsigned)y < HW && (unsigned)x < HW) val = bf2f(M[(size_t)(y * HW + x) * C_IN + c]);
    v[s] = val + 1e-7f;
    acc += v[s] * v[s];
  }
  #pragma unroll
  for (int off = 32; off; off >>= 1) acc += __shfl_xor(acc, off);
  __shared__ float red[4];
  if ((c & 63) == 0) red[c >> 6] = acc;
  __syncthreads();
  float rn = 1.f / sqrtf(red[0] + red[1] + red[2] + red[3]);
  if (c == 0) rnorm[bl] = rn;
  unsigned short* O = Kn + (size_t)bl * KP;
  #pragma unroll
  for (int s = 0; s < 9; s++) O[s * 256 + c] = f2bf(v[s] * rn);
}

// ---------------- P2: FgP'[b][p][s*256+c] bf16 ----------------------------------
__global__ __launch_bounds__(256) void fgp_pack(const unsigned short* __restrict__ fgT,
                                                unsigned short* __restrict__ FgP){
  int bp = blockIdx.x;
  int b = bp >> 10, p = bp & 1023;
  int h = p >> 5, w = p & 31;
  int c = threadIdx.x;
  const unsigned short* F = fgT + (size_t)b * L * C_IN;
  unsigned short* O = FgP + (size_t)bp * KP;
  #pragma unroll
  for (int s = 0; s < 9; s++){
    int y = h + s / 3 - 1, x = w + s % 3 - 1;
    unsigned short val = 0;
    if ((unsigned)y < HW && (unsigned)x < HW) val = F[(size_t)(y * HW + x) * C_IN + c];
    O[s * 256 + c] = val;
  }
}

// ---------------- P3: Knt'[b][s*256+c][l] bf16 ----------------------------------
__global__ __launch_bounds__(256) void write_knt(const float* __restrict__ bgd,
                                                 const float* __restrict__ mask,
                                                 const float* __restrict__ rnorm,
                                                 unsigned short* __restrict__ Knt){
  int gid = blockIdx.x;
  int b = gid / KP, q = gid - b * KP;
  int s = q >> 8, c = q & 255;
  int dy = s / 3 - 1, dx = s % 3 - 1;
  const float* bg = bgd + ((size_t)b * C_IN + c) * L;
  const float* rn = rnorm + b * L;
  unsigned short* out = Knt + (size_t)gid * L;
  for (int l = threadIdx.x; l < L; l += 256){
    int y = (l >> 5) + dy, x = (l & 31) + dx;
    float v = 0.f;
    if ((unsigned)y < HW && (unsigned)x < HW)
      v = bg[y * HW + x] * (1.f - mask[y * HW + x]);
    out[l] = f2bf((v + 1e-7f) * rn[l]);
  }
}

// ---------------- P4: Wr[g][s][n][c] bf16 ---------------------------------------
__global__ __launch_bounds__(256) void wr_prep(const float* __restrict__ conv_w,
                                               unsigned short* __restrict__ Wr){
  int idx = blockIdx.x * 256 + threadIdx.x;
  int c = idx & 255;
  int rest = idx >> 8;
  int n = rest & 63;
  int sg = rest >> 6;
  int s = sg % 9, g = sg / 9;
  Wr[idx] = f2bf(conv_w[(((size_t)(g * 64 + n)) * C_IN + c) * 9 + s]);
}

// ---------------- GEMM: BK=64 double-buffered, T2 swizzle, T1 XCD swizzle -------
// C[m][n] = sum_k A[m][k]*B[n][k]; 128x128 tile, 4 waves, 1D grid (gx*gy*8)
template<int OUT_BF16>
__global__ __launch_bounds__(256) void gemm_bt(const unsigned short* __restrict__ A,
                                               const unsigned short* __restrict__ B,
                                               void* __restrict__ Cv,
                                               int K, int N, int nt, int gx, int gxy,
                                               long strideA, long strideB, long strideC)
{
  __shared__ unsigned short As[2][128][64];   // 32 KB
  __shared__ unsigned short Bs[2][128][64];   // 32 KB
  // T1: bijective XCD swizzle (gridDim.x % 8 == 0 by construction)
  int nwg = gridDim.x, bid = blockIdx.x;
  int chunk = nwg >> 3;
  int nid = (bid & 7) * chunk + (bid >> 3);
  int bz = nid / gxy, r = nid - bz * gxy;
  int by = r / gx, bx = r - by * gx;

  const unsigned short* Ab = A + (size_t)bz * strideA + (size_t)by * 128 * K;
  const unsigned short* Bb = B + (size_t)bz * strideB + (size_t)bx * 128 * K;
  int tid = threadIdx.x, lane = tid & 63, wv = tid >> 6;
  int wm = (wv & 1) * 64, wn = (wv >> 1) * 64;
  int rsel = lane & 15, sx = lane >> 4;      // sx in 0..3 (16B slot within k-half)
  int rp = rsel & 7;                         // row parity for swizzle

  // staging source: lane covers row (lane>>3) of each 8-row group, pre-swizzled col
  int srow = lane >> 3;                      // 0..7
  int scol = ((lane & 7) ^ srow) * 8;        // inverse-swizzled global column (elements)
  const unsigned short* Ag = Ab + (size_t)(wv * 32 + srow) * K + scol;
  const unsigned short* Bg = Bb + (size_t)(wv * 32 + srow) * K + scol;

  f32x4 acc[4][4] = {};

  // prologue: stage buffer 0
  #pragma unroll
  for (int g = 0; g < 4; g++){
    GLDS16(Ag + (size_t)g * 8 * K, &As[0][wv * 32 + g * 8][0]);
    GLDS16(Bg + (size_t)g * 8 * K, &Bs[0][wv * 32 + g * 8][0]);
  }
  __syncthreads();

  int cur = 0;
  for (int t = 0; t < nt; ++t){
    // ds_read current tile fragments (swizzled columns)
    short8 af[2][4], bf[2][4];
    #pragma unroll
    for (int kk = 0; kk < 2; kk++){
      int s0 = kk * 4 + sx;
      int col = ((s0 ^ rp) << 3);
      #pragma unroll
      for (int i = 0; i < 4; i++){
        af[kk][i] = *(const short8*)&As[cur][wm + i * 16 + rsel][col];
        bf[kk][i] = *(const short8*)&Bs[cur][wn + i * 16 + rsel][col];
      }
    }
    // issue next-tile stage (overlaps with MFMA below)
    if (t + 1 < nt){
      size_t kt = (size_t)(t + 1) * 64;
      int nb = cur ^ 1;
      #pragma unroll
      for (int g = 0; g < 4; g++){
        GLDS16(Ag + kt + (size_t)g * 8 * K, &As[nb][wv * 32 + g * 8][0]);
        GLDS16(Bg + kt + (size_t)g * 8 * K, &Bs[nb][wv * 32 + g * 8][0]);
      }
    }
    #pragma unroll
    for (int kk = 0; kk < 2; kk++)
      #pragma unroll
      for (int i = 0; i < 4; i++)
        #pragma unroll
        for (int j = 0; j < 4; j++)
          acc[i][j] = __builtin_amdgcn_mfma_f32_16x16x32_bf16(af[kk][i], bf[kk][j], acc[i][j], 0, 0, 0);
    __syncthreads();   // drains vmcnt (prefetch) + releases buf[cur]
    cur ^= 1;
  }

  int m0 = by * 128, n0 = bx * 128;
  int rowb = (lane >> 4) * 4, col = lane & 15;
  if (OUT_BF16){
    unsigned short* Cb = (unsigned short*)Cv + (size_t)bz * strideC;
    #pragma unroll
    for (int i = 0; i < 4; i++)
      #pragma unroll
      for (int j = 0; j < 4; j++)
        #pragma unroll
        for (int r2 = 0; r2 < 4; r2++)
          Cb[(size_t)(m0 + wm + i * 16 + rowb + r2) * N + (n0 + wn + j * 16 + col)] = f2bf(acc[i][j][r2]);
  } else {
    float* Cb = (float*)Cv + (size_t)bz * strideC;
    #pragma unroll
    for (int i = 0; i < 4; i++)
      #pragma unroll
      for (int j = 0; j < 4; j++)
        #pragma unroll
        for (int r2 = 0; r2 < 4; r2++)
          Cb[(size_t)(m0 + wm + i * 16 + rowb + r2) * N + (n0 + wn + j * 16 + col)] = acc[i][j][r2];
  }
}

// ---------------- K2: window-sum + softmax, 2x2 spatial tile per block ----------
__global__ __launch_bounds__(256) void prop_softmax(const float* __restrict__ scores,
                                                    unsigned short* __restrict__ attn){
  int bt = blockIdx.x;                 // b*256 + tile
  int b = bt >> 8, tp = bt & 255;
  int h0 = (tp >> 4) * 2, w0 = (tp & 15) * 2;
  const float* S = scores + ((size_t)b << 20);
  int tid = threadIdx.x, wv = tid >> 6;
  float a0[4] = {0,0,0,0}, a1[4] = {0,0,0,0}, a2[4] = {0,0,0,0}, a3[4] = {0,0,0,0};
  #pragma unroll
  for (int dy = 0; dy < 4; dy++){
    int y = h0 + dy - 1; if ((unsigned)y >= HW) continue;
    #pragma unroll
    for (int dx = 0; dx < 4; dx++){
      int x = w0 + dx - 1; if ((unsigned)x >= HW) continue;
      float4 v = *(const float4*)(S + (((size_t)(y * HW + x)) << 10) + tid * 4);
      // output (oy,ox) uses source iff |dy-1-oy|<=1 && |dx-1-ox|<=1  (compile-time)
      #pragma unroll
      for (int oy = 0; oy < 2; oy++)
        #pragma unroll
        for (int ox = 0; ox < 2; ox++){
          int ddy = dy - 1 - oy, ddx = dx - 1 - ox;
          if (ddy >= -1 && ddy <= 1 && ddx >= -1 && ddx <= 1){
            float* a = (oy * 2 + ox == 0) ? a0 : (oy * 2 + ox == 1) ? a1 : (oy * 2 + ox == 2) ? a2 : a3;
            a[0] += v.x; a[1] += v.y; a[2] += v.z; a[3] += v.w;
          }
        }
    }
  }
  float* accs[4] = {a0, a1, a2, a3};
  __shared__ float redm[4][4], reds[4][4];
  float mx[4];
  #pragma unroll
  for (int o = 0; o < 4; o++){
    float* a = accs[o];
    float m = fmaxf(fmaxf(a[0], a[1]), fmaxf(a[2], a[3]));
    #pragma unroll
    for (int off = 32; off; off >>= 1) m = fmaxf(m, __shfl_xor(m, off));
    if ((tid & 63) == 0) redm[wv][o] = m;
  }
  __syncthreads();
  #pragma unroll
  for (int o = 0; o < 4; o++)
    mx[o] = fmaxf(fmaxf(redm[0][o], redm[1][o]), fmaxf(redm[2][o], redm[3][o]));
  float e[4][4], sm[4];
  #pragma unroll
  for (int o = 0; o < 4; o++){
    float* a = accs[o];
    float t = 0.f;
    #pragma unroll
    for (int c2 = 0; c2 < 4; c2++){ e[o][c2] = __expf(a[c2] - mx[o]); t += e[o][c2]; }
    #pragma unroll
    for (int off = 32; off; off >>= 1) t += __shfl_xor(t, off);
    if ((tid & 63) == 0) reds[wv][o] = t;
  }
  __syncthreads();
  #pragma unroll
  for (int o = 0; o < 4; o++) sm[o] = 1.f / (reds[0][o] + reds[1][o] + reds[2][o] + reds[3][o]);
  #pragma unroll
  for (int oy = 0; oy < 2; oy++)
    #pragma unroll
    for (int ox = 0; ox < 2; ox++){
      int o = oy * 2 + ox;
      int p = (h0 + oy) * HW + (w0 + ox);
      ushort4 ov;
      ov.x = f2bf(e[o][0] * sm[o]); ov.y = f2bf(e[o][1] * sm[o]);
      ov.z = f2bf(e[o][2] * sm[o]); ov.w = f2bf(e[o][3] * sm[o]);
      *(ushort4*)&attn[(((size_t)(b * L + p)) << 10) + tid * 4] = ov;
    }
}

// ---------------- K3: fold Rt[p][s*256+c] -> finalT[b][p][c] bf16 ---------------
__global__ __launch_bounds__(256) void fold_final(const unsigned short* __restrict__ Rt,
                                                  const unsigned short* __restrict__ fgT,
                                                  const float* __restrict__ mask,
                                                  unsigned short* __restrict__ finalT){
  int bp = blockIdx.x;
  int b = bp >> 10, p = bp & 1023;
  int h = p >> 5, w = p & 31;
  int c = threadIdx.x;
  float val;
  if (mask[p] != 0.f){
    const unsigned short* R = Rt + (size_t)b * L * KP;
    float sum = 0.f;
    #pragma unroll
    for (int u = 0; u < 3; u++){
      int y = h + 1 - u; if ((unsigned)y >= HW) continue;
      #pragma unroll
      for (int v = 0; v < 3; v++){
        int x = w + 1 - v; if ((unsigned)x >= HW) continue;
        sum += bf2f(R[(size_t)(y * HW + x) * KP + (u * 3 + v) * 256 + c]);
      }
    }
    val = sum / 9.0f;
  } else {
    val = bf2f(fgT[(size_t)bp * C_IN + c]);
  }
  finalT[(size_t)bp * C_IN + c] = f2bf(val);
}

// ---------------- K4: 4 dilated conv branches as 9-shifted register GEMMs -------
__global__ __launch_bounds__(256) void branch_conv(const unsigned short* __restrict__ finalT,
                                                   const unsigned short* __restrict__ Wr,
                                                   const float* __restrict__ conv_b,
                                                   float* __restrict__ out){
  int mt = blockIdx.x;
  int bg_ = blockIdx.y;
  int b = bg_ >> 2, g = bg_ & 3;
  int rate = 1 << g;
  int p0 = mt * 64;
  int tid = threadIdx.x, lane = tid & 63, wv = tid >> 6;
  int wm = (wv & 1) * 32, wn = (wv >> 1) * 32;
  int rsel = lane & 15, ksel = (lane >> 4) * 8;
  const unsigned short* FT = finalT + (size_t)b * L * C_IN;
  const unsigned short* WG = Wr + (size_t)g * 9 * 64 * C_IN;
  int hh[2], ww[2], nn[2];
  #pragma unroll
  for (int mi = 0; mi < 2; mi++){
    int p = p0 + wm + mi * 16 + rsel; hh[mi] = p >> 5; ww[mi] = p & 31;
  }
  #pragma unroll
  for (int ni = 0; ni < 2; ni++) nn[ni] = wn + ni * 16 + rsel;
  f32x4 acc[2][2] = {};
  for (int s = 0; s < 9; s++){
    int dy = s / 3 - 1, dx = s - (s / 3) * 3 - 1;
    int abase[2];
    #pragma unroll
    for (int mi = 0; mi < 2; mi++){
      int y = hh[mi] + rate * dy, x = ww[mi] + rate * dx;
      bool ok = ((unsigned)y < HW) && ((unsigned)x < HW);
      abase[mi] = ok ? ((y * HW + x) * C_IN + ksel) : -1;
    }
    int bbase[2];
    #pragma unroll
    for (int ni = 0; ni < 2; ni++) bbase[ni] = (s * 64 + nn[ni]) * C_IN + ksel;
    #pragma unroll
    for (int cc = 0; cc < 8; cc++){
      int c0 = cc * 32;
      short8 a[2], bb[2];
      short8 z = {0, 0, 0, 0, 0, 0, 0, 0};
      #pragma unroll
      for (int mi = 0; mi < 2; mi++)
        a[mi] = (abase[mi] >= 0) ? *(const short8*)&FT[abase[mi] + c0] : z;
      #pragma unroll
      for (int ni = 0; ni < 2; ni++)
        bb[ni] = *(const short8*)&WG[bbase[ni] + c0];
      #pragma unroll
      for (int mi = 0; mi < 2; mi++)
        #pragma unroll
        for (int ni = 0; ni < 2; ni++)
          acc[mi][ni] = __builtin_amdgcn_mfma_f32_16x16x32_bf16(a[mi], bb[ni], acc[mi][ni], 0, 0, 0);
    }
  }
  int rowb = (lane >> 4) * 4, col = lane & 15;
  float* O = out + (size_t)(b * 256 + g * 64) * L;
  #pragma unroll
  for (int mi = 0; mi < 2; mi++)
    #pragma unroll
    for (int ni = 0; ni < 2; ni++){
      int n = wn + ni * 16 + col;
      float bias = conv_b[g * 64 + n];
      #pragma unroll
      for (int r2 = 0; r2 < 4; r2++){
        int p = p0 + wm + mi * 16 + rowb + r2;
        O[(size_t)n * L + p] = fmaxf(acc[mi][ni][r2] + bias, 0.f);
      }
    }
}

// ---------------- workspace layout: same as round 2 -----------------------------
extern "C" void kernel_launch(void* const* d_in, const int* in_sizes, int n_in,
                              void* d_out, int out_size, void* d_ws, size_t ws_size,
                              hipStream_t stream){
  const float* fg     = (const float*)d_in[0];
  const float* mask   = (const float*)d_in[1];
  const float* bgd    = (const float*)d_in[2];
  const float* conv_w = (const float*)d_in[3];
  const float* conv_b = (const float*)d_in[4];

  char* ws = (char*)d_ws;
  unsigned short* Kn     = (unsigned short*)(ws + 0);
  unsigned short* Knt    = Kn;
  unsigned short* FgP    = (unsigned short*)(ws + 37748736);
  unsigned short* Rt     = FgP;
  unsigned short* mbgT   = (unsigned short*)(ws + 75497472);
  float*          scores = (float*)(ws + 75497472);
  unsigned short* finalT = (unsigned short*)scores;
  unsigned short* attn   = (unsigned short*)(ws + 109051904);
  float*          rnorm  = (float*)(ws + 125829120);
  unsigned short* Wr     = (unsigned short*)(ws + 125861888);
  unsigned short* fgT    = (unsigned short*)d_out;
  float* out = (float*)d_out;

  transpose_pack<<<dim3(16, 4, 8), 256, 0, stream>>>(fg, bgd, mask, fgT, mbgT);
  kn_norm <<<8192, 256, 0, stream>>>(mbgT, Kn, rnorm);
  fgp_pack<<<8192, 256, 0, stream>>>(fgT, FgP);
  wr_prep <<<2304, 256, 0, stream>>>(conv_w, Wr);

  // GEMM1: scores[p][l] = FgP'[p][:] . Kn'[l][:]   (M=N=1024, K=2304, nt=36)
  gemm_bt<0><<<512, 256, 0, stream>>>(FgP, Kn, scores, 2304, 1024, 36, 8, 64,
      (long)1024 * 2304, (long)1024 * 2304, (long)1024 * 1024);

  prop_softmax<<<2048, 256, 0, stream>>>(scores, attn);

  write_knt<<<18432, 256, 0, stream>>>(bgd, mask, rnorm, Knt);

  // GEMM2: Rt[p][q'] = attn[p][:] . Knt'[q'][:]    (M=1024, N=2304, K=1024, nt=16)
  gemm_bt<1><<<1152, 256, 0, stream>>>(attn, Knt, Rt, 1024, 2304, 16, 18, 144,
      (long)1024 * 1024, (long)2304 * 1024, (long)1024 * 2304);

  fold_final<<<8192, 256, 0, stream>>>(Rt, fgT, mask, finalT);

  branch_conv<<<dim3(16, 32), 256, 0, stream>>>(finalT, Wr, conv_b, out);
}

// Round 4
// 226.852 us; speedup vs baseline: 1.7815x; 1.1700x over previous
//
#include <hip/hip_runtime.h>

typedef __attribute__((ext_vector_type(8))) short short8;
typedef __attribute__((ext_vector_type(4))) float f32x4;

#define HW 32
#define L 1024        // HW*HW
#define C_IN 256
#define KP 2304       // C_IN*9
#define BATCH 8

static __device__ __forceinline__ unsigned short f2bf(float f){
  unsigned int u = __float_as_uint(f);
  unsigned int r = (u + 0x7FFFu + ((u >> 16) & 1u)) >> 16;   // RNE (no NaN inputs)
  return (unsigned short)r;
}
static __device__ __forceinline__ float bf2f(unsigned short h){
  return __uint_as_float(((unsigned int)h) << 16);
}

#define GLDS16(g, l) __builtin_amdgcn_global_load_lds(                          \
    (const __attribute__((address_space(1))) void*)(g),                         \
    (__attribute__((address_space(3))) void*)(l), 16, 0, 0)

// ---------------- P0: channel-last transposes: fgT[b][p][c], mbgT[b][p][c] ------
__global__ __launch_bounds__(256) void transpose_pack(const float* __restrict__ fg,
                                                      const float* __restrict__ bgd,
                                                      const float* __restrict__ mask,
                                                      unsigned short* __restrict__ fgT,
                                                      unsigned short* __restrict__ mbgT){
  __shared__ float T[64][65];
  int p0 = blockIdx.x * 64, c0 = blockIdx.y * 64, b = blockIdx.z;
  int tx = threadIdx.x & 63, ty = threadIdx.x >> 6;
  const float* F = fg  + ((size_t)b * C_IN + c0) * L + p0;
  const float* G = bgd + ((size_t)b * C_IN + c0) * L + p0;
  for (int cc = ty; cc < 64; cc += 4) T[cc][tx] = F[(size_t)cc * L + tx];
  __syncthreads();
  for (int pp = ty; pp < 64; pp += 4)
    fgT[(size_t)(b * L + p0 + pp) * C_IN + c0 + tx] = f2bf(T[tx][pp]);
  __syncthreads();
  float mm = 1.f - mask[p0 + tx];
  for (int cc = ty; cc < 64; cc += 4) T[cc][tx] = G[(size_t)cc * L + tx] * mm;
  __syncthreads();
  for (int pp = ty; pp < 64; pp += 4)
    mbgT[(size_t)(b * L + p0 + pp) * C_IN + c0 + tx] = f2bf(T[tx][pp]);
}

// ---------------- P1: fused norm + Kn'[b][l][s*256+c] bf16 ----------------------
__global__ __launch_bounds__(256) void kn_norm(const unsigned short* __restrict__ mbgT,
                                               unsigned short* __restrict__ Kn,
                                               float* __restrict__ rnorm){
  int bl = blockIdx.x;
  int b = bl >> 10, l = bl & 1023;
  int h = l >> 5, w = l & 31;
  int c = threadIdx.x;
  const unsigned short* M = mbgT + (size_t)b * L * C_IN;
  float v[9]; float acc = 0.f;
  #pragma unroll
  for (int s = 0; s < 9; s++){
    int y = h + s / 3 - 1, x = w + s % 3 - 1;
    float val = 0.f;
    if ((unsigned)y < HW && (unsigned)x < HW) val = bf2f(M[(size_t)(y * HW + x) * C_IN + c]);
    v[s] = val + 1e-7f;
    acc += v[s] * v[s];
  }
  #pragma unroll
  for (int off = 32; off; off >>= 1) acc += __shfl_xor(acc, off);
  __shared__ float red[4];
  if ((c & 63) == 0) red[c >> 6] = acc;
  __syncthreads();
  float rn = 1.f / sqrtf(red[0] + red[1] + red[2] + red[3]);
  if (c == 0) rnorm[bl] = rn;
  unsigned short* O = Kn + (size_t)bl * KP;
  #pragma unroll
  for (int s = 0; s < 9; s++) O[s * 256 + c] = f2bf(v[s] * rn);
}

// ---------------- P2: FgP'[b][p][s*256+c] bf16 ----------------------------------
__global__ __launch_bounds__(256) void fgp_pack(const unsigned short* __restrict__ fgT,
                                                unsigned short* __restrict__ FgP){
  int bp = blockIdx.x;
  int b = bp >> 10, p = bp & 1023;
  int h = p >> 5, w = p & 31;
  int c = threadIdx.x;
  const unsigned short* F = fgT + (size_t)b * L * C_IN;
  unsigned short* O = FgP + (size_t)bp * KP;
  #pragma unroll
  for (int s = 0; s < 9; s++){
    int y = h + s / 3 - 1, x = w + s % 3 - 1;
    unsigned short val = 0;
    if ((unsigned)y < HW && (unsigned)x < HW) val = F[(size_t)(y * HW + x) * C_IN + c];
    O[s * 256 + c] = val;
  }
}

// ---------------- P3: Knt'[b][s*256+c][l] bf16 ----------------------------------
__global__ __launch_bounds__(256) void write_knt(const float* __restrict__ bgd,
                                                 const float* __restrict__ mask,
                                                 const float* __restrict__ rnorm,
                                                 unsigned short* __restrict__ Knt){
  int gid = blockIdx.x;
  int b = gid / KP, q = gid - b * KP;
  int s = q >> 8, c = q & 255;
  int dy = s / 3 - 1, dx = s % 3 - 1;
  const float* bg = bgd + ((size_t)b * C_IN + c) * L;
  const float* rn = rnorm + b * L;
  unsigned short* out = Knt + (size_t)gid * L;
  for (int l = threadIdx.x; l < L; l += 256){
    int y = (l >> 5) + dy, x = (l & 31) + dx;
    float v = 0.f;
    if ((unsigned)y < HW && (unsigned)x < HW)
      v = bg[y * HW + x] * (1.f - mask[y * HW + x]);
    out[l] = f2bf((v + 1e-7f) * rn[l]);
  }
}

// ---------------- P4: Wr[g][s][n][c] bf16 ---------------------------------------
__global__ __launch_bounds__(256) void wr_prep(const float* __restrict__ conv_w,
                                               unsigned short* __restrict__ Wr){
  int idx = blockIdx.x * 256 + threadIdx.x;
  int c = idx & 255;
  int rest = idx >> 8;
  int n = rest & 63;
  int sg = rest >> 6;
  int s = sg % 9, g = sg / 9;
  Wr[idx] = f2bf(conv_w[(((size_t)(g * 64 + n)) * C_IN + c) * 9 + s]);
}

// ---------------- zero page init (reuses dead Knt region) -----------------------
__global__ void zinit(unsigned short* z){ z[threadIdx.x] = 0; }

// ---------------- GEMM: BK=64 double-buffered, T2 swizzle, T1 XCD swizzle -------
template<int OUT_BF16>
__global__ __launch_bounds__(256) void gemm_bt(const unsigned short* __restrict__ A,
                                               const unsigned short* __restrict__ B,
                                               void* __restrict__ Cv,
                                               int K, int N, int nt, int gx, int gxy,
                                               long strideA, long strideB, long strideC)
{
  __shared__ unsigned short As[2][128][64];
  __shared__ unsigned short Bs[2][128][64];
  int nwg = gridDim.x, bid = blockIdx.x;
  int chunk = nwg >> 3;
  int nid = (bid & 7) * chunk + (bid >> 3);
  int bz = nid / gxy, r = nid - bz * gxy;
  int by = r / gx, bx = r - by * gx;

  const unsigned short* Ab = A + (size_t)bz * strideA + (size_t)by * 128 * K;
  const unsigned short* Bb = B + (size_t)bz * strideB + (size_t)bx * 128 * K;
  int tid = threadIdx.x, lane = tid & 63, wv = tid >> 6;
  int wm = (wv & 1) * 64, wn = (wv >> 1) * 64;
  int rsel = lane & 15, sx = lane >> 4;
  int rp = rsel & 7;

  int srow = lane >> 3;
  int scol = ((lane & 7) ^ srow) * 8;
  const unsigned short* Ag = Ab + (size_t)(wv * 32 + srow) * K + scol;
  const unsigned short* Bg = Bb + (size_t)(wv * 32 + srow) * K + scol;

  f32x4 acc[4][4] = {};

  #pragma unroll
  for (int g = 0; g < 4; g++){
    GLDS16(Ag + (size_t)g * 8 * K, &As[0][wv * 32 + g * 8][0]);
    GLDS16(Bg + (size_t)g * 8 * K, &Bs[0][wv * 32 + g * 8][0]);
  }
  __syncthreads();

  int cur = 0;
  for (int t = 0; t < nt; ++t){
    short8 af[2][4], bf[2][4];
    #pragma unroll
    for (int kk = 0; kk < 2; kk++){
      int s0 = kk * 4 + sx;
      int col = ((s0 ^ rp) << 3);
      #pragma unroll
      for (int i = 0; i < 4; i++){
        af[kk][i] = *(const short8*)&As[cur][wm + i * 16 + rsel][col];
        bf[kk][i] = *(const short8*)&Bs[cur][wn + i * 16 + rsel][col];
      }
    }
    if (t + 1 < nt){
      size_t kt = (size_t)(t + 1) * 64;
      int nb = cur ^ 1;
      #pragma unroll
      for (int g = 0; g < 4; g++){
        GLDS16(Ag + kt + (size_t)g * 8 * K, &As[nb][wv * 32 + g * 8][0]);
        GLDS16(Bg + kt + (size_t)g * 8 * K, &Bs[nb][wv * 32 + g * 8][0]);
      }
    }
    #pragma unroll
    for (int kk = 0; kk < 2; kk++)
      #pragma unroll
      for (int i = 0; i < 4; i++)
        #pragma unroll
        for (int j = 0; j < 4; j++)
          acc[i][j] = __builtin_amdgcn_mfma_f32_16x16x32_bf16(af[kk][i], bf[kk][j], acc[i][j], 0, 0, 0);
    __syncthreads();
    cur ^= 1;
  }

  int m0 = by * 128, n0 = bx * 128;
  int rowb = (lane >> 4) * 4, col = lane & 15;
  if (OUT_BF16){
    unsigned short* Cb = (unsigned short*)Cv + (size_t)bz * strideC;
    #pragma unroll
    for (int i = 0; i < 4; i++)
      #pragma unroll
      for (int j = 0; j < 4; j++)
        #pragma unroll
        for (int r2 = 0; r2 < 4; r2++)
          Cb[(size_t)(m0 + wm + i * 16 + rowb + r2) * N + (n0 + wn + j * 16 + col)] = f2bf(acc[i][j][r2]);
  } else {
    float* Cb = (float*)Cv + (size_t)bz * strideC;
    #pragma unroll
    for (int i = 0; i < 4; i++)
      #pragma unroll
      for (int j = 0; j < 4; j++)
        #pragma unroll
        for (int r2 = 0; r2 < 4; r2++)
          Cb[(size_t)(m0 + wm + i * 16 + rowb + r2) * N + (n0 + wn + j * 16 + col)] = acc[i][j][r2];
  }
}

// ---------------- K2: window-sum + softmax, 2x2 spatial tile per block ----------
__global__ __launch_bounds__(256) void prop_softmax(const float* __restrict__ scores,
                                                    unsigned short* __restrict__ attn){
  int bt = blockIdx.x;
  int b = bt >> 8, tp = bt & 255;
  int h0 = (tp >> 4) * 2, w0 = (tp & 15) * 2;
  const float* S = scores + ((size_t)b << 20);
  int tid = threadIdx.x, wv = tid >> 6;
  float a0[4] = {0,0,0,0}, a1[4] = {0,0,0,0}, a2[4] = {0,0,0,0}, a3[4] = {0,0,0,0};
  #pragma unroll
  for (int dy = 0; dy < 4; dy++){
    int y = h0 + dy - 1; if ((unsigned)y >= HW) continue;
    #pragma unroll
    for (int dx = 0; dx < 4; dx++){
      int x = w0 + dx - 1; if ((unsigned)x >= HW) continue;
      float4 v = *(const float4*)(S + (((size_t)(y * HW + x)) << 10) + tid * 4);
      #pragma unroll
      for (int oy = 0; oy < 2; oy++)
        #pragma unroll
        for (int ox = 0; ox < 2; ox++){
          int ddy = dy - 1 - oy, ddx = dx - 1 - ox;
          if (ddy >= -1 && ddy <= 1 && ddx >= -1 && ddx <= 1){
            float* a = (oy * 2 + ox == 0) ? a0 : (oy * 2 + ox == 1) ? a1 : (oy * 2 + ox == 2) ? a2 : a3;
            a[0] += v.x; a[1] += v.y; a[2] += v.z; a[3] += v.w;
          }
        }
    }
  }
  float* accs[4] = {a0, a1, a2, a3};
  __shared__ float redm[4][4], reds[4][4];
  float mx[4];
  #pragma unroll
  for (int o = 0; o < 4; o++){
    float* a = accs[o];
    float m = fmaxf(fmaxf(a[0], a[1]), fmaxf(a[2], a[3]));
    #pragma unroll
    for (int off = 32; off; off >>= 1) m = fmaxf(m, __shfl_xor(m, off));
    if ((tid & 63) == 0) redm[wv][o] = m;
  }
  __syncthreads();
  #pragma unroll
  for (int o = 0; o < 4; o++)
    mx[o] = fmaxf(fmaxf(redm[0][o], redm[1][o]), fmaxf(redm[2][o], redm[3][o]));
  float e[4][4], sm[4];
  #pragma unroll
  for (int o = 0; o < 4; o++){
    float* a = accs[o];
    float t = 0.f;
    #pragma unroll
    for (int c2 = 0; c2 < 4; c2++){ e[o][c2] = __expf(a[c2] - mx[o]); t += e[o][c2]; }
    #pragma unroll
    for (int off = 32; off; off >>= 1) t += __shfl_xor(t, off);
    if ((tid & 63) == 0) reds[wv][o] = t;
  }
  __syncthreads();
  #pragma unroll
  for (int o = 0; o < 4; o++) sm[o] = 1.f / (reds[0][o] + reds[1][o] + reds[2][o] + reds[3][o]);
  #pragma unroll
  for (int oy = 0; oy < 2; oy++)
    #pragma unroll
    for (int ox = 0; ox < 2; ox++){
      int o = oy * 2 + ox;
      int p = (h0 + oy) * HW + (w0 + ox);
      ushort4 ov;
      ov.x = f2bf(e[o][0] * sm[o]); ov.y = f2bf(e[o][1] * sm[o]);
      ov.z = f2bf(e[o][2] * sm[o]); ov.w = f2bf(e[o][3] * sm[o]);
      *(ushort4*)&attn[(((size_t)(b * L + p)) << 10) + tid * 4] = ov;
    }
}

// ---------------- K3: fold Rt[p][s*256+c] -> finalT[b][p][c] bf16 ---------------
__global__ __launch_bounds__(256) void fold_final(const unsigned short* __restrict__ Rt,
                                                  const unsigned short* __restrict__ fgT,
                                                  const float* __restrict__ mask,
                                                  unsigned short* __restrict__ finalT){
  int bp = blockIdx.x;
  int b = bp >> 10, p = bp & 1023;
  int h = p >> 5, w = p & 31;
  int c = threadIdx.x;
  float val;
  if (mask[p] != 0.f){
    const unsigned short* R = Rt + (size_t)b * L * KP;
    float sum = 0.f;
    #pragma unroll
    for (int u = 0; u < 3; u++){
      int y = h + 1 - u; if ((unsigned)y >= HW) continue;
      #pragma unroll
      for (int v = 0; v < 3; v++){
        int x = w + 1 - v; if ((unsigned)x >= HW) continue;
        sum += bf2f(R[(size_t)(y * HW + x) * KP + (u * 3 + v) * 256 + c]);
      }
    }
    val = sum / 9.0f;
  } else {
    val = bf2f(fgT[(size_t)bp * C_IN + c]);
  }
  finalT[(size_t)bp * C_IN + c] = f2bf(val);
}

// ---------------- K4: branch convs as shifted, LDS-staged GEMM ------------------
// per block: 64 p x 64 n(out-ch of one g), K = 9 taps x 256 c = 36 steps of BK=64
__global__ __launch_bounds__(256) void branch_gemm(const unsigned short* __restrict__ finalT,
                                                   const unsigned short* __restrict__ Wr,
                                                   const float* __restrict__ conv_b,
                                                   const unsigned short* __restrict__ zpage,
                                                   float* __restrict__ out){
  __shared__ unsigned short As[2][64][64];   // 16 KB
  __shared__ unsigned short Bs[2][64][64];   // 16 KB
  int nwg = gridDim.x, bid = blockIdx.x;
  int nid = (bid & 7) * (nwg >> 3) + (bid >> 3);   // T1 bijective (512 % 8 == 0)
  int bg = nid >> 4, pt = nid & 15;
  int b = bg >> 2, g = bg & 3;
  int rate = 1 << g;
  int p0 = pt * 64;
  int tid = threadIdx.x, lane = tid & 63, wv = tid >> 6;
  int wm = (wv & 1) * 32, wn = (wv >> 1) * 32;
  int rsel = lane & 15;
  int srow = lane >> 3;                      // 0..7
  int scol = ((lane & 7) ^ srow) * 8;        // pre-swizzled col (elements)
  const unsigned short* FT = finalT + (size_t)b * L * C_IN;
  const unsigned short* WG = Wr + (size_t)(g * 9) * 64 * C_IN;

  int ay[2], ax[2];
  #pragma unroll
  for (int g8 = 0; g8 < 2; g8++){
    int p = p0 + wv * 16 + g8 * 8 + srow;
    ay[g8] = p >> 5; ax[g8] = p & 31;
  }

  auto a_src = [&](int t, int g8) -> const unsigned short* {
    int s = t >> 2, q = t & 3;
    int dy = s / 3 - 1, dx = s - (s / 3) * 3 - 1;
    int iy = ay[g8] + rate * dy, ix = ax[g8] + rate * dx;
    if ((unsigned)iy < HW && (unsigned)ix < HW)
      return FT + (size_t)(iy * HW + ix) * C_IN + q * 64 + scol;
    return zpage;                            // wave-uniform zero 16B, per-lane ok
  };
  auto b_src = [&](int t, int g8) -> const unsigned short* {
    int s = t >> 2, q = t & 3;
    int n = wv * 16 + g8 * 8 + srow;
    return WG + (size_t)(s * 64 + n) * C_IN + q * 64 + scol;
  };

  f32x4 acc[2][2] = {};
  #pragma unroll
  for (int g8 = 0; g8 < 2; g8++){
    GLDS16(a_src(0, g8), &As[0][wv * 16 + g8 * 8][0]);
    GLDS16(b_src(0, g8), &Bs[0][wv * 16 + g8 * 8][0]);
  }
  __syncthreads();
  int cur = 0;
  for (int t = 0; t < 36; ++t){
    short8 af[2][2], bf[2][2];
    #pragma unroll
    for (int kk = 0; kk < 2; kk++){
      int s0 = kk * 4 + (lane >> 4);
      int col = ((s0 ^ (rsel & 7)) << 3);
      #pragma unroll
      for (int i = 0; i < 2; i++){
        af[kk][i] = *(const short8*)&As[cur][wm + i * 16 + rsel][col];
        bf[kk][i] = *(const short8*)&Bs[cur][wn + i * 16 + rsel][col];
      }
    }
    if (t + 1 < 36){
      int nb = cur ^ 1;
      #pragma unroll
      for (int g8 = 0; g8 < 2; g8++){
        GLDS16(a_src(t + 1, g8), &As[nb][wv * 16 + g8 * 8][0]);
        GLDS16(b_src(t + 1, g8), &Bs[nb][wv * 16 + g8 * 8][0]);
      }
    }
    #pragma unroll
    for (int kk = 0; kk < 2; kk++)
      #pragma unroll
      for (int i = 0; i < 2; i++)
        #pragma unroll
        for (int j = 0; j < 2; j++)
          acc[i][j] = __builtin_amdgcn_mfma_f32_16x16x32_bf16(af[kk][i], bf[kk][j], acc[i][j], 0, 0, 0);
    __syncthreads();
    cur ^= 1;
  }
  int rowb = (lane >> 4) * 4, col = lane & 15;
  float* O = out + (size_t)(b * 256 + g * 64) * L;
  #pragma unroll
  for (int i = 0; i < 2; i++)
    #pragma unroll
    for (int j = 0; j < 2; j++){
      int n = wn + j * 16 + col;
      float bias = conv_b[g * 64 + n];
      #pragma unroll
      for (int r2 = 0; r2 < 4; r2++){
        int p = p0 + wm + i * 16 + rowb + r2;
        O[(size_t)n * L + p] = fmaxf(acc[i][j][r2] + bias, 0.f);
      }
    }
}

// ---------------- workspace layout: same as round 2/3 ---------------------------
extern "C" void kernel_launch(void* const* d_in, const int* in_sizes, int n_in,
                              void* d_out, int out_size, void* d_ws, size_t ws_size,
                              hipStream_t stream){
  const float* fg     = (const float*)d_in[0];
  const float* mask   = (const float*)d_in[1];
  const float* bgd    = (const float*)d_in[2];
  const float* conv_w = (const float*)d_in[3];
  const float* conv_b = (const float*)d_in[4];

  char* ws = (char*)d_ws;
  unsigned short* Kn     = (unsigned short*)(ws + 0);
  unsigned short* Knt    = Kn;
  unsigned short* FgP    = (unsigned short*)(ws + 37748736);
  unsigned short* Rt     = FgP;
  unsigned short* mbgT   = (unsigned short*)(ws + 75497472);
  float*          scores = (float*)(ws + 75497472);
  unsigned short* finalT = (unsigned short*)scores;
  unsigned short* attn   = (unsigned short*)(ws + 109051904);
  float*          rnorm  = (float*)(ws + 125829120);
  unsigned short* Wr     = (unsigned short*)(ws + 125861888);
  unsigned short* fgT    = (unsigned short*)d_out;
  unsigned short* zpage  = Kn;                 // Knt dead after GEMM2; zeroed by zinit
  float* out = (float*)d_out;

  transpose_pack<<<dim3(16, 4, 8), 256, 0, stream>>>(fg, bgd, mask, fgT, mbgT);
  kn_norm <<<8192, 256, 0, stream>>>(mbgT, Kn, rnorm);
  fgp_pack<<<8192, 256, 0, stream>>>(fgT, FgP);
  wr_prep <<<2304, 256, 0, stream>>>(conv_w, Wr);

  // GEMM1: scores[p][l] = FgP'[p][:] . Kn'[l][:]   (M=N=1024, K=2304, nt=36)
  gemm_bt<0><<<512, 256, 0, stream>>>(FgP, Kn, scores, 2304, 1024, 36, 8, 64,
      (long)1024 * 2304, (long)1024 * 2304, (long)1024 * 1024);

  prop_softmax<<<2048, 256, 0, stream>>>(scores, attn);

  write_knt<<<18432, 256, 0, stream>>>(bgd, mask, rnorm, Knt);

  // GEMM2: Rt[p][q'] = attn[p][:] . Knt'[q'][:]    (M=1024, N=2304, K=1024, nt=16)
  gemm_bt<1><<<1152, 256, 0, stream>>>(attn, Knt, Rt, 1024, 2304, 16, 18, 144,
      (long)1024 * 1024, (long)2304 * 1024, (long)1024 * 2304);

  zinit<<<1, 128, 0, stream>>>(zpage);         // zero page for OOB taps

  fold_final<<<8192, 256, 0, stream>>>(Rt, fgT, mask, finalT);

  branch_gemm<<<512, 256, 0, stream>>>(finalT, Wr, conv_b, zpage, out);
}

// Round 5
// 181.592 us; speedup vs baseline: 2.2256x; 1.2492x over previous
//
#include <hip/hip_runtime.h>

typedef __attribute__((ext_vector_type(8))) short short8;
typedef __attribute__((ext_vector_type(4))) float f32x4;

#define HW 32
#define L 1024        // HW*HW
#define C_IN 256
#define BATCH 8
#define NQ 1156       // 34*34 extended grid

static __device__ __forceinline__ unsigned short f2bf(float f){
  unsigned int u = __float_as_uint(f);
  unsigned int r = (u + 0x7FFFu + ((u >> 16) & 1u)) >> 16;   // RNE (no NaN inputs)
  return (unsigned short)r;
}
static __device__ __forceinline__ float bf2f(unsigned short h){
  return __uint_as_float(((unsigned int)h) << 16);
}

#define GLDS16(g, l) __builtin_amdgcn_global_load_lds(                          \
    (const __attribute__((address_space(1))) void*)(g),                         \
    (__attribute__((address_space(3))) void*)(l), 16, 0, 0)

// ---------------- P0: fgT[b][p][c], mbgT[b][p][c], mbgS[b][c][p] (all bf16) ----
__global__ __launch_bounds__(256) void transpose_pack(const float* __restrict__ fg,
                                                      const float* __restrict__ bgd,
                                                      const float* __restrict__ mask,
                                                      unsigned short* __restrict__ fgT,
                                                      unsigned short* __restrict__ mbgT,
                                                      unsigned short* __restrict__ mbgS){
  __shared__ float T[64][65];
  int p0 = blockIdx.x * 64, c0 = blockIdx.y * 64, b = blockIdx.z;
  int tx = threadIdx.x & 63, ty = threadIdx.x >> 6;
  const float* F = fg  + ((size_t)b * C_IN + c0) * L + p0;
  const float* G = bgd + ((size_t)b * C_IN + c0) * L + p0;
  for (int cc = ty; cc < 64; cc += 4) T[cc][tx] = F[(size_t)cc * L + tx];
  __syncthreads();
  for (int pp = ty; pp < 64; pp += 4)
    fgT[(size_t)(b * L + p0 + pp) * C_IN + c0 + tx] = f2bf(T[tx][pp]);
  __syncthreads();
  float mm = 1.f - mask[p0 + tx];
  for (int cc = ty; cc < 64; cc += 4){
    float v = G[(size_t)cc * L + tx] * mm;
    T[cc][tx] = v;
    mbgS[((size_t)b * C_IN + c0 + cc) * L + p0 + tx] = f2bf(v);
  }
  __syncthreads();
  for (int pp = ty; pp < 64; pp += 4)
    mbgT[(size_t)(b * L + p0 + pp) * C_IN + c0 + tx] = f2bf(T[tx][pp]);
}

// ---------------- P1: rn[b][l] (patch 1/norm) and rsum[b][u] (fg row sums) ------
__global__ __launch_bounds__(256) void rnorm_rsum(const unsigned short* __restrict__ mbgT,
                                                  const unsigned short* __restrict__ fgT,
                                                  float* __restrict__ rn,
                                                  float* __restrict__ rsum){
  int bid = blockIdx.x;                // 8192: b = bid&7 (XCD), u = bid>>3
  int b = bid & 7, u = bid >> 3;
  int uy = u >> 5, ux = u & 31, c = threadIdx.x;
  const unsigned short* M = mbgT + (size_t)b * L * C_IN;
  float fv = bf2f(fgT[((size_t)b * L + u) * C_IN + c]);
  float acc = 0.f;
  #pragma unroll
  for (int s = 0; s < 9; s++){
    int y = uy + s / 3 - 1, x = ux + s % 3 - 1;
    float v = 0.f;
    if ((unsigned)y < HW && (unsigned)x < HW) v = bf2f(M[(size_t)(y * HW + x) * C_IN + c]);
    v += 1e-7f;
    acc += v * v;
  }
  #pragma unroll
  for (int off = 32; off; off >>= 1){ acc += __shfl_xor(acc, off); fv += __shfl_xor(fv, off); }
  __shared__ float ra[4], rb_[4];
  int lane = c & 63, w = c >> 6;
  if (lane == 0){ ra[w] = acc; rb_[w] = fv; }
  __syncthreads();
  if (c == 0){
    rn[b * L + u]   = 1.f / sqrtf(ra[0] + ra[1] + ra[2] + ra[3]);
    rsum[b * L + u] = rb_[0] + rb_[1] + rb_[2] + rb_[3];
  }
}

// ---------------- P4: Wr[g][s][n][c] bf16 ---------------------------------------
__global__ __launch_bounds__(256) void wr_prep(const float* __restrict__ conv_w,
                                               unsigned short* __restrict__ Wr){
  int idx = blockIdx.x * 256 + threadIdx.x;
  int c = idx & 255;
  int rest = idx >> 8;
  int n = rest & 63;
  int sg = rest >> 6;
  int s = sg % 9, g = sg / 9;
  Wr[idx] = f2bf(conv_w[(((size_t)(g * 64 + n)) * C_IN + c) * 9 + s]);
}

__global__ void zinit(unsigned short* z){ z[threadIdx.x] = 0; }

// ---------------- G1: D[b][u][v] = sum_c fgT[u][c]*mbgT[v][c]  (K=256, 1-shot) --
__global__ __launch_bounds__(256) void gemm_d(const unsigned short* __restrict__ fgT,
                                              const unsigned short* __restrict__ mbgT,
                                              float* __restrict__ D){
  __shared__ unsigned short As[64][256];   // 32 KB
  __shared__ unsigned short Bs[64][256];   // 32 KB
  int bid = blockIdx.x;                // 2048 = 8 * 256: b = bid&7 (XCD-affine)
  int b = bid & 7, r = bid >> 3;
  int by = r >> 4, bx = r & 15;
  const unsigned short* Ab = fgT  + ((size_t)b * L + by * 64) * C_IN;
  const unsigned short* Bb = mbgT + ((size_t)b * L + bx * 64) * C_IN;
  int tid = threadIdx.x, lane = tid & 63, wv = tid >> 6;
  int row_off = lane >> 5, slot = lane & 31;
  int q = slot >> 3, sl = slot & 7;
  #pragma unroll
  for (int i = 0; i < 8; i++){
    int rr = wv * 16 + i * 2 + row_off;
    int srcs = q * 8 + (sl ^ (rr & 7));
    GLDS16(Ab + (size_t)rr * C_IN + srcs * 8, &As[wv * 16 + i * 2][0]);
    GLDS16(Bb + (size_t)rr * C_IN + srcs * 8, &Bs[wv * 16 + i * 2][0]);
  }
  __syncthreads();
  int wm = (wv & 1) * 32, wn = (wv >> 1) * 32;
  int rsel = lane & 15, sx = lane >> 4;
  f32x4 acc[2][2] = {};
  #pragma unroll
  for (int st = 0; st < 8; st++){
    int gs = st * 4 + sx, qq = gs >> 3, ss = gs & 7;
    short8 af[2], bf[2];
    #pragma unroll
    for (int i = 0; i < 2; i++){
      int ra = wm + i * 16 + rsel;
      af[i] = *(const short8*)&As[ra][(qq * 8 + (ss ^ (ra & 7))) * 8];
      int rb = wn + i * 16 + rsel;
      bf[i] = *(const short8*)&Bs[rb][(qq * 8 + (ss ^ (rb & 7))) * 8];
    }
    #pragma unroll
    for (int i = 0; i < 2; i++)
      #pragma unroll
      for (int j = 0; j < 2; j++)
        acc[i][j] = __builtin_amdgcn_mfma_f32_16x16x32_bf16(af[i], bf[j], acc[i][j], 0, 0, 0);
  }
  float* Db = D + ((size_t)b << 20);
  int rowb = (lane >> 4) * 4, col = lane & 15;
  #pragma unroll
  for (int i = 0; i < 2; i++)
    #pragma unroll
    for (int j = 0; j < 2; j++)
      #pragma unroll
      for (int r2 = 0; r2 < 4; r2++)
        Db[(size_t)(by * 64 + wm + i * 16 + rowb + r2) * L + bx * 64 + wn + j * 16 + col] = acc[i][j][r2];
}

// ---------------- S1: Rbox[b][q] = 3x3 box of rsum on extended 34x34 grid -------
__global__ __launch_bounds__(256) void rbox_kernel(const float* __restrict__ rsum,
                                                   float* __restrict__ Rbox){
  int idx = blockIdx.x * 256 + threadIdx.x;
  if (idx >= BATCH * NQ) return;
  int b = idx / NQ, q2 = idx - b * NQ;
  int qy = q2 / 34 - 1, qx = q2 % 34 - 1;
  float a = 0.f;
  #pragma unroll
  for (int dy = -1; dy <= 1; dy++)
    #pragma unroll
    for (int dx = -1; dx <= 1; dx++){
      int y = qy + dy, x = qx + dx;
      if ((unsigned)y < HW && (unsigned)x < HW) a += rsum[b * L + y * HW + x];
    }
  Rbox[idx] = a;
}

// ---------------- S2: W[b][q][v] = 3x3 box of D over u, extended q grid ---------
__global__ __launch_bounds__(256) void box3(const float* __restrict__ D,
                                            float* __restrict__ W){
  int bid = blockIdx.x;                // 9248 = 8*1156: b = bid&7
  int b = bid & 7, q2 = bid >> 3;
  int qy = q2 / 34 - 1, qx = q2 % 34 - 1;
  const float* Db = D + ((size_t)b << 20);
  int tid = threadIdx.x;
  float4 a = {0.f, 0.f, 0.f, 0.f};
  #pragma unroll
  for (int dy = -1; dy <= 1; dy++)
    #pragma unroll
    for (int dx = -1; dx <= 1; dx++){
      int y = qy + dy, x = qx + dx;
      if ((unsigned)y < HW && (unsigned)x < HW){
        float4 v = ((const float4*)(Db + ((size_t)(y * HW + x) << 10)))[tid];
        a.x += v.x; a.y += v.y; a.z += v.z; a.w += v.w;
      }
    }
  ((float4*)(W + ((size_t)(b * NQ + q2) << 10)))[tid] = a;
}

// ---------------- S3: diag 9-tap + rn scale + softmax -> AR = bf16(attn*rn) -----
__global__ __launch_bounds__(256) void prop_softmax_diag(const float* __restrict__ W,
                                                         const float* __restrict__ Rbox,
                                                         const float* __restrict__ rn,
                                                         unsigned short* __restrict__ AR){
  int bid = blockIdx.x;                // 8192: b = bid&7
  int b = bid & 7, p = bid >> 3;
  int py = p >> 5, px = p & 31;
  const float* Wb = W + (size_t)b * NQ * L;
  int tid = threadIdx.x, wv = tid >> 6;
  float epsv = 0.f;
  #pragma unroll
  for (int s = 0; s < 9; s++){
    int dy = s / 3 - 1, dx = s % 3 - 1;
    epsv += Rbox[b * NQ + (py + dy + 1) * 34 + (px + dx + 1)];
  }
  epsv *= 1e-7f;
  float val[4], rnl[4];
  #pragma unroll
  for (int j = 0; j < 4; j++){
    int l = j * 256 + tid;
    int ly = l >> 5, lx = l & 31;
    float a = 0.f;
    #pragma unroll
    for (int s = 0; s < 9; s++){
      int dy = s / 3 - 1, dx = s % 3 - 1;
      if ((unsigned)(ly + dy) < HW && (unsigned)(lx + dx) < HW){
        const float* row = Wb + ((size_t)((py + dy + 1) * 34 + (px + dx + 1)) << 10);
        a += row[l + dy * 32 + dx];
      }
    }
    rnl[j] = rn[b * L + l];
    val[j] = rnl[j] * (a + epsv);
  }
  float m = fmaxf(fmaxf(val[0], val[1]), fmaxf(val[2], val[3]));
  #pragma unroll
  for (int off = 32; off; off >>= 1) m = fmaxf(m, __shfl_xor(m, off));
  __shared__ float redm[4], reds[4];
  if ((tid & 63) == 0) redm[wv] = m;
  __syncthreads();
  m = fmaxf(fmaxf(redm[0], redm[1]), fmaxf(redm[2], redm[3]));
  float e[4], t = 0.f;
  #pragma unroll
  for (int j = 0; j < 4; j++){ e[j] = __expf(val[j] - m); t += e[j]; }
  #pragma unroll
  for (int off = 32; off; off >>= 1) t += __shfl_xor(t, off);
  if ((tid & 63) == 0) reds[wv] = t;
  __syncthreads();
  t = reds[0] + reds[1] + reds[2] + reds[3];
  float inv = 1.f / t;
  unsigned short* O = AR + ((size_t)b << 20) + ((size_t)p << 10);
  #pragma unroll
  for (int j = 0; j < 4; j++)
    O[j * 256 + tid] = f2bf(e[j] * inv * rnl[j]);
}

// ---------------- S4: U[p][v] = sum_s gated AR[p+ds][v+ds]  (bf16 out) ----------
__global__ __launch_bounds__(256) void u_stencil(const unsigned short* __restrict__ AR,
                                                 unsigned short* __restrict__ U){
  int bid = blockIdx.x;                // 8192: b = bid&7
  int b = bid & 7, p = bid >> 3;
  int py = p >> 5, px = p & 31;
  int tid = threadIdx.x;
  const unsigned short* A = AR + ((size_t)b << 20);
  float acc[4] = {0.f, 0.f, 0.f, 0.f};
  #pragma unroll
  for (int s = 0; s < 9; s++){
    int dy = s / 3 - 1, dx = s % 3 - 1;
    int py2 = py + dy, px2 = px + dx;
    if ((unsigned)py2 >= HW || (unsigned)px2 >= HW) continue;
    const unsigned short* row = A + ((size_t)(py2 * HW + px2) << 10);
    #pragma unroll
    for (int j = 0; j < 4; j++){
      int v = j * 256 + tid;
      int vy = v >> 5, vx = v & 31;
      if ((unsigned)(vy + dy) < HW && (unsigned)(vx + dx) < HW)
        acc[j] += bf2f(row[v + dy * 32 + dx]);
    }
  }
  unsigned short* O = U + ((size_t)b << 20) + ((size_t)p << 10);
  #pragma unroll
  for (int j = 0; j < 4; j++) O[j * 256 + tid] = f2bf(acc[j]);
}

// ---------------- G2: finalT[p][c] = mask? (U.mbgS)/9 : fgT   (M=1024,N=256,K=1024)
__global__ __launch_bounds__(256) void gemm3_final(const unsigned short* __restrict__ U,
                                                   const unsigned short* __restrict__ mbgS,
                                                   const float* __restrict__ mask,
                                                   const unsigned short* __restrict__ fgT,
                                                   unsigned short* __restrict__ finalT){
  __shared__ unsigned short As[2][64][64];
  __shared__ unsigned short Bs[2][64][64];
  int bid = blockIdx.x;                // 512: b = bid&7
  int b = bid & 7, r = bid >> 3;       // r in [0,64)
  int mt = r >> 2, ct = r & 3;
  int tid = threadIdx.x, lane = tid & 63, wv = tid >> 6;
  int wm = (wv & 1) * 32, wn = (wv >> 1) * 32;
  int rsel = lane & 15;
  int srow = lane >> 3, scol = ((lane & 7) ^ srow) * 8;
  const unsigned short* Ab = U    + ((size_t)b * L + mt * 64) * L;
  const unsigned short* Bb = mbgS + ((size_t)b * C_IN + ct * 64) * L;
  #pragma unroll
  for (int g8 = 0; g8 < 2; g8++){
    GLDS16(Ab + (size_t)(wv * 16 + g8 * 8 + srow) * L + scol, &As[0][wv * 16 + g8 * 8][0]);
    GLDS16(Bb + (size_t)(wv * 16 + g8 * 8 + srow) * L + scol, &Bs[0][wv * 16 + g8 * 8][0]);
  }
  __syncthreads();
  f32x4 acc[2][2] = {};
  int cur = 0;
  for (int t = 0; t < 16; ++t){
    short8 af[2][2], bf[2][2];
    #pragma unroll
    for (int kk = 0; kk < 2; kk++){
      int s0 = kk * 4 + (lane >> 4);
      int col = ((s0 ^ (rsel & 7)) << 3);
      #pragma unroll
      for (int i = 0; i < 2; i++){
        af[kk][i] = *(const short8*)&As[cur][wm + i * 16 + rsel][col];
        bf[kk][i] = *(const short8*)&Bs[cur][wn + i * 16 + rsel][col];
      }
    }
    if (t + 1 < 16){
      int nb = cur ^ 1;
      size_t kt = (size_t)(t + 1) * 64;
      #pragma unroll
      for (int g8 = 0; g8 < 2; g8++){
        GLDS16(Ab + (size_t)(wv * 16 + g8 * 8 + srow) * L + kt + scol, &As[nb][wv * 16 + g8 * 8][0]);
        GLDS16(Bb + (size_t)(wv * 16 + g8 * 8 + srow) * L + kt + scol, &Bs[nb][wv * 16 + g8 * 8][0]);
      }
    }
    #pragma unroll
    for (int kk = 0; kk < 2; kk++)
      #pragma unroll
      for (int i = 0; i < 2; i++)
        #pragma unroll
        for (int j = 0; j < 2; j++)
          acc[i][j] = __builtin_amdgcn_mfma_f32_16x16x32_bf16(af[kk][i], bf[kk][j], acc[i][j], 0, 0, 0);
    __syncthreads();
    cur ^= 1;
  }
  int rowb = (lane >> 4) * 4, col = lane & 15;
  #pragma unroll
  for (int i = 0; i < 2; i++)
    #pragma unroll
    for (int j = 0; j < 2; j++)
      #pragma unroll
      for (int r2 = 0; r2 < 4; r2++){
        int p = mt * 64 + wm + i * 16 + rowb + r2;
        int c = ct * 64 + wn + j * 16 + col;
        unsigned short o;
        if (mask[p] != 0.f) o = f2bf(acc[i][j][r2] * (1.f / 9.f));
        else                o = fgT[((size_t)b * L + p) * C_IN + c];
        finalT[((size_t)b * L + p) * C_IN + c] = o;
      }
}

// ---------------- K4: branch convs as shifted, LDS-staged GEMM (unchanged) ------
__global__ __launch_bounds__(256) void branch_gemm(const unsigned short* __restrict__ finalT,
                                                   const unsigned short* __restrict__ Wr,
                                                   const float* __restrict__ conv_b,
                                                   const unsigned short* __restrict__ zpage,
                                                   float* __restrict__ out){
  __shared__ unsigned short As[2][64][64];
  __shared__ unsigned short Bs[2][64][64];
  int nwg = gridDim.x, bid = blockIdx.x;
  int nid = (bid & 7) * (nwg >> 3) + (bid >> 3);
  int bg = nid >> 4, pt = nid & 15;
  int b = bg >> 2, g = bg & 3;
  int rate = 1 << g;
  int p0 = pt * 64;
  int tid = threadIdx.x, lane = tid & 63, wv = tid >> 6;
  int wm = (wv & 1) * 32, wn = (wv >> 1) * 32;
  int rsel = lane & 15;
  int srow = lane >> 3;
  int scol = ((lane & 7) ^ srow) * 8;
  const unsigned short* FT = finalT + (size_t)b * L * C_IN;
  const unsigned short* WG = Wr + (size_t)(g * 9) * 64 * C_IN;

  int ay[2], ax[2];
  #pragma unroll
  for (int g8 = 0; g8 < 2; g8++){
    int p = p0 + wv * 16 + g8 * 8 + srow;
    ay[g8] = p >> 5; ax[g8] = p & 31;
  }
  auto a_src = [&](int t, int g8) -> const unsigned short* {
    int s = t >> 2, q = t & 3;
    int dy = s / 3 - 1, dx = s - (s / 3) * 3 - 1;
    int iy = ay[g8] + rate * dy, ix = ax[g8] + rate * dx;
    if ((unsigned)iy < HW && (unsigned)ix < HW)
      return FT + (size_t)(iy * HW + ix) * C_IN + q * 64 + scol;
    return zpage;
  };
  auto b_src = [&](int t, int g8) -> const unsigned short* {
    int s = t >> 2, q = t & 3;
    int n = wv * 16 + g8 * 8 + srow;
    return WG + (size_t)(s * 64 + n) * C_IN + q * 64 + scol;
  };

  f32x4 acc[2][2] = {};
  #pragma unroll
  for (int g8 = 0; g8 < 2; g8++){
    GLDS16(a_src(0, g8), &As[0][wv * 16 + g8 * 8][0]);
    GLDS16(b_src(0, g8), &Bs[0][wv * 16 + g8 * 8][0]);
  }
  __syncthreads();
  int cur = 0;
  for (int t = 0; t < 36; ++t){
    short8 af[2][2], bf[2][2];
    #pragma unroll
    for (int kk = 0; kk < 2; kk++){
      int s0 = kk * 4 + (lane >> 4);
      int col = ((s0 ^ (rsel & 7)) << 3);
      #pragma unroll
      for (int i = 0; i < 2; i++){
        af[kk][i] = *(const short8*)&As[cur][wm + i * 16 + rsel][col];
        bf[kk][i] = *(const short8*)&Bs[cur][wn + i * 16 + rsel][col];
      }
    }
    if (t + 1 < 36){
      int nb = cur ^ 1;
      #pragma unroll
      for (int g8 = 0; g8 < 2; g8++){
        GLDS16(a_src(t + 1, g8), &As[nb][wv * 16 + g8 * 8][0]);
        GLDS16(b_src(t + 1, g8), &Bs[nb][wv * 16 + g8 * 8][0]);
      }
    }
    #pragma unroll
    for (int kk = 0; kk < 2; kk++)
      #pragma unroll
      for (int i = 0; i < 2; i++)
        #pragma unroll
        for (int j = 0; j < 2; j++)
          acc[i][j] = __builtin_amdgcn_mfma_f32_16x16x32_bf16(af[kk][i], bf[kk][j], acc[i][j], 0, 0, 0);
    __syncthreads();
    cur ^= 1;
  }
  int rowb = (lane >> 4) * 4, col = lane & 15;
  float* O = out + (size_t)(b * 256 + g * 64) * L;
  #pragma unroll
  for (int i = 0; i < 2; i++)
    #pragma unroll
    for (int j = 0; j < 2; j++){
      int n = wn + j * 16 + col;
      float bias = conv_b[g * 64 + n];
      #pragma unroll
      for (int r2 = 0; r2 < 4; r2++){
        int p = p0 + wm + i * 16 + rowb + r2;
        O[(size_t)n * L + p] = fmaxf(acc[i][j][r2] + bias, 0.f);
      }
    }
}

// ---------------- workspace layout (bytes) --------------------------------------
// [0,         33554432)  : D     (8*1024*1024 f32)
// [33554432,  71434240)  : W_ext (8*1156*1024 f32)
// [71434240,  88211456)  : AR    (8*1024*1024 bf16)
// [88211456, 104988672)  : U     (8*1024*1024 bf16)
// [104988672,109182976)  : mbgT  (8*1024*256 bf16)
// [109182976,113377280)  : mbgS  (8*256*1024 bf16)
// [113377280,117571584)  : finalT(8*1024*256 bf16)
// [117571584,118751232)  : Wr    (4*9*64*256 bf16)
// [118751232,118784000)  : rsum  (8*1024 f32)
// [118784000,118816768)  : rn    (8*1024 f32)
// [118816768,118853760)  : Rbox  (8*1156 f32)
// [118853760,118854272)  : zpage (512 B)
// fgT lives in d_out[0 .. 4.2MB) (d_out only written by branch_gemm at the end)

extern "C" void kernel_launch(void* const* d_in, const int* in_sizes, int n_in,
                              void* d_out, int out_size, void* d_ws, size_t ws_size,
                              hipStream_t stream){
  const float* fg     = (const float*)d_in[0];
  const float* mask   = (const float*)d_in[1];
  const float* bgd    = (const float*)d_in[2];
  const float* conv_w = (const float*)d_in[3];
  const float* conv_b = (const float*)d_in[4];

  char* ws = (char*)d_ws;
  float*          D      = (float*)(ws + 0);
  float*          W      = (float*)(ws + 33554432);
  unsigned short* AR     = (unsigned short*)(ws + 71434240);
  unsigned short* U      = (unsigned short*)(ws + 88211456);
  unsigned short* mbgT   = (unsigned short*)(ws + 104988672);
  unsigned short* mbgS   = (unsigned short*)(ws + 109182976);
  unsigned short* finalT = (unsigned short*)(ws + 113377280);
  unsigned short* Wr     = (unsigned short*)(ws + 117571584);
  float*          rsum   = (float*)(ws + 118751232);
  float*          rn     = (float*)(ws + 118784000);
  float*          Rbox   = (float*)(ws + 118816768);
  unsigned short* zpage  = (unsigned short*)(ws + 118853760);
  unsigned short* fgT    = (unsigned short*)d_out;
  float* out = (float*)d_out;

  transpose_pack<<<dim3(16, 4, 8), 256, 0, stream>>>(fg, bgd, mask, fgT, mbgT, mbgS);
  rnorm_rsum<<<8192, 256, 0, stream>>>(mbgT, fgT, rn, rsum);
  wr_prep<<<2304, 256, 0, stream>>>(conv_w, Wr);
  zinit<<<1, 256, 0, stream>>>(zpage);

  gemm_d<<<2048, 256, 0, stream>>>(fgT, mbgT, D);
  rbox_kernel<<<37, 256, 0, stream>>>(rsum, Rbox);
  box3<<<9248, 256, 0, stream>>>(D, W);
  prop_softmax_diag<<<8192, 256, 0, stream>>>(W, Rbox, rn, AR);
  u_stencil<<<8192, 256, 0, stream>>>(AR, U);
  gemm3_final<<<512, 256, 0, stream>>>(U, mbgS, mask, fgT, finalT);
  branch_gemm<<<512, 256, 0, stream>>>(finalT, Wr, conv_b, zpage, out);
}

// Round 6
// 170.563 us; speedup vs baseline: 2.3695x; 1.0647x over previous
//
#include <hip/hip_runtime.h>

typedef __attribute__((ext_vector_type(8))) short short8;
typedef __attribute__((ext_vector_type(4))) float f32x4;

#define HW 32
#define L 1024        // HW*HW
#define C_IN 256
#define BATCH 8
#define NQ 1156       // 34*34 extended grid

static __device__ __forceinline__ unsigned short f2bf(float f){
  unsigned int u = __float_as_uint(f);
  unsigned int r = (u + 0x7FFFu + ((u >> 16) & 1u)) >> 16;   // RNE (no NaN inputs)
  return (unsigned short)r;
}
static __device__ __forceinline__ float bf2f(unsigned short h){
  return __uint_as_float(((unsigned int)h) << 16);
}

#define GLDS16(g, l) __builtin_amdgcn_global_load_lds(                          \
    (const __attribute__((address_space(1))) void*)(g),                         \
    (__attribute__((address_space(3))) void*)(l), 16, 0, 0)

// ---------------- P0: fgT[b][p][c], mbgT[b][p][c], mbgS[b][c][p] (all bf16) ----
__global__ __launch_bounds__(256) void transpose_pack(const float* __restrict__ fg,
                                                      const float* __restrict__ bgd,
                                                      const float* __restrict__ mask,
                                                      unsigned short* __restrict__ fgT,
                                                      unsigned short* __restrict__ mbgT,
                                                      unsigned short* __restrict__ mbgS){
  __shared__ float T[64][65];
  int p0 = blockIdx.x * 64, c0 = blockIdx.y * 64, b = blockIdx.z;
  int tx = threadIdx.x & 63, ty = threadIdx.x >> 6;
  const float* F = fg  + ((size_t)b * C_IN + c0) * L + p0;
  const float* G = bgd + ((size_t)b * C_IN + c0) * L + p0;
  for (int cc = ty; cc < 64; cc += 4) T[cc][tx] = F[(size_t)cc * L + tx];
  __syncthreads();
  for (int pp = ty; pp < 64; pp += 4)
    fgT[(size_t)(b * L + p0 + pp) * C_IN + c0 + tx] = f2bf(T[tx][pp]);
  __syncthreads();
  float mm = 1.f - mask[p0 + tx];
  for (int cc = ty; cc < 64; cc += 4){
    float v = G[(size_t)cc * L + tx] * mm;
    T[cc][tx] = v;
    mbgS[((size_t)b * C_IN + c0 + cc) * L + p0 + tx] = f2bf(v);
  }
  __syncthreads();
  for (int pp = ty; pp < 64; pp += 4)
    mbgT[(size_t)(b * L + p0 + pp) * C_IN + c0 + tx] = f2bf(T[tx][pp]);
}

// ---------------- P1: per-pixel moments: rsum=sum_c fg, S1m=sum_c mbg, S2m=sum mbg^2
__global__ __launch_bounds__(256) void moments(const unsigned short* __restrict__ fgT,
                                               const unsigned short* __restrict__ mbgT,
                                               float* __restrict__ rsum,
                                               float* __restrict__ S1m,
                                               float* __restrict__ S2m){
  int t = threadIdx.x;
  int pi = t >> 5, l32 = t & 31;
  size_t bp = (size_t)blockIdx.x * 8 + pi;       // flat b*L + p, grid 1024
  short8 fv = *(const short8*)(fgT  + bp * C_IN + l32 * 8);
  short8 mv = *(const short8*)(mbgT + bp * C_IN + l32 * 8);
  float s1f = 0.f, s1m = 0.f, s2m = 0.f;
  #pragma unroll
  for (int j = 0; j < 8; j++){
    float f = bf2f((unsigned short)fv[j]); s1f += f;
    float m = bf2f((unsigned short)mv[j]); s1m += m; s2m += m * m;
  }
  #pragma unroll
  for (int msk = 16; msk; msk >>= 1){
    s1f += __shfl_xor(s1f, msk, 32);
    s1m += __shfl_xor(s1m, msk, 32);
    s2m += __shfl_xor(s2m, msk, 32);
  }
  if (l32 == 0){ rsum[bp] = s1f; S1m[bp] = s1m; S2m[bp] = s2m; }
}

// ---------------- P2: rn[b][l] = 1/sqrt(sum_valid(S2+2e-7*S1) + 2304e-14) -------
__global__ __launch_bounds__(256) void rn_stencil(const float* __restrict__ S1m,
                                                  const float* __restrict__ S2m,
                                                  float* __restrict__ rn){
  int idx = blockIdx.x * 256 + threadIdx.x;      // 8192
  int b = idx >> 10, l = idx & 1023;
  int ly = l >> 5, lx = l & 31;
  float n2 = 2.304e-11f;                         // 2304 * 1e-14
  #pragma unroll
  for (int s = 0; s < 9; s++){
    int y = ly + s / 3 - 1, x = lx + s % 3 - 1;
    if ((unsigned)y < HW && (unsigned)x < HW){
      int q = b * L + y * HW + x;
      n2 += S2m[q] + 2e-7f * S1m[q];
    }
  }
  rn[idx] = 1.f / sqrtf(n2);
}

// ---------------- P4: Wr[g][s][n][c] bf16 (+zpage zero from block 0) ------------
__global__ __launch_bounds__(256) void wr_prep(const float* __restrict__ conv_w,
                                               unsigned short* __restrict__ Wr,
                                               unsigned short* __restrict__ zpage){
  if (blockIdx.x == 0) zpage[threadIdx.x] = 0;   // 512 B zero page
  int idx = blockIdx.x * 256 + threadIdx.x;
  int c = idx & 255;
  int rest = idx >> 8;
  int n = rest & 63;
  int sg = rest >> 6;
  int s = sg % 9, g = sg / 9;
  Wr[idx] = f2bf(conv_w[(((size_t)(g * 64 + n)) * C_IN + c) * 9 + s]);
}

// ---------------- G1: D[b][u][v] = sum_c fgT[u][c]*mbgT[v][c]  (bf16 out) -------
__global__ __launch_bounds__(256) void gemm_d(const unsigned short* __restrict__ fgT,
                                              const unsigned short* __restrict__ mbgT,
                                              unsigned short* __restrict__ D){
  __shared__ unsigned short As[64][256];   // 32 KB
  __shared__ unsigned short Bs[64][256];   // 32 KB
  int bid = blockIdx.x;                // 2048 = 8 * 256: b = bid&7 (XCD-affine)
  int b = bid & 7, r = bid >> 3;
  int by = r >> 4, bx = r & 15;
  const unsigned short* Ab = fgT  + ((size_t)b * L + by * 64) * C_IN;
  const unsigned short* Bb = mbgT + ((size_t)b * L + bx * 64) * C_IN;
  int tid = threadIdx.x, lane = tid & 63, wv = tid >> 6;
  int row_off = lane >> 5, slot = lane & 31;
  int q = slot >> 3, sl = slot & 7;
  #pragma unroll
  for (int i = 0; i < 8; i++){
    int rr = wv * 16 + i * 2 + row_off;
    int srcs = q * 8 + (sl ^ (rr & 7));
    GLDS16(Ab + (size_t)rr * C_IN + srcs * 8, &As[wv * 16 + i * 2][0]);
    GLDS16(Bb + (size_t)rr * C_IN + srcs * 8, &Bs[wv * 16 + i * 2][0]);
  }
  __syncthreads();
  int wm = (wv & 1) * 32, wn = (wv >> 1) * 32;
  int rsel = lane & 15, sx = lane >> 4;
  f32x4 acc[2][2] = {};
  #pragma unroll
  for (int st = 0; st < 8; st++){
    int gs = st * 4 + sx, qq = gs >> 3, ss = gs & 7;
    short8 af[2], bf[2];
    #pragma unroll
    for (int i = 0; i < 2; i++){
      int ra = wm + i * 16 + rsel;
      af[i] = *(const short8*)&As[ra][(qq * 8 + (ss ^ (ra & 7))) * 8];
      int rb = wn + i * 16 + rsel;
      bf[i] = *(const short8*)&Bs[rb][(qq * 8 + (ss ^ (rb & 7))) * 8];
    }
    #pragma unroll
    for (int i = 0; i < 2; i++)
      #pragma unroll
      for (int j = 0; j < 2; j++)
        acc[i][j] = __builtin_amdgcn_mfma_f32_16x16x32_bf16(af[i], bf[j], acc[i][j], 0, 0, 0);
  }
  unsigned short* Db = D + ((size_t)b << 20);
  int rowb = (lane >> 4) * 4, col = lane & 15;
  #pragma unroll
  for (int i = 0; i < 2; i++)
    #pragma unroll
    for (int j = 0; j < 2; j++)
      #pragma unroll
      for (int r2 = 0; r2 < 4; r2++)
        Db[(size_t)(by * 64 + wm + i * 16 + rowb + r2) * L + bx * 64 + wn + j * 16 + col] = f2bf(acc[i][j][r2]);
}

// ---------------- S2: W[b][q][v] = 3x3 box of D over u (bf16 in/out) ------------
__global__ __launch_bounds__(256) void box3(const unsigned short* __restrict__ D,
                                            unsigned short* __restrict__ W){
  int bid = blockIdx.x;                // 9248 = 8*1156: b = bid&7
  int b = bid & 7, q2 = bid >> 3;
  int qy = q2 / 34 - 1, qx = q2 % 34 - 1;
  const unsigned short* Db = D + ((size_t)b << 20);
  int tid = threadIdx.x;
  float a0 = 0.f, a1 = 0.f, a2 = 0.f, a3 = 0.f;
  #pragma unroll
  for (int dy = -1; dy <= 1; dy++)
    #pragma unroll
    for (int dx = -1; dx <= 1; dx++){
      int y = qy + dy, x = qx + dx;
      if ((unsigned)y < HW && (unsigned)x < HW){
        ushort4 v = *(const ushort4*)(Db + ((size_t)(y * HW + x) << 10) + tid * 4);
        a0 += bf2f(v.x); a1 += bf2f(v.y); a2 += bf2f(v.z); a3 += bf2f(v.w);
      }
    }
  ushort4 o;
  o.x = f2bf(a0); o.y = f2bf(a1); o.z = f2bf(a2); o.w = f2bf(a3);
  *(ushort4*)(W + ((size_t)(b * NQ + q2) << 10) + tid * 4) = o;
}

// ---------------- S3: diag 9-tap + tent-eps + rn scale + softmax -> AR ----------
__global__ __launch_bounds__(256) void prop_softmax_diag(const unsigned short* __restrict__ W,
                                                         const float* __restrict__ rsum,
                                                         const float* __restrict__ rn,
                                                         unsigned short* __restrict__ AR){
  int bid = blockIdx.x;                // 8192: b = bid&7
  int b = bid & 7, p = bid >> 3;
  int py = p >> 5, px = p & 31;
  const unsigned short* Wb = W + (size_t)b * NQ * L;
  int tid = threadIdx.x, wv = tid >> 6;
  // epsv = 1e-7 * (5x5 tent ⊛ rsum)(p), tent = conv(3x3 ones, 3x3 ones)
  const float* rs = rsum + b * L;
  float epsv = 0.f;
  const int tw[5] = {1, 2, 3, 2, 1};
  #pragma unroll
  for (int oy = -2; oy <= 2; oy++)
    #pragma unroll
    for (int ox = -2; ox <= 2; ox++){
      int y = py + oy, x = px + ox;
      if ((unsigned)y < HW && (unsigned)x < HW)
        epsv += (float)(tw[oy + 2] * tw[ox + 2]) * rs[y * HW + x];
    }
  epsv *= 1e-7f;
  float val[4], rnl[4];
  #pragma unroll
  for (int j = 0; j < 4; j++){
    int l = j * 256 + tid;
    int ly = l >> 5, lx = l & 31;
    float a = 0.f;
    #pragma unroll
    for (int s = 0; s < 9; s++){
      int dy = s / 3 - 1, dx = s % 3 - 1;
      if ((unsigned)(ly + dy) < HW && (unsigned)(lx + dx) < HW){
        const unsigned short* row = Wb + ((size_t)((py + dy + 1) * 34 + (px + dx + 1)) << 10);
        a += bf2f(row[l + dy * 32 + dx]);
      }
    }
    rnl[j] = rn[b * L + l];
    val[j] = rnl[j] * (a + epsv);
  }
  float m = fmaxf(fmaxf(val[0], val[1]), fmaxf(val[2], val[3]));
  #pragma unroll
  for (int off = 32; off; off >>= 1) m = fmaxf(m, __shfl_xor(m, off));
  __shared__ float redm[4], reds[4];
  if ((tid & 63) == 0) redm[wv] = m;
  __syncthreads();
  m = fmaxf(fmaxf(redm[0], redm[1]), fmaxf(redm[2], redm[3]));
  float e[4], t = 0.f;
  #pragma unroll
  for (int j = 0; j < 4; j++){ e[j] = __expf(val[j] - m); t += e[j]; }
  #pragma unroll
  for (int off = 32; off; off >>= 1) t += __shfl_xor(t, off);
  if ((tid & 63) == 0) reds[wv] = t;
  __syncthreads();
  t = reds[0] + reds[1] + reds[2] + reds[3];
  float inv = 1.f / t;
  unsigned short* O = AR + ((size_t)b << 20) + ((size_t)p << 10);
  #pragma unroll
  for (int j = 0; j < 4; j++)
    O[j * 256 + tid] = f2bf(e[j] * inv * rnl[j]);
}

// ---------------- S4: U[p][v] = sum_s gated AR[p+ds][v+ds]  (bf16 out) ----------
__global__ __launch_bounds__(256) void u_stencil(const unsigned short* __restrict__ AR,
                                                 unsigned short* __restrict__ U){
  int bid = blockIdx.x;                // 8192: b = bid&7
  int b = bid & 7, p = bid >> 3;
  int py = p >> 5, px = p & 31;
  int tid = threadIdx.x;
  const unsigned short* A = AR + ((size_t)b << 20);
  float acc[4] = {0.f, 0.f, 0.f, 0.f};
  #pragma unroll
  for (int s = 0; s < 9; s++){
    int dy = s / 3 - 1, dx = s % 3 - 1;
    int py2 = py + dy, px2 = px + dx;
    if ((unsigned)py2 >= HW || (unsigned)px2 >= HW) continue;
    const unsigned short* row = A + ((size_t)(py2 * HW + px2) << 10);
    #pragma unroll
    for (int j = 0; j < 4; j++){
      int v = j * 256 + tid;
      int vy = v >> 5, vx = v & 31;
      if ((unsigned)(vy + dy) < HW && (unsigned)(vx + dx) < HW)
        acc[j] += bf2f(row[v + dy * 32 + dx]);
    }
  }
  unsigned short* O = U + ((size_t)b << 20) + ((size_t)p << 10);
  #pragma unroll
  for (int j = 0; j < 4; j++) O[j * 256 + tid] = f2bf(acc[j]);
}

// ---------------- G2: finalT[p][c] = mask? (U.mbgS)/9 : fgT ---------------------
__global__ __launch_bounds__(256) void gemm3_final(const unsigned short* __restrict__ U,
                                                   const unsigned short* __restrict__ mbgS,
                                                   const float* __restrict__ mask,
                                                   const unsigned short* __restrict__ fgT,
                                                   unsigned short* __restrict__ finalT){
  __shared__ unsigned short As[2][64][64];
  __shared__ unsigned short Bs[2][64][64];
  int bid = blockIdx.x;                // 512: b = bid&7
  int b = bid & 7, r = bid >> 3;       // r in [0,64)
  int mt = r >> 2, ct = r & 3;
  int tid = threadIdx.x, lane = tid & 63, wv = tid >> 6;
  int wm = (wv & 1) * 32, wn = (wv >> 1) * 32;
  int rsel = lane & 15;
  int srow = lane >> 3, scol = ((lane & 7) ^ srow) * 8;
  const unsigned short* Ab = U    + ((size_t)b * L + mt * 64) * L;
  const unsigned short* Bb = mbgS + ((size_t)b * C_IN + ct * 64) * L;
  #pragma unroll
  for (int g8 = 0; g8 < 2; g8++){
    GLDS16(Ab + (size_t)(wv * 16 + g8 * 8 + srow) * L + scol, &As[0][wv * 16 + g8 * 8][0]);
    GLDS16(Bb + (size_t)(wv * 16 + g8 * 8 + srow) * L + scol, &Bs[0][wv * 16 + g8 * 8][0]);
  }
  __syncthreads();
  f32x4 acc[2][2] = {};
  int cur = 0;
  for (int t = 0; t < 16; ++t){
    short8 af[2][2], bf[2][2];
    #pragma unroll
    for (int kk = 0; kk < 2; kk++){
      int s0 = kk * 4 + (lane >> 4);
      int col = ((s0 ^ (rsel & 7)) << 3);
      #pragma unroll
      for (int i = 0; i < 2; i++){
        af[kk][i] = *(const short8*)&As[cur][wm + i * 16 + rsel][col];
        bf[kk][i] = *(const short8*)&Bs[cur][wn + i * 16 + rsel][col];
      }
    }
    if (t + 1 < 16){
      int nb = cur ^ 1;
      size_t kt = (size_t)(t + 1) * 64;
      #pragma unroll
      for (int g8 = 0; g8 < 2; g8++){
        GLDS16(Ab + (size_t)(wv * 16 + g8 * 8 + srow) * L + kt + scol, &As[nb][wv * 16 + g8 * 8][0]);
        GLDS16(Bb + (size_t)(wv * 16 + g8 * 8 + srow) * L + kt + scol, &Bs[nb][wv * 16 + g8 * 8][0]);
      }
    }
    #pragma unroll
    for (int kk = 0; kk < 2; kk++)
      #pragma unroll
      for (int i = 0; i < 2; i++)
        #pragma unroll
        for (int j = 0; j < 2; j++)
          acc[i][j] = __builtin_amdgcn_mfma_f32_16x16x32_bf16(af[kk][i], bf[kk][j], acc[i][j], 0, 0, 0);
    __syncthreads();
    cur ^= 1;
  }
  int rowb = (lane >> 4) * 4, col = lane & 15;
  #pragma unroll
  for (int i = 0; i < 2; i++)
    #pragma unroll
    for (int j = 0; j < 2; j++)
      #pragma unroll
      for (int r2 = 0; r2 < 4; r2++){
        int p = mt * 64 + wm + i * 16 + rowb + r2;
        int c = ct * 64 + wn + j * 16 + col;
        unsigned short o;
        if (mask[p] != 0.f) o = f2bf(acc[i][j][r2] * (1.f / 9.f));
        else                o = fgT[((size_t)b * L + p) * C_IN + c];
        finalT[((size_t)b * L + p) * C_IN + c] = o;
      }
}

// ---------------- K4: branch convs as shifted, LDS-staged GEMM ------------------
__global__ __launch_bounds__(256) void branch_gemm(const unsigned short* __restrict__ finalT,
                                                   const unsigned short* __restrict__ Wr,
                                                   const float* __restrict__ conv_b,
                                                   const unsigned short* __restrict__ zpage,
                                                   float* __restrict__ out){
  __shared__ unsigned short As[2][64][64];
  __shared__ unsigned short Bs[2][64][64];
  int nwg = gridDim.x, bid = blockIdx.x;
  int nid = (bid & 7) * (nwg >> 3) + (bid >> 3);
  int bg = nid >> 4, pt = nid & 15;
  int b = bg >> 2, g = bg & 3;
  int rate = 1 << g;
  int p0 = pt * 64;
  int tid = threadIdx.x, lane = tid & 63, wv = tid >> 6;
  int wm = (wv & 1) * 32, wn = (wv >> 1) * 32;
  int rsel = lane & 15;
  int srow = lane >> 3;
  int scol = ((lane & 7) ^ srow) * 8;
  const unsigned short* FT = finalT + (size_t)b * L * C_IN;
  const unsigned short* WG = Wr + (size_t)(g * 9) * 64 * C_IN;

  int ay[2], ax[2];
  #pragma unroll
  for (int g8 = 0; g8 < 2; g8++){
    int p = p0 + wv * 16 + g8 * 8 + srow;
    ay[g8] = p >> 5; ax[g8] = p & 31;
  }
  auto a_src = [&](int t, int g8) -> const unsigned short* {
    int s = t >> 2, q = t & 3;
    int dy = s / 3 - 1, dx = s - (s / 3) * 3 - 1;
    int iy = ay[g8] + rate * dy, ix = ax[g8] + rate * dx;
    if ((unsigned)iy < HW && (unsigned)ix < HW)
      return FT + (size_t)(iy * HW + ix) * C_IN + q * 64 + scol;
    return zpage;
  };
  auto b_src = [&](int t, int g8) -> const unsigned short* {
    int s = t >> 2, q = t & 3;
    int n = wv * 16 + g8 * 8 + srow;
    return WG + (size_t)(s * 64 + n) * C_IN + q * 64 + scol;
  };

  f32x4 acc[2][2] = {};
  #pragma unroll
  for (int g8 = 0; g8 < 2; g8++){
    GLDS16(a_src(0, g8), &As[0][wv * 16 + g8 * 8][0]);
    GLDS16(b_src(0, g8), &Bs[0][wv * 16 + g8 * 8][0]);
  }
  __syncthreads();
  int cur = 0;
  for (int t = 0; t < 36; ++t){
    short8 af[2][2], bf[2][2];
    #pragma unroll
    for (int kk = 0; kk < 2; kk++){
      int s0 = kk * 4 + (lane >> 4);
      int col = ((s0 ^ (rsel & 7)) << 3);
      #pragma unroll
      for (int i = 0; i < 2; i++){
        af[kk][i] = *(const short8*)&As[cur][wm + i * 16 + rsel][col];
        bf[kk][i] = *(const short8*)&Bs[cur][wn + i * 16 + rsel][col];
      }
    }
    if (t + 1 < 36){
      int nb = cur ^ 1;
      #pragma unroll
      for (int g8 = 0; g8 < 2; g8++){
        GLDS16(a_src(t + 1, g8), &As[nb][wv * 16 + g8 * 8][0]);
        GLDS16(b_src(t + 1, g8), &Bs[nb][wv * 16 + g8 * 8][0]);
      }
    }
    #pragma unroll
    for (int kk = 0; kk < 2; kk++)
      #pragma unroll
      for (int i = 0; i < 2; i++)
        #pragma unroll
        for (int j = 0; j < 2; j++)
          acc[i][j] = __builtin_amdgcn_mfma_f32_16x16x32_bf16(af[kk][i], bf[kk][j], acc[i][j], 0, 0, 0);
    __syncthreads();
    cur ^= 1;
  }
  int rowb = (lane >> 4) * 4, col = lane & 15;
  float* O = out + (size_t)(b * 256 + g * 64) * L;
  #pragma unroll
  for (int i = 0; i < 2; i++)
    #pragma unroll
    for (int j = 0; j < 2; j++){
      int n = wn + j * 16 + col;
      float bias = conv_b[g * 64 + n];
      #pragma unroll
      for (int r2 = 0; r2 < 4; r2++){
        int p = p0 + wm + i * 16 + rowb + r2;
        O[(size_t)n * L + p] = fmaxf(acc[i][j][r2] + bias, 0.f);
      }
    }
}

// ---------------- workspace layout (bytes) --------------------------------------
// [0,        16777216) : D    (8*1024*1024 bf16)
// [16777216, 35717120) : W    (8*1156*1024 bf16)
// [35717120, 52494336) : AR   (8*1024*1024 bf16)
// [52494336, 69271552) : U    (8*1024*1024 bf16)
// [69271552, 73465856) : mbgT (8*1024*256 bf16)
// [73465856, 77660160) : mbgS (8*256*1024 bf16)
// [77660160, 81854464) : finalT (8*1024*256 bf16)
// [81854464, 83034112) : Wr   (4*9*64*256 bf16)
// [83034112, 83066880) : rsum (8*1024 f32)
// [83066880, 83099648) : S1m  (8*1024 f32)
// [83099648, 83132416) : S2m  (8*1024 f32)
// [83132416, 83165184) : rn   (8*1024 f32)
// [83165184, 83165696) : zpage (512 B)
// fgT lives in d_out[0 .. 4.2MB) (d_out only written by branch_gemm at the end)

extern "C" void kernel_launch(void* const* d_in, const int* in_sizes, int n_in,
                              void* d_out, int out_size, void* d_ws, size_t ws_size,
                              hipStream_t stream){
  const float* fg     = (const float*)d_in[0];
  const float* mask   = (const float*)d_in[1];
  const float* bgd    = (const float*)d_in[2];
  const float* conv_w = (const float*)d_in[3];
  const float* conv_b = (const float*)d_in[4];

  char* ws = (char*)d_ws;
  unsigned short* D      = (unsigned short*)(ws + 0);
  unsigned short* W      = (unsigned short*)(ws + 16777216);
  unsigned short* AR     = (unsigned short*)(ws + 35717120);
  unsigned short* U      = (unsigned short*)(ws + 52494336);
  unsigned short* mbgT   = (unsigned short*)(ws + 69271552);
  unsigned short* mbgS   = (unsigned short*)(ws + 73465856);
  unsigned short* finalT = (unsigned short*)(ws + 77660160);
  unsigned short* Wr     = (unsigned short*)(ws + 81854464);
  float*          rsum   = (float*)(ws + 83034112);
  float*          S1m    = (float*)(ws + 83066880);
  float*          S2m    = (float*)(ws + 83099648);
  float*          rn     = (float*)(ws + 83132416);
  unsigned short* zpage  = (unsigned short*)(ws + 83165184);
  unsigned short* fgT    = (unsigned short*)d_out;
  float* out = (float*)d_out;

  transpose_pack<<<dim3(16, 4, 8), 256, 0, stream>>>(fg, bgd, mask, fgT, mbgT, mbgS);
  moments<<<1024, 256, 0, stream>>>(fgT, mbgT, rsum, S1m, S2m);
  rn_stencil<<<32, 256, 0, stream>>>(S1m, S2m, rn);
  wr_prep<<<2304, 256, 0, stream>>>(conv_w, Wr, zpage);

  gemm_d<<<2048, 256, 0, stream>>>(fgT, mbgT, D);
  box3<<<9248, 256, 0, stream>>>(D, W);
  prop_softmax_diag<<<8192, 256, 0, stream>>>(W, rsum, rn, AR);
  u_stencil<<<8192, 256, 0, stream>>>(AR, U);
  gemm3_final<<<512, 256, 0, stream>>>(U, mbgS, mask, fgT, finalT);
  branch_gemm<<<512, 256, 0, stream>>>(finalT, Wr, conv_b, zpage, out);
}

// Round 7
// 123.964 us; speedup vs baseline: 3.2602x; 1.3759x over previous
//
#include <hip/hip_runtime.h>

typedef __attribute__((ext_vector_type(8))) short short8;
typedef __attribute__((ext_vector_type(4))) float f32x4;

#define HW 32
#define L 1024        // HW*HW
#define C_IN 256
#define BATCH 8
#define NQ 1156       // 34*34 extended grid

static __device__ __forceinline__ unsigned short f2bf(float f){
  unsigned int u = __float_as_uint(f);
  unsigned int r = (u + 0x7FFFu + ((u >> 16) & 1u)) >> 16;   // RNE (no NaN inputs)
  return (unsigned short)r;
}
static __device__ __forceinline__ float bf2f(unsigned short h){
  return __uint_as_float(((unsigned int)h) << 16);
}

#define GLDS16(g, l) __builtin_amdgcn_global_load_lds(                          \
    (const __attribute__((address_space(1))) void*)(g),                         \
    (__attribute__((address_space(3))) void*)(l), 16, 0, 0)

// ---------------- P0: fgT[b][p][c], mbgT[b][p][c], mbgS[b][c][p] (all bf16) ----
__global__ __launch_bounds__(256) void transpose_pack(const float* __restrict__ fg,
                                                      const float* __restrict__ bgd,
                                                      const float* __restrict__ mask,
                                                      unsigned short* __restrict__ fgT,
                                                      unsigned short* __restrict__ mbgT,
                                                      unsigned short* __restrict__ mbgS){
  __shared__ float T[64][65];
  int p0 = blockIdx.x * 64, c0 = blockIdx.y * 64, b = blockIdx.z;
  int tx = threadIdx.x & 63, ty = threadIdx.x >> 6;
  const float* F = fg  + ((size_t)b * C_IN + c0) * L + p0;
  const float* G = bgd + ((size_t)b * C_IN + c0) * L + p0;
  for (int cc = ty; cc < 64; cc += 4) T[cc][tx] = F[(size_t)cc * L + tx];
  __syncthreads();
  for (int pp = ty; pp < 64; pp += 4)
    fgT[(size_t)(b * L + p0 + pp) * C_IN + c0 + tx] = f2bf(T[tx][pp]);
  __syncthreads();
  float mm = 1.f - mask[p0 + tx];
  for (int cc = ty; cc < 64; cc += 4){
    float v = G[(size_t)cc * L + tx] * mm;
    T[cc][tx] = v;
    mbgS[((size_t)b * C_IN + c0 + cc) * L + p0 + tx] = f2bf(v);
  }
  __syncthreads();
  for (int pp = ty; pp < 64; pp += 4)
    mbgT[(size_t)(b * L + p0 + pp) * C_IN + c0 + tx] = f2bf(T[tx][pp]);
}

// ---------------- P1: per-pixel moments: rsum=sum_c fg, S1m=sum_c mbg, S2m=sum mbg^2
__global__ __launch_bounds__(256) void moments(const unsigned short* __restrict__ fgT,
                                               const unsigned short* __restrict__ mbgT,
                                               float* __restrict__ rsum,
                                               float* __restrict__ S1m,
                                               float* __restrict__ S2m){
  int t = threadIdx.x;
  int pi = t >> 5, l32 = t & 31;
  size_t bp = (size_t)blockIdx.x * 8 + pi;       // flat b*L + p, grid 1024
  short8 fv = *(const short8*)(fgT  + bp * C_IN + l32 * 8);
  short8 mv = *(const short8*)(mbgT + bp * C_IN + l32 * 8);
  float s1f = 0.f, s1m = 0.f, s2m = 0.f;
  #pragma unroll
  for (int j = 0; j < 8; j++){
    float f = bf2f((unsigned short)fv[j]); s1f += f;
    float m = bf2f((unsigned short)mv[j]); s1m += m; s2m += m * m;
  }
  #pragma unroll
  for (int msk = 16; msk; msk >>= 1){
    s1f += __shfl_xor(s1f, msk, 32);
    s1m += __shfl_xor(s1m, msk, 32);
    s2m += __shfl_xor(s2m, msk, 32);
  }
  if (l32 == 0){ rsum[bp] = s1f; S1m[bp] = s1m; S2m[bp] = s2m; }
}

// ---------------- P2: rn = 1/||patch||, eps = 1e-7*(5x5 tent ⊛ rsum) ------------
__global__ __launch_bounds__(256) void rn_eps(const float* __restrict__ S1m,
                                              const float* __restrict__ S2m,
                                              const float* __restrict__ rsum,
                                              float* __restrict__ rn,
                                              float* __restrict__ eps){
  int idx = blockIdx.x * 256 + threadIdx.x;      // 8192
  int b = idx >> 10, l = idx & 1023;
  int ly = l >> 5, lx = l & 31;
  float n2 = 2.304e-11f;                         // 2304 * 1e-14
  #pragma unroll
  for (int s = 0; s < 9; s++){
    int y = ly + s / 3 - 1, x = lx + s % 3 - 1;
    if ((unsigned)y < HW && (unsigned)x < HW){
      int q = b * L + y * HW + x;
      n2 += S2m[q] + 2e-7f * S1m[q];
    }
  }
  rn[idx] = 1.f / sqrtf(n2);
  const float* rs = rsum + b * L;
  float ev = 0.f;
  const int tw[5] = {1, 2, 3, 2, 1};
  #pragma unroll
  for (int oy = -2; oy <= 2; oy++)
    #pragma unroll
    for (int ox = -2; ox <= 2; ox++){
      int y = ly + oy, x = lx + ox;
      if ((unsigned)y < HW && (unsigned)x < HW)
        ev += (float)(tw[oy + 2] * tw[ox + 2]) * rs[y * HW + x];
    }
  eps[idx] = 1e-7f * ev;
}

// ---------------- P4: Wr[g][s][n][c] bf16 (+zpage zero from block 0) ------------
__global__ __launch_bounds__(256) void wr_prep(const float* __restrict__ conv_w,
                                               unsigned short* __restrict__ Wr,
                                               unsigned short* __restrict__ zpage){
  if (blockIdx.x == 0) zpage[threadIdx.x] = 0;   // 512 B zero page
  int idx = blockIdx.x * 256 + threadIdx.x;
  int c = idx & 255;
  int rest = idx >> 8;
  int n = rest & 63;
  int sg = rest >> 6;
  int s = sg % 9, g = sg / 9;
  Wr[idx] = f2bf(conv_w[(((size_t)(g * 64 + n)) * C_IN + c) * 9 + s]);
}

// ---------------- G1: D[b][u][v] = sum_c fgT[u][c]*mbgT[v][c]  (bf16 out) -------
__global__ __launch_bounds__(256) void gemm_d(const unsigned short* __restrict__ fgT,
                                              const unsigned short* __restrict__ mbgT,
                                              unsigned short* __restrict__ D){
  __shared__ unsigned short As[64][256];   // 32 KB
  __shared__ unsigned short Bs[64][256];   // 32 KB
  int bid = blockIdx.x;                // 2048 = 8 * 256: b = bid&7 (XCD-affine)
  int b = bid & 7, r = bid >> 3;
  int by = r >> 4, bx = r & 15;
  const unsigned short* Ab = fgT  + ((size_t)b * L + by * 64) * C_IN;
  const unsigned short* Bb = mbgT + ((size_t)b * L + bx * 64) * C_IN;
  int tid = threadIdx.x, lane = tid & 63, wv = tid >> 6;
  int row_off = lane >> 5, slot = lane & 31;
  int q = slot >> 3, sl = slot & 7;
  #pragma unroll
  for (int i = 0; i < 8; i++){
    int rr = wv * 16 + i * 2 + row_off;
    int srcs = q * 8 + (sl ^ (rr & 7));
    GLDS16(Ab + (size_t)rr * C_IN + srcs * 8, &As[wv * 16 + i * 2][0]);
    GLDS16(Bb + (size_t)rr * C_IN + srcs * 8, &Bs[wv * 16 + i * 2][0]);
  }
  __syncthreads();
  int wm = (wv & 1) * 32, wn = (wv >> 1) * 32;
  int rsel = lane & 15, sx = lane >> 4;
  f32x4 acc[2][2] = {};
  #pragma unroll
  for (int st = 0; st < 8; st++){
    int gs = st * 4 + sx, qq = gs >> 3, ss = gs & 7;
    short8 af[2], bf[2];
    #pragma unroll
    for (int i = 0; i < 2; i++){
      int ra = wm + i * 16 + rsel;
      af[i] = *(const short8*)&As[ra][(qq * 8 + (ss ^ (ra & 7))) * 8];
      int rb = wn + i * 16 + rsel;
      bf[i] = *(const short8*)&Bs[rb][(qq * 8 + (ss ^ (rb & 7))) * 8];
    }
    #pragma unroll
    for (int i = 0; i < 2; i++)
      #pragma unroll
      for (int j = 0; j < 2; j++)
        acc[i][j] = __builtin_amdgcn_mfma_f32_16x16x32_bf16(af[i], bf[j], acc[i][j], 0, 0, 0);
  }
  unsigned short* Db = D + ((size_t)b << 20);
  int rowb = (lane >> 4) * 4, col = lane & 15;
  #pragma unroll
  for (int i = 0; i < 2; i++)
    #pragma unroll
    for (int j = 0; j < 2; j++)
      #pragma unroll
      for (int r2 = 0; r2 < 4; r2++)
        Db[(size_t)(by * 64 + wm + i * 16 + rowb + r2) * L + bx * 64 + wn + j * 16 + col] = f2bf(acc[i][j][r2]);
}

// ---------------- S2: W[b][q][v] = 3x3 box of D over u (bf16 in/out) ------------
__global__ __launch_bounds__(256) void box3(const unsigned short* __restrict__ D,
                                            unsigned short* __restrict__ W){
  int bid = blockIdx.x;                // 9248 = 8*1156: b = bid&7
  int b = bid & 7, q2 = bid >> 3;
  int qy = q2 / 34 - 1, qx = q2 % 34 - 1;
  const unsigned short* Db = D + ((size_t)b << 20);
  int tid = threadIdx.x;
  float a0 = 0.f, a1 = 0.f, a2 = 0.f, a3 = 0.f;
  #pragma unroll
  for (int dy = -1; dy <= 1; dy++)
    #pragma unroll
    for (int dx = -1; dx <= 1; dx++){
      int y = qy + dy, x = qx + dx;
      if ((unsigned)y < HW && (unsigned)x < HW){
        ushort4 v = *(const ushort4*)(Db + ((size_t)(y * HW + x) << 10) + tid * 4);
        a0 += bf2f(v.x); a1 += bf2f(v.y); a2 += bf2f(v.z); a3 += bf2f(v.w);
      }
    }
  ushort4 o;
  o.x = f2bf(a0); o.y = f2bf(a1); o.z = f2bf(a2); o.w = f2bf(a3);
  *(ushort4*)(W + ((size_t)(b * NQ + q2) << 10) + tid * 4) = o;
}

// ---------------- S3: diag 9-tap via LDS-staged W rows + softmax -> AR ----------
__global__ __launch_bounds__(256) void prop_softmax_diag(const unsigned short* __restrict__ W,
                                                         const float* __restrict__ eps,
                                                         const float* __restrict__ rn,
                                                         unsigned short* __restrict__ AR){
  __shared__ unsigned short Wl[9][1024];   // 18 KB
  __shared__ float redm[4], reds[4];
  int bid = blockIdx.x;                // 8192: b = bid&7
  int b = bid & 7, p = bid >> 3;
  int py = p >> 5, px = p & 31;
  const unsigned short* Wb = W + (size_t)b * NQ * L;
  int tid = threadIdx.x, lane = tid & 63, wv = tid >> 6;
  // stage 9 rows (all q in [0,34)^2, always valid) : 18 wave-units of 1KB
  #pragma unroll
  for (int k = 0; k < 5; k++){
    int u = k * 4 + wv;
    if (u < 18){
      int s = u >> 1, half = u & 1;
      int qs = (py + s / 3) * 34 + (px + s % 3);
      GLDS16(Wb + (((size_t)qs) << 10) + half * 512 + lane * 8, &Wl[s][half * 512]);
    }
  }
  float epsv = eps[b * L + p];           // block-uniform scalar
  __syncthreads();
  float val[4], rnl[4];
  #pragma unroll
  for (int j = 0; j < 4; j++){
    int l = j * 256 + tid;
    int ly = l >> 5, lx = l & 31;
    float a = 0.f;
    #pragma unroll
    for (int s = 0; s < 9; s++){
      int dy = s / 3 - 1, dx = s % 3 - 1;
      bool ok = ((unsigned)(ly + dy) < HW) && ((unsigned)(lx + dx) < HW);
      unsigned short uv = Wl[s][(l + dy * 32 + dx) & 1023];   // unconditional ds_read
      float fv = __uint_as_float(((unsigned)uv) << 16);
      a += ok ? fv : 0.f;
    }
    rnl[j] = rn[b * L + l];
    val[j] = rnl[j] * (a + epsv);
  }
  float m = fmaxf(fmaxf(val[0], val[1]), fmaxf(val[2], val[3]));
  #pragma unroll
  for (int off = 32; off; off >>= 1) m = fmaxf(m, __shfl_xor(m, off));
  if (lane == 0) redm[wv] = m;
  __syncthreads();
  m = fmaxf(fmaxf(redm[0], redm[1]), fmaxf(redm[2], redm[3]));
  float e[4], t = 0.f;
  #pragma unroll
  for (int j = 0; j < 4; j++){ e[j] = __expf(val[j] - m); t += e[j]; }
  #pragma unroll
  for (int off = 32; off; off >>= 1) t += __shfl_xor(t, off);
  if (lane == 0) reds[wv] = t;
  __syncthreads();
  t = reds[0] + reds[1] + reds[2] + reds[3];
  float inv = 1.f / t;
  unsigned short* O = AR + ((size_t)b << 20) + ((size_t)p << 10);
  #pragma unroll
  for (int j = 0; j < 4; j++)
    O[j * 256 + tid] = f2bf(e[j] * inv * rnl[j]);
}

// ---------------- S4: U[p][v] = sum_s gated AR[p+ds][v+ds] via LDS staging ------
__global__ __launch_bounds__(256) void u_stencil(const unsigned short* __restrict__ AR,
                                                 unsigned short* __restrict__ U){
  __shared__ unsigned short Al[9][1024];   // 18 KB
  int bid = blockIdx.x;                // 8192: b = bid&7
  int b = bid & 7, p = bid >> 3;
  int py = p >> 5, px = p & 31;
  int tid = threadIdx.x, lane = tid & 63, wv = tid >> 6;
  const unsigned short* A = AR + ((size_t)b << 20);
  // stage 9 rows; invalid rows staged from row 0 (clamped) and masked at read
  #pragma unroll
  for (int k = 0; k < 5; k++){
    int u = k * 4 + wv;
    if (u < 18){
      int s = u >> 1, half = u & 1;
      int yy = py + s / 3 - 1, xx = px + s % 3 - 1;
      bool rok = ((unsigned)yy < HW) && ((unsigned)xx < HW);
      int p2 = rok ? (yy * HW + xx) : 0;
      GLDS16(A + (((size_t)p2) << 10) + half * 512 + lane * 8, &Al[s][half * 512]);
    }
  }
  int rowmask = 0;
  #pragma unroll
  for (int s = 0; s < 9; s++){
    int yy = py + s / 3 - 1, xx = px + s % 3 - 1;
    if (((unsigned)yy < HW) && ((unsigned)xx < HW)) rowmask |= 1 << s;
  }
  __syncthreads();
  float acc[4] = {0.f, 0.f, 0.f, 0.f};
  #pragma unroll
  for (int s = 0; s < 9; s++){
    int dy = s / 3 - 1, dx = s % 3 - 1;
    bool rok = (rowmask >> s) & 1;
    #pragma unroll
    for (int j = 0; j < 4; j++){
      int v = j * 256 + tid;
      int vy = v >> 5, vx = v & 31;
      bool ok = rok && ((unsigned)(vy + dy) < HW) && ((unsigned)(vx + dx) < HW);
      unsigned short uv = Al[s][(v + dy * 32 + dx) & 1023];
      float fv = __uint_as_float(((unsigned)uv) << 16);
      acc[j] += ok ? fv : 0.f;
    }
  }
  unsigned short* O = U + ((size_t)b << 20) + ((size_t)p << 10);
  #pragma unroll
  for (int j = 0; j < 4; j++) O[j * 256 + tid] = f2bf(acc[j]);
}

// ---------------- G2: finalT[p][c] = mask? (U.mbgS)/9 : fgT ---------------------
__global__ __launch_bounds__(256) void gemm3_final(const unsigned short* __restrict__ U,
                                                   const unsigned short* __restrict__ mbgS,
                                                   const float* __restrict__ mask,
                                                   const unsigned short* __restrict__ fgT,
                                                   unsigned short* __restrict__ finalT){
  __shared__ unsigned short As[2][64][64];
  __shared__ unsigned short Bs[2][64][64];
  int bid = blockIdx.x;                // 512: b = bid&7
  int b = bid & 7, r = bid >> 3;       // r in [0,64)
  int mt = r >> 2, ct = r & 3;
  int tid = threadIdx.x, lane = tid & 63, wv = tid >> 6;
  int wm = (wv & 1) * 32, wn = (wv >> 1) * 32;
  int rsel = lane & 15;
  int srow = lane >> 3, scol = ((lane & 7) ^ srow) * 8;
  const unsigned short* Ab = U    + ((size_t)b * L + mt * 64) * L;
  const unsigned short* Bb = mbgS + ((size_t)b * C_IN + ct * 64) * L;
  #pragma unroll
  for (int g8 = 0; g8 < 2; g8++){
    GLDS16(Ab + (size_t)(wv * 16 + g8 * 8 + srow) * L + scol, &As[0][wv * 16 + g8 * 8][0]);
    GLDS16(Bb + (size_t)(wv * 16 + g8 * 8 + srow) * L + scol, &Bs[0][wv * 16 + g8 * 8][0]);
  }
  __syncthreads();
  f32x4 acc[2][2] = {};
  int cur = 0;
  for (int t = 0; t < 16; ++t){
    short8 af[2][2], bf[2][2];
    #pragma unroll
    for (int kk = 0; kk < 2; kk++){
      int s0 = kk * 4 + (lane >> 4);
      int col = ((s0 ^ (rsel & 7)) << 3);
      #pragma unroll
      for (int i = 0; i < 2; i++){
        af[kk][i] = *(const short8*)&As[cur][wm + i * 16 + rsel][col];
        bf[kk][i] = *(const short8*)&Bs[cur][wn + i * 16 + rsel][col];
      }
    }
    if (t + 1 < 16){
      int nb = cur ^ 1;
      size_t kt = (size_t)(t + 1) * 64;
      #pragma unroll
      for (int g8 = 0; g8 < 2; g8++){
        GLDS16(Ab + (size_t)(wv * 16 + g8 * 8 + srow) * L + kt + scol, &As[nb][wv * 16 + g8 * 8][0]);
        GLDS16(Bb + (size_t)(wv * 16 + g8 * 8 + srow) * L + kt + scol, &Bs[nb][wv * 16 + g8 * 8][0]);
      }
    }
    #pragma unroll
    for (int kk = 0; kk < 2; kk++)
      #pragma unroll
      for (int i = 0; i < 2; i++)
        #pragma unroll
        for (int j = 0; j < 2; j++)
          acc[i][j] = __builtin_amdgcn_mfma_f32_16x16x32_bf16(af[kk][i], bf[kk][j], acc[i][j], 0, 0, 0);
    __syncthreads();
    cur ^= 1;
  }
  int rowb = (lane >> 4) * 4, col = lane & 15;
  #pragma unroll
  for (int i = 0; i < 2; i++)
    #pragma unroll
    for (int j = 0; j < 2; j++)
      #pragma unroll
      for (int r2 = 0; r2 < 4; r2++){
        int p = mt * 64 + wm + i * 16 + rowb + r2;
        int c = ct * 64 + wn + j * 16 + col;
        unsigned short o;
        if (mask[p] != 0.f) o = f2bf(acc[i][j][r2] * (1.f / 9.f));
        else                o = fgT[((size_t)b * L + p) * C_IN + c];
        finalT[((size_t)b * L + p) * C_IN + c] = o;
      }
}

// ---------------- K4: branch convs as shifted, LDS-staged GEMM ------------------
__global__ __launch_bounds__(256) void branch_gemm(const unsigned short* __restrict__ finalT,
                                                   const unsigned short* __restrict__ Wr,
                                                   const float* __restrict__ conv_b,
                                                   const unsigned short* __restrict__ zpage,
                                                   float* __restrict__ out){
  __shared__ unsigned short As[2][64][64];
  __shared__ unsigned short Bs[2][64][64];
  int nwg = gridDim.x, bid = blockIdx.x;
  int nid = (bid & 7) * (nwg >> 3) + (bid >> 3);
  int bg = nid >> 4, pt = nid & 15;
  int b = bg >> 2, g = bg & 3;
  int rate = 1 << g;
  int p0 = pt * 64;
  int tid = threadIdx.x, lane = tid & 63, wv = tid >> 6;
  int wm = (wv & 1) * 32, wn = (wv >> 1) * 32;
  int rsel = lane & 15;
  int srow = lane >> 3;
  int scol = ((lane & 7) ^ srow) * 8;
  const unsigned short* FT = finalT + (size_t)b * L * C_IN;
  const unsigned short* WG = Wr + (size_t)(g * 9) * 64 * C_IN;

  int ay[2], ax[2];
  #pragma unroll
  for (int g8 = 0; g8 < 2; g8++){
    int p = p0 + wv * 16 + g8 * 8 + srow;
    ay[g8] = p >> 5; ax[g8] = p & 31;
  }
  auto a_src = [&](int t, int g8) -> const unsigned short* {
    int s = t >> 2, q = t & 3;
    int dy = s / 3 - 1, dx = s - (s / 3) * 3 - 1;
    int iy = ay[g8] + rate * dy, ix = ax[g8] + rate * dx;
    if ((unsigned)iy < HW && (unsigned)ix < HW)
      return FT + (size_t)(iy * HW + ix) * C_IN + q * 64 + scol;
    return zpage;
  };
  auto b_src = [&](int t, int g8) -> const unsigned short* {
    int s = t >> 2, q = t & 3;
    int n = wv * 16 + g8 * 8 + srow;
    return WG + (size_t)(s * 64 + n) * C_IN + q * 64 + scol;
  };

  f32x4 acc[2][2] = {};
  #pragma unroll
  for (int g8 = 0; g8 < 2; g8++){
    GLDS16(a_src(0, g8), &As[0][wv * 16 + g8 * 8][0]);
    GLDS16(b_src(0, g8), &Bs[0][wv * 16 + g8 * 8][0]);
  }
  __syncthreads();
  int cur = 0;
  for (int t = 0; t < 36; ++t){
    short8 af[2][2], bf[2][2];
    #pragma unroll
    for (int kk = 0; kk < 2; kk++){
      int s0 = kk * 4 + (lane >> 4);
      int col = ((s0 ^ (rsel & 7)) << 3);
      #pragma unroll
      for (int i = 0; i < 2; i++){
        af[kk][i] = *(const short8*)&As[cur][wm + i * 16 + rsel][col];
        bf[kk][i] = *(const short8*)&Bs[cur][wn + i * 16 + rsel][col];
      }
    }
    if (t + 1 < 36){
      int nb = cur ^ 1;
      #pragma unroll
      for (int g8 = 0; g8 < 2; g8++){
        GLDS16(a_src(t + 1, g8), &As[nb][wv * 16 + g8 * 8][0]);
        GLDS16(b_src(t + 1, g8), &Bs[nb][wv * 16 + g8 * 8][0]);
      }
    }
    #pragma unroll
    for (int kk = 0; kk < 2; kk++)
      #pragma unroll
      for (int i = 0; i < 2; i++)
        #pragma unroll
        for (int j = 0; j < 2; j++)
          acc[i][j] = __builtin_amdgcn_mfma_f32_16x16x32_bf16(af[kk][i], bf[kk][j], acc[i][j], 0, 0, 0);
    __syncthreads();
    cur ^= 1;
  }
  int rowb = (lane >> 4) * 4, col = lane & 15;
  float* O = out + (size_t)(b * 256 + g * 64) * L;
  #pragma unroll
  for (int i = 0; i < 2; i++)
    #pragma unroll
    for (int j = 0; j < 2; j++){
      int n = wn + j * 16 + col;
      float bias = conv_b[g * 64 + n];
      #pragma unroll
      for (int r2 = 0; r2 < 4; r2++){
        int p = p0 + wm + i * 16 + rowb + r2;
        O[(size_t)n * L + p] = fmaxf(acc[i][j][r2] + bias, 0.f);
      }
    }
}

// ---------------- workspace layout (bytes) --------------------------------------
// [0,        16777216) : D    (8*1024*1024 bf16)
// [16777216, 35717120) : W    (8*1156*1024 bf16)
// [35717120, 52494336) : AR   (8*1024*1024 bf16)
// [52494336, 69271552) : U    (8*1024*1024 bf16)
// [69271552, 73465856) : mbgT (8*1024*256 bf16)
// [73465856, 77660160) : mbgS (8*256*1024 bf16)
// [77660160, 81854464) : finalT (8*1024*256 bf16)
// [81854464, 83034112) : Wr   (4*9*64*256 bf16)
// [83034112, 83066880) : rsum (8*1024 f32)
// [83066880, 83099648) : S1m  (8*1024 f32)
// [83099648, 83132416) : S2m  (8*1024 f32)
// [83132416, 83165184) : rn   (8*1024 f32)
// [83165184, 83197952) : eps  (8*1024 f32)
// [83197952, 83198464) : zpage (512 B)
// fgT lives in d_out[0 .. 4.2MB) (d_out only written by branch_gemm at the end)

extern "C" void kernel_launch(void* const* d_in, const int* in_sizes, int n_in,
                              void* d_out, int out_size, void* d_ws, size_t ws_size,
                              hipStream_t stream){
  const float* fg     = (const float*)d_in[0];
  const float* mask   = (const float*)d_in[1];
  const float* bgd    = (const float*)d_in[2];
  const float* conv_w = (const float*)d_in[3];
  const float* conv_b = (const float*)d_in[4];

  char* ws = (char*)d_ws;
  unsigned short* D      = (unsigned short*)(ws + 0);
  unsigned short* W      = (unsigned short*)(ws + 16777216);
  unsigned short* AR     = (unsigned short*)(ws + 35717120);
  unsigned short* U      = (unsigned short*)(ws + 52494336);
  unsigned short* mbgT   = (unsigned short*)(ws + 69271552);
  unsigned short* mbgS   = (unsigned short*)(ws + 73465856);
  unsigned short* finalT = (unsigned short*)(ws + 77660160);
  unsigned short* Wr     = (unsigned short*)(ws + 81854464);
  float*          rsum   = (float*)(ws + 83034112);
  float*          S1m    = (float*)(ws + 83066880);
  float*          S2m    = (float*)(ws + 83099648);
  float*          rn     = (float*)(ws + 83132416);
  float*          eps    = (float*)(ws + 83165184);
  unsigned short* zpage  = (unsigned short*)(ws + 83197952);
  unsigned short* fgT    = (unsigned short*)d_out;
  float* out = (float*)d_out;

  transpose_pack<<<dim3(16, 4, 8), 256, 0, stream>>>(fg, bgd, mask, fgT, mbgT, mbgS);
  moments<<<1024, 256, 0, stream>>>(fgT, mbgT, rsum, S1m, S2m);
  rn_eps<<<32, 256, 0, stream>>>(S1m, S2m, rsum, rn, eps);
  wr_prep<<<2304, 256, 0, stream>>>(conv_w, Wr, zpage);

  gemm_d<<<2048, 256, 0, stream>>>(fgT, mbgT, D);
  box3<<<9248, 256, 0, stream>>>(D, W);
  prop_softmax_diag<<<8192, 256, 0, stream>>>(W, eps, rn, AR);
  u_stencil<<<8192, 256, 0, stream>>>(AR, U);
  gemm3_final<<<512, 256, 0, stream>>>(U, mbgS, mask, fgT, finalT);
  branch_gemm<<<512, 256, 0, stream>>>(finalT, Wr, conv_b, zpage, out);
}

// Round 8
// 123.919 us; speedup vs baseline: 3.2614x; 1.0004x over previous
//
#include <hip/hip_runtime.h>

typedef __attribute__((ext_vector_type(8))) short short8;
typedef __attribute__((ext_vector_type(4))) float f32x4;

#define HW 32
#define L 1024        // HW*HW
#define C_IN 256
#define BATCH 8
#define NQ 1156       // 34*34 extended grid

static __device__ __forceinline__ unsigned short f2bf(float f){
  unsigned int u = __float_as_uint(f);
  unsigned int r = (u + 0x7FFFu + ((u >> 16) & 1u)) >> 16;   // RNE (no NaN inputs)
  return (unsigned short)r;
}
static __device__ __forceinline__ float bf2f(unsigned short h){
  return __uint_as_float(((unsigned int)h) << 16);
}

#define GLDS16(g, l) __builtin_amdgcn_global_load_lds(                          \
    (const __attribute__((address_space(1))) void*)(g),                         \
    (__attribute__((address_space(3))) void*)(l), 16, 0, 0)

// ---------------- P0: transposes + fused per-pixel moments (atomicAdd) ----------
__global__ __launch_bounds__(256) void transpose_pack(const float* __restrict__ fg,
                                                      const float* __restrict__ bgd,
                                                      const float* __restrict__ mask,
                                                      unsigned short* __restrict__ fgT,
                                                      unsigned short* __restrict__ mbgT,
                                                      unsigned short* __restrict__ mbgS,
                                                      float* __restrict__ rsum,
                                                      float* __restrict__ S1m,
                                                      float* __restrict__ S2m){
  __shared__ float T[64][65];
  __shared__ float ps[3][4][64];
  int p0 = blockIdx.x * 64, c0 = blockIdx.y * 64, b = blockIdx.z;
  int tx = threadIdx.x & 63, ty = threadIdx.x >> 6;
  const float* F = fg  + ((size_t)b * C_IN + c0) * L + p0;
  const float* G = bgd + ((size_t)b * C_IN + c0) * L + p0;
  float sf = 0.f;
  for (int cc = ty; cc < 64; cc += 4){
    float v = F[(size_t)cc * L + tx];
    T[cc][tx] = v; sf += v;
  }
  ps[0][ty][tx] = sf;
  __syncthreads();
  for (int pp = ty; pp < 64; pp += 4)
    fgT[(size_t)(b * L + p0 + pp) * C_IN + c0 + tx] = f2bf(T[tx][pp]);
  if (ty == 0)
    atomicAdd(&rsum[b * L + p0 + tx], ps[0][0][tx] + ps[0][1][tx] + ps[0][2][tx] + ps[0][3][tx]);
  __syncthreads();
  float mm = 1.f - mask[p0 + tx];
  float s1 = 0.f, s2 = 0.f;
  for (int cc = ty; cc < 64; cc += 4){
    float v = G[(size_t)cc * L + tx] * mm;
    T[cc][tx] = v; s1 += v; s2 += v * v;
    mbgS[((size_t)b * C_IN + c0 + cc) * L + p0 + tx] = f2bf(v);
  }
  ps[1][ty][tx] = s1; ps[2][ty][tx] = s2;
  __syncthreads();
  for (int pp = ty; pp < 64; pp += 4)
    mbgT[(size_t)(b * L + p0 + pp) * C_IN + c0 + tx] = f2bf(T[tx][pp]);
  if (ty == 0){
    atomicAdd(&S1m[b * L + p0 + tx], ps[1][0][tx] + ps[1][1][tx] + ps[1][2][tx] + ps[1][3][tx]);
    atomicAdd(&S2m[b * L + p0 + tx], ps[2][0][tx] + ps[2][1][tx] + ps[2][2][tx] + ps[2][3][tx]);
  }
}

// ---------------- P1: merged rn/eps (blocks 0..31) + Wr prep (blocks 32..2335) --
__global__ __launch_bounds__(256) void prep_misc(const float* __restrict__ S1m,
                                                 const float* __restrict__ S2m,
                                                 const float* __restrict__ rsum,
                                                 float* __restrict__ rn,
                                                 float* __restrict__ eps,
                                                 const float* __restrict__ conv_w,
                                                 unsigned short* __restrict__ Wr,
                                                 unsigned short* __restrict__ zpage){
  int blk = blockIdx.x;
  if (blk < 32){
    int idx = blk * 256 + threadIdx.x;           // 8192
    int b = idx >> 10, l = idx & 1023;
    int ly = l >> 5, lx = l & 31;
    float n2 = 2.304e-11f;                       // 2304 * 1e-14
    #pragma unroll
    for (int s = 0; s < 9; s++){
      int y = ly + s / 3 - 1, x = lx + s % 3 - 1;
      if ((unsigned)y < HW && (unsigned)x < HW){
        int q = b * L + y * HW + x;
        n2 += S2m[q] + 2e-7f * S1m[q];
      }
    }
    rn[idx] = 1.f / sqrtf(n2);
    const float* rs = rsum + b * L;
    float ev = 0.f;
    const int tw[5] = {1, 2, 3, 2, 1};
    #pragma unroll
    for (int oy = -2; oy <= 2; oy++)
      #pragma unroll
      for (int ox = -2; ox <= 2; ox++){
        int y = ly + oy, x = lx + ox;
        if ((unsigned)y < HW && (unsigned)x < HW)
          ev += (float)(tw[oy + 2] * tw[ox + 2]) * rs[y * HW + x];
      }
    eps[idx] = 1e-7f * ev;
  } else {
    if (blk == 32) zpage[threadIdx.x] = 0;
    int idx = (blk - 32) * 256 + threadIdx.x;    // 589824
    int c = idx & 255;
    int rest = idx >> 8;
    int n = rest & 63;
    int sg = rest >> 6;
    int s = sg % 9, g = sg / 9;
    Wr[idx] = f2bf(conv_w[(((size_t)(g * 64 + n)) * C_IN + c) * 9 + s]);
  }
}

// ---------------- G1: D[b][u][v] = sum_c fgT[u][c]*mbgT[v][c]  (bf16 out) -------
__global__ __launch_bounds__(256) void gemm_d(const unsigned short* __restrict__ fgT,
                                              const unsigned short* __restrict__ mbgT,
                                              unsigned short* __restrict__ D){
  __shared__ unsigned short As[64][256];   // 32 KB
  __shared__ unsigned short Bs[64][256];   // 32 KB
  int bid = blockIdx.x;                // 2048 = 8 * 256: b = bid&7 (XCD-affine)
  int b = bid & 7, r = bid >> 3;
  int by = r >> 4, bx = r & 15;
  const unsigned short* Ab = fgT  + ((size_t)b * L + by * 64) * C_IN;
  const unsigned short* Bb = mbgT + ((size_t)b * L + bx * 64) * C_IN;
  int tid = threadIdx.x, lane = tid & 63, wv = tid >> 6;
  int row_off = lane >> 5, slot = lane & 31;
  int q = slot >> 3, sl = slot & 7;
  #pragma unroll
  for (int i = 0; i < 8; i++){
    int rr = wv * 16 + i * 2 + row_off;
    int srcs = q * 8 + (sl ^ (rr & 7));
    GLDS16(Ab + (size_t)rr * C_IN + srcs * 8, &As[wv * 16 + i * 2][0]);
    GLDS16(Bb + (size_t)rr * C_IN + srcs * 8, &Bs[wv * 16 + i * 2][0]);
  }
  __syncthreads();
  int wm = (wv & 1) * 32, wn = (wv >> 1) * 32;
  int rsel = lane & 15, sx = lane >> 4;
  f32x4 acc[2][2] = {};
  #pragma unroll
  for (int st = 0; st < 8; st++){
    int gs = st * 4 + sx, qq = gs >> 3, ss = gs & 7;
    short8 af[2], bf[2];
    #pragma unroll
    for (int i = 0; i < 2; i++){
      int ra = wm + i * 16 + rsel;
      af[i] = *(const short8*)&As[ra][(qq * 8 + (ss ^ (ra & 7))) * 8];
      int rb = wn + i * 16 + rsel;
      bf[i] = *(const short8*)&Bs[rb][(qq * 8 + (ss ^ (rb & 7))) * 8];
    }
    #pragma unroll
    for (int i = 0; i < 2; i++)
      #pragma unroll
      for (int j = 0; j < 2; j++)
        acc[i][j] = __builtin_amdgcn_mfma_f32_16x16x32_bf16(af[i], bf[j], acc[i][j], 0, 0, 0);
  }
  unsigned short* Db = D + ((size_t)b << 20);
  int rowb = (lane >> 4) * 4, col = lane & 15;
  #pragma unroll
  for (int i = 0; i < 2; i++)
    #pragma unroll
    for (int j = 0; j < 2; j++)
      #pragma unroll
      for (int r2 = 0; r2 < 4; r2++)
        Db[(size_t)(by * 64 + wm + i * 16 + rowb + r2) * L + bx * 64 + wn + j * 16 + col] = f2bf(acc[i][j][r2]);
}

// ---------------- S2: W[b][q][v] = 3x3 box of D over u (bf16 in/out) ------------
__global__ __launch_bounds__(256) void box3(const unsigned short* __restrict__ D,
                                            unsigned short* __restrict__ W){
  int bid = blockIdx.x;                // 9248 = 8*1156: b = bid&7
  int b = bid & 7, q2 = bid >> 3;
  int qy = q2 / 34 - 1, qx = q2 % 34 - 1;
  const unsigned short* Db = D + ((size_t)b << 20);
  int tid = threadIdx.x;
  float a0 = 0.f, a1 = 0.f, a2 = 0.f, a3 = 0.f;
  #pragma unroll
  for (int dy = -1; dy <= 1; dy++)
    #pragma unroll
    for (int dx = -1; dx <= 1; dx++){
      int y = qy + dy, x = qx + dx;
      if ((unsigned)y < HW && (unsigned)x < HW){
        ushort4 v = *(const ushort4*)(Db + ((size_t)(y * HW + x) << 10) + tid * 4);
        a0 += bf2f(v.x); a1 += bf2f(v.y); a2 += bf2f(v.z); a3 += bf2f(v.w);
      }
    }
  ushort4 o;
  o.x = f2bf(a0); o.y = f2bf(a1); o.z = f2bf(a2); o.w = f2bf(a3);
  *(ushort4*)(W + ((size_t)(b * NQ + q2) << 10) + tid * 4) = o;
}

// ------- vector tap read: 4 bf16 at (base l0*?) + delta with static shift -------
// H[idx..idx+3] out of two aligned b64 reads; shift = idx&3 is compile-time.
static __device__ __forceinline__ void tap4(const unsigned* __restrict__ row32,
                                            int idx, int sh,
                                            unsigned &o0, unsigned &o1){
  int a0 = idx & ~3;
  const uint2* row = (const uint2*)row32;
  uint2 q0 = row[a0 >> 2];
  uint2 q1 = row[((a0 + 4) & 1023) >> 2];
  if (sh == 0){ o0 = q0.x; o1 = q0.y; }
  else if (sh == 1){ o0 = (q0.x >> 16) | (q0.y << 16); o1 = (q0.y >> 16) | (q1.x << 16); }
  else if (sh == 2){ o0 = q0.y; o1 = q1.x; }
  else { o0 = (q0.y >> 16) | (q1.x << 16); o1 = (q1.x >> 16) | (q1.y << 16); }
}

// ---------------- S3: diag 9-tap via LDS-staged W rows + softmax -> AR ----------
__global__ __launch_bounds__(256) void prop_softmax_diag(const unsigned short* __restrict__ W,
                                                         const float* __restrict__ eps,
                                                         const float* __restrict__ rn,
                                                         unsigned short* __restrict__ AR){
  __shared__ __align__(16) unsigned short Wl[9][1024];   // 18 KB
  __shared__ float redm[4], reds[4];
  int bid = blockIdx.x;                // 8192: b = bid&7
  int b = bid & 7, p = bid >> 3;
  int py = p >> 5, px = p & 31;
  const unsigned short* Wb = W + (size_t)b * NQ * L;
  int tid = threadIdx.x, lane = tid & 63, wv = tid >> 6;
  #pragma unroll
  for (int k = 0; k < 5; k++){
    int u = k * 4 + wv;
    if (u < 18){
      int s = u >> 1, half = u & 1;
      int qs = (py + s / 3) * 34 + (px + s % 3);
      GLDS16(Wb + (((size_t)qs) << 10) + half * 512 + lane * 8, &Wl[s][half * 512]);
    }
  }
  float epsv = eps[b * L + p];           // block-uniform scalar
  __syncthreads();
  int l0 = tid * 4;
  int ly = l0 >> 5, lx0 = l0 & 31;
  float4 rnl = *(const float4*)&rn[b * L + l0];
  float a[4] = {0.f, 0.f, 0.f, 0.f};
  #pragma unroll
  for (int s = 0; s < 9; s++){
    const int dy = s / 3 - 1, dx = s % 3 - 1;
    const int dlt = dy * 32 + dx;
    const int sh = dlt & 3;
    bool rok = (unsigned)(ly + dy) < HW;
    int idx = (l0 + dlt) & 1023;
    unsigned o0, o1;
    tap4((const unsigned*)&Wl[s][0], idx, sh, o0, o1);
    float f0 = __uint_as_float(o0 << 16), f1 = __uint_as_float(o0 & 0xffff0000u);
    float f2 = __uint_as_float(o1 << 16), f3 = __uint_as_float(o1 & 0xffff0000u);
    a[0] += (rok && (unsigned)(lx0 + 0 + dx) < HW) ? f0 : 0.f;
    a[1] += (rok && (unsigned)(lx0 + 1 + dx) < HW) ? f1 : 0.f;
    a[2] += (rok && (unsigned)(lx0 + 2 + dx) < HW) ? f2 : 0.f;
    a[3] += (rok && (unsigned)(lx0 + 3 + dx) < HW) ? f3 : 0.f;
  }
  float val[4];
  val[0] = rnl.x * (a[0] + epsv); val[1] = rnl.y * (a[1] + epsv);
  val[2] = rnl.z * (a[2] + epsv); val[3] = rnl.w * (a[3] + epsv);
  float m = fmaxf(fmaxf(val[0], val[1]), fmaxf(val[2], val[3]));
  #pragma unroll
  for (int off = 32; off; off >>= 1) m = fmaxf(m, __shfl_xor(m, off));
  if (lane == 0) redm[wv] = m;
  __syncthreads();
  m = fmaxf(fmaxf(redm[0], redm[1]), fmaxf(redm[2], redm[3]));
  float e[4], t = 0.f;
  #pragma unroll
  for (int j = 0; j < 4; j++){ e[j] = __expf(val[j] - m); t += e[j]; }
  #pragma unroll
  for (int off = 32; off; off >>= 1) t += __shfl_xor(t, off);
  if (lane == 0) reds[wv] = t;
  __syncthreads();
  t = reds[0] + reds[1] + reds[2] + reds[3];
  float inv = 1.f / t;
  unsigned short* O = AR + ((size_t)b << 20) + ((size_t)p << 10);
  ushort4 ov;
  ov.x = f2bf(e[0] * inv * rnl.x); ov.y = f2bf(e[1] * inv * rnl.y);
  ov.z = f2bf(e[2] * inv * rnl.z); ov.w = f2bf(e[3] * inv * rnl.w);
  *(ushort4*)&O[l0] = ov;
}

// ---------------- S4: U[p][v] = sum_s gated AR[p+ds][v+ds] via LDS staging ------
__global__ __launch_bounds__(256) void u_stencil(const unsigned short* __restrict__ AR,
                                                 unsigned short* __restrict__ U){
  __shared__ __align__(16) unsigned short Al[9][1024];   // 18 KB
  int bid = blockIdx.x;                // 8192: b = bid&7
  int b = bid & 7, p = bid >> 3;
  int py = p >> 5, px = p & 31;
  int tid = threadIdx.x, lane = tid & 63, wv = tid >> 6;
  const unsigned short* A = AR + ((size_t)b << 20);
  #pragma unroll
  for (int k = 0; k < 5; k++){
    int u = k * 4 + wv;
    if (u < 18){
      int s = u >> 1, half = u & 1;
      int yy = py + s / 3 - 1, xx = px + s % 3 - 1;
      bool rok = ((unsigned)yy < HW) && ((unsigned)xx < HW);
      int p2 = rok ? (yy * HW + xx) : 0;
      GLDS16(A + (((size_t)p2) << 10) + half * 512 + lane * 8, &Al[s][half * 512]);
    }
  }
  int rowmask = 0;
  #pragma unroll
  for (int s = 0; s < 9; s++){
    int yy = py + s / 3 - 1, xx = px + s % 3 - 1;
    if (((unsigned)yy < HW) && ((unsigned)xx < HW)) rowmask |= 1 << s;
  }
  __syncthreads();
  int v0 = tid * 4;
  int vy = v0 >> 5, vx0 = v0 & 31;
  float acc[4] = {0.f, 0.f, 0.f, 0.f};
  #pragma unroll
  for (int s = 0; s < 9; s++){
    const int dy = s / 3 - 1, dx = s % 3 - 1;
    const int dlt = dy * 32 + dx;
    const int sh = dlt & 3;
    bool rok = ((rowmask >> s) & 1) && ((unsigned)(vy + dy) < HW);
    int idx = (v0 + dlt) & 1023;
    unsigned o0, o1;
    tap4((const unsigned*)&Al[s][0], idx, sh, o0, o1);
    float f0 = __uint_as_float(o0 << 16), f1 = __uint_as_float(o0 & 0xffff0000u);
    float f2 = __uint_as_float(o1 << 16), f3 = __uint_as_float(o1 & 0xffff0000u);
    acc[0] += (rok && (unsigned)(vx0 + 0 + dx) < HW) ? f0 : 0.f;
    acc[1] += (rok && (unsigned)(vx0 + 1 + dx) < HW) ? f1 : 0.f;
    acc[2] += (rok && (unsigned)(vx0 + 2 + dx) < HW) ? f2 : 0.f;
    acc[3] += (rok && (unsigned)(vx0 + 3 + dx) < HW) ? f3 : 0.f;
  }
  unsigned short* O = U + ((size_t)b << 20) + ((size_t)p << 10);
  ushort4 ov;
  ov.x = f2bf(acc[0]); ov.y = f2bf(acc[1]); ov.z = f2bf(acc[2]); ov.w = f2bf(acc[3]);
  *(ushort4*)&O[v0] = ov;
}

// ---------------- G2: finalT[p][c] = mask? (U.mbgS)/9 : fgT  (32-row tiles) -----
__global__ __launch_bounds__(256) void gemm3_final(const unsigned short* __restrict__ U,
                                                   const unsigned short* __restrict__ mbgS,
                                                   const float* __restrict__ mask,
                                                   const unsigned short* __restrict__ fgT,
                                                   unsigned short* __restrict__ finalT){
  __shared__ unsigned short As[2][32][64];   // 8 KB
  __shared__ unsigned short Bs[2][64][64];   // 16 KB
  int bid = blockIdx.x;                // 1024: b = bid&7
  int b = bid & 7, r = bid >> 3;       // r in [0,128)
  int mt = r >> 2, ct = r & 3;         // mt 0..31
  int tid = threadIdx.x, lane = tid & 63, wv = tid >> 6;
  int wm = (wv & 1) * 16, wn = (wv >> 1) * 32;
  int rsel = lane & 15;
  int srow = lane >> 3, scol = ((lane & 7) ^ srow) * 8;
  const unsigned short* Ab = U    + ((size_t)b * L + mt * 32) * L;
  const unsigned short* Bb = mbgS + ((size_t)b * C_IN + ct * 64) * L;
  GLDS16(Ab + (size_t)(wv * 8 + srow) * L + scol, &As[0][wv * 8][0]);
  #pragma unroll
  for (int g8 = 0; g8 < 2; g8++)
    GLDS16(Bb + (size_t)(wv * 16 + g8 * 8 + srow) * L + scol, &Bs[0][wv * 16 + g8 * 8][0]);
  __syncthreads();
  f32x4 acc[2] = {};
  int cur = 0;
  for (int t = 0; t < 16; ++t){
    short8 af[2], bf[2][2];
    #pragma unroll
    for (int kk = 0; kk < 2; kk++){
      int s0 = kk * 4 + (lane >> 4);
      int col = ((s0 ^ (rsel & 7)) << 3);
      af[kk] = *(const short8*)&As[cur][wm + rsel][col];
      bf[kk][0] = *(const short8*)&Bs[cur][wn + rsel][col];
      bf[kk][1] = *(const short8*)&Bs[cur][wn + 16 + rsel][col];
    }
    if (t + 1 < 16){
      int nb = cur ^ 1;
      size_t kt = (size_t)(t + 1) * 64;
      GLDS16(Ab + (size_t)(wv * 8 + srow) * L + kt + scol, &As[nb][wv * 8][0]);
      #pragma unroll
      for (int g8 = 0; g8 < 2; g8++)
        GLDS16(Bb + (size_t)(wv * 16 + g8 * 8 + srow) * L + kt + scol, &Bs[nb][wv * 16 + g8 * 8][0]);
    }
    #pragma unroll
    for (int kk = 0; kk < 2; kk++)
      #pragma unroll
      for (int j = 0; j < 2; j++)
        acc[j] = __builtin_amdgcn_mfma_f32_16x16x32_bf16(af[kk], bf[kk][j], acc[j], 0, 0, 0);
    __syncthreads();
    cur ^= 1;
  }
  int rowb = (lane >> 4) * 4, col = lane & 15;
  #pragma unroll
  for (int j = 0; j < 2; j++)
    #pragma unroll
    for (int r2 = 0; r2 < 4; r2++){
      int p = mt * 32 + wm + rowb + r2;
      int c = ct * 64 + wn + j * 16 + col;
      unsigned short o;
      if (mask[p] != 0.f) o = f2bf(acc[j][r2] * (1.f / 9.f));
      else                o = fgT[((size_t)b * L + p) * C_IN + c];
      finalT[((size_t)b * L + p) * C_IN + c] = o;
    }
}

// ---------------- K4: branch convs as shifted GEMM (32-row tiles) ---------------
__global__ __launch_bounds__(256) void branch_gemm(const unsigned short* __restrict__ finalT,
                                                   const unsigned short* __restrict__ Wr,
                                                   const float* __restrict__ conv_b,
                                                   const unsigned short* __restrict__ zpage,
                                                   float* __restrict__ out){
  __shared__ unsigned short As[2][32][64];   // 8 KB
  __shared__ unsigned short Bs[2][64][64];   // 16 KB
  int nwg = gridDim.x, bid = blockIdx.x;     // 1024
  int nid = (bid & 7) * (nwg >> 3) + (bid >> 3);   // XCD-affine: b == bid&7
  int bg = nid >> 5, pt = nid & 31;
  int b = bg >> 2, g = bg & 3;
  int rate = 1 << g;
  int p0 = pt * 32;
  int tid = threadIdx.x, lane = tid & 63, wv = tid >> 6;
  int wm = (wv & 1) * 16, wn = (wv >> 1) * 32;
  int rsel = lane & 15;
  int srow = lane >> 3;
  int scol = ((lane & 7) ^ srow) * 8;
  const unsigned short* FT = finalT + (size_t)b * L * C_IN;
  const unsigned short* WG = Wr + (size_t)(g * 9) * 64 * C_IN;

  int prow = p0 + wv * 8 + srow;
  int ayy = prow >> 5, axx = prow & 31;
  auto a_src = [&](int t) -> const unsigned short* {
    int s = t >> 2, q = t & 3;
    int dy = s / 3 - 1, dx = s - (s / 3) * 3 - 1;
    int iy = ayy + rate * dy, ix = axx + rate * dx;
    if ((unsigned)iy < HW && (unsigned)ix < HW)
      return FT + (size_t)(iy * HW + ix) * C_IN + q * 64 + scol;
    return zpage;
  };
  auto b_src = [&](int t, int g8) -> const unsigned short* {
    int s = t >> 2, q = t & 3;
    int n = wv * 16 + g8 * 8 + srow;
    return WG + (size_t)(s * 64 + n) * C_IN + q * 64 + scol;
  };

  f32x4 acc[2] = {};
  GLDS16(a_src(0), &As[0][wv * 8][0]);
  GLDS16(b_src(0, 0), &Bs[0][wv * 16][0]);
  GLDS16(b_src(0, 1), &Bs[0][wv * 16 + 8][0]);
  __syncthreads();
  int cur = 0;
  for (int t = 0; t < 36; ++t){
    short8 af[2], bf[2][2];
    #pragma unroll
    for (int kk = 0; kk < 2; kk++){
      int s0 = kk * 4 + (lane >> 4);
      int col = ((s0 ^ (rsel & 7)) << 3);
      af[kk] = *(const short8*)&As[cur][wm + rsel][col];
      bf[kk][0] = *(const short8*)&Bs[cur][wn + rsel][col];
      bf[kk][1] = *(const short8*)&Bs[cur][wn + 16 + rsel][col];
    }
    if (t + 1 < 36){
      int nb = cur ^ 1;
      GLDS16(a_src(t + 1), &As[nb][wv * 8][0]);
      GLDS16(b_src(t + 1, 0), &Bs[nb][wv * 16][0]);
      GLDS16(b_src(t + 1, 1), &Bs[nb][wv * 16 + 8][0]);
    }
    #pragma unroll
    for (int kk = 0; kk < 2; kk++)
      #pragma unroll
      for (int j = 0; j < 2; j++)
        acc[j] = __builtin_amdgcn_mfma_f32_16x16x32_bf16(af[kk], bf[kk][j], acc[j], 0, 0, 0);
    __syncthreads();
    cur ^= 1;
  }
  int rowb = (lane >> 4) * 4, col = lane & 15;
  float* O = out + (size_t)(b * 256 + g * 64) * L;
  #pragma unroll
  for (int j = 0; j < 2; j++){
    int n = wn + j * 16 + col;
    float bias = conv_b[g * 64 + n];
    #pragma unroll
    for (int r2 = 0; r2 < 4; r2++){
      int p = p0 + wm + rowb + r2;
      O[(size_t)n * L + p] = fmaxf(acc[j][r2] + bias, 0.f);
    }
  }
}

// ---------------- workspace layout (bytes) --------------------------------------
// [0,        16777216) : D    (8*1024*1024 bf16)
// [16777216, 35717120) : W    (8*1156*1024 bf16)
// [35717120, 52494336) : AR   (8*1024*1024 bf16)
// [52494336, 69271552) : U    (8*1024*1024 bf16)
// [69271552, 73465856) : mbgT (8*1024*256 bf16)
// [73465856, 77660160) : mbgS (8*256*1024 bf16)
// [77660160, 81854464) : finalT (8*1024*256 bf16)
// [81854464, 83034112) : Wr   (4*9*64*256 bf16)
// [83034112, 83066880) : rsum (8*1024 f32)   \
// [83066880, 83099648) : S1m  (8*1024 f32)    } zeroed by one memsetAsync
// [83099648, 83132416) : S2m  (8*1024 f32)   /
// [83132416, 83165184) : rn   (8*1024 f32)
// [83165184, 83197952) : eps  (8*1024 f32)
// [83197952, 83198464) : zpage (512 B)
// fgT lives in d_out[0 .. 4.2MB) (d_out only written by branch_gemm at the end)

extern "C" void kernel_launch(void* const* d_in, const int* in_sizes, int n_in,
                              void* d_out, int out_size, void* d_ws, size_t ws_size,
                              hipStream_t stream){
  const float* fg     = (const float*)d_in[0];
  const float* mask   = (const float*)d_in[1];
  const float* bgd    = (const float*)d_in[2];
  const float* conv_w = (const float*)d_in[3];
  const float* conv_b = (const float*)d_in[4];

  char* ws = (char*)d_ws;
  unsigned short* D      = (unsigned short*)(ws + 0);
  unsigned short* W      = (unsigned short*)(ws + 16777216);
  unsigned short* AR     = (unsigned short*)(ws + 35717120);
  unsigned short* U      = (unsigned short*)(ws + 52494336);
  unsigned short* mbgT   = (unsigned short*)(ws + 69271552);
  unsigned short* mbgS   = (unsigned short*)(ws + 73465856);
  unsigned short* finalT = (unsigned short*)(ws + 77660160);
  unsigned short* Wr     = (unsigned short*)(ws + 81854464);
  float*          rsum   = (float*)(ws + 83034112);
  float*          S1m    = (float*)(ws + 83066880);
  float*          S2m    = (float*)(ws + 83099648);
  float*          rn     = (float*)(ws + 83132416);
  float*          eps    = (float*)(ws + 83165184);
  unsigned short* zpage  = (unsigned short*)(ws + 83197952);
  unsigned short* fgT    = (unsigned short*)d_out;
  float* out = (float*)d_out;

  hipMemsetAsync(rsum, 0, 98304, stream);   // rsum+S1m+S2m (accumulated via atomics)

  transpose_pack<<<dim3(16, 4, 8), 256, 0, stream>>>(fg, bgd, mask, fgT, mbgT, mbgS,
                                                     rsum, S1m, S2m);
  prep_misc<<<2336, 256, 0, stream>>>(S1m, S2m, rsum, rn, eps, conv_w, Wr, zpage);

  gemm_d<<<2048, 256, 0, stream>>>(fgT, mbgT, D);
  box3<<<9248, 256, 0, stream>>>(D, W);
  prop_softmax_diag<<<8192, 256, 0, stream>>>(W, eps, rn, AR);
  u_stencil<<<8192, 256, 0, stream>>>(AR, U);
  gemm3_final<<<1024, 256, 0, stream>>>(U, mbgS, mask, fgT, finalT);
  branch_gemm<<<1024, 256, 0, stream>>>(finalT, Wr, conv_b, zpage, out);
}

// Round 9
// 119.765 us; speedup vs baseline: 3.3745x; 1.0347x over previous
//
#include <hip/hip_runtime.h>

typedef __attribute__((ext_vector_type(8))) short short8;
typedef __attribute__((ext_vector_type(4))) float f32x4;

#define HW 32
#define L 1024        // HW*HW
#define C_IN 256
#define BATCH 8
#define NQ 1156       // 34*34 extended grid

static __device__ __forceinline__ unsigned short f2bf(float f){
  unsigned int u = __float_as_uint(f);
  unsigned int r = (u + 0x7FFFu + ((u >> 16) & 1u)) >> 16;   // RNE (no NaN inputs)
  return (unsigned short)r;
}
static __device__ __forceinline__ float bf2f(unsigned short h){
  return __uint_as_float(((unsigned int)h) << 16);
}

#define GLDS16(g, l) __builtin_amdgcn_global_load_lds(                          \
    (const __attribute__((address_space(1))) void*)(g),                         \
    (__attribute__((address_space(3))) void*)(l), 16, 0, 0)

// ---------------- P0: transposes + per-pixel moment PARTIALS (no atomics) -------
// psum layout: [cb 0..3][j 0..2][b*L+p]  (j: 0=rsum_fg, 1=S1_mbg, 2=S2_mbg)
__global__ __launch_bounds__(256) void transpose_pack(const float* __restrict__ fg,
                                                      const float* __restrict__ bgd,
                                                      const float* __restrict__ mask,
                                                      unsigned short* __restrict__ fgT,
                                                      unsigned short* __restrict__ mbgT,
                                                      unsigned short* __restrict__ mbgS,
                                                      float* __restrict__ psum){
  __shared__ float T[64][65];
  __shared__ float ps[3][4][64];
  int p0 = blockIdx.x * 64, c0 = blockIdx.y * 64, b = blockIdx.z;
  int cb = blockIdx.y;
  int tx = threadIdx.x & 63, ty = threadIdx.x >> 6;
  const float* F = fg  + ((size_t)b * C_IN + c0) * L + p0;
  const float* G = bgd + ((size_t)b * C_IN + c0) * L + p0;
  float sf = 0.f;
  for (int cc = ty; cc < 64; cc += 4){
    float v = F[(size_t)cc * L + tx];
    T[cc][tx] = v; sf += v;
  }
  ps[0][ty][tx] = sf;
  __syncthreads();
  for (int pp = ty; pp < 64; pp += 4)
    fgT[(size_t)(b * L + p0 + pp) * C_IN + c0 + tx] = f2bf(T[tx][pp]);
  if (ty == 0)
    psum[(size_t)(cb * 3 + 0) * (BATCH * L) + b * L + p0 + tx] =
        ps[0][0][tx] + ps[0][1][tx] + ps[0][2][tx] + ps[0][3][tx];
  __syncthreads();
  float mm = 1.f - mask[p0 + tx];
  float s1 = 0.f, s2 = 0.f;
  for (int cc = ty; cc < 64; cc += 4){
    float v = G[(size_t)cc * L + tx] * mm;
    T[cc][tx] = v; s1 += v; s2 += v * v;
    mbgS[((size_t)b * C_IN + c0 + cc) * L + p0 + tx] = f2bf(v);
  }
  ps[1][ty][tx] = s1; ps[2][ty][tx] = s2;
  __syncthreads();
  for (int pp = ty; pp < 64; pp += 4)
    mbgT[(size_t)(b * L + p0 + pp) * C_IN + c0 + tx] = f2bf(T[tx][pp]);
  if (ty == 0){
    psum[(size_t)(cb * 3 + 1) * (BATCH * L) + b * L + p0 + tx] =
        ps[1][0][tx] + ps[1][1][tx] + ps[1][2][tx] + ps[1][3][tx];
    psum[(size_t)(cb * 3 + 2) * (BATCH * L) + b * L + p0 + tx] =
        ps[2][0][tx] + ps[2][1][tx] + ps[2][2][tx] + ps[2][3][tx];
  }
}

// ---------------- P1: merged rn/eps (blocks 0..31) + Wr prep (blocks 32..2335) --
__global__ __launch_bounds__(256) void prep_misc(const float* __restrict__ psum,
                                                 float* __restrict__ rn,
                                                 float* __restrict__ eps,
                                                 const float* __restrict__ conv_w,
                                                 unsigned short* __restrict__ Wr,
                                                 unsigned short* __restrict__ zpage){
  int blk = blockIdx.x;
  if (blk < 32){
    int idx = blk * 256 + threadIdx.x;           // 8192
    int b = idx >> 10, l = idx & 1023;
    int ly = l >> 5, lx = l & 31;
    const int NP = BATCH * L;
    float n2 = 2.304e-11f;                       // 2304 * 1e-14
    #pragma unroll
    for (int s = 0; s < 9; s++){
      int y = ly + s / 3 - 1, x = lx + s % 3 - 1;
      if ((unsigned)y < HW && (unsigned)x < HW){
        int q = b * L + y * HW + x;
        float s1 = 0.f, s2 = 0.f;
        #pragma unroll
        for (int k = 0; k < 4; k++){
          s1 += psum[(size_t)(k * 3 + 1) * NP + q];
          s2 += psum[(size_t)(k * 3 + 2) * NP + q];
        }
        n2 += s2 + 2e-7f * s1;
      }
    }
    rn[idx] = 1.f / sqrtf(n2);
    float ev = 0.f;
    const int tw[5] = {1, 2, 3, 2, 1};
    #pragma unroll
    for (int oy = -2; oy <= 2; oy++)
      #pragma unroll
      for (int ox = -2; ox <= 2; ox++){
        int y = ly + oy, x = lx + ox;
        if ((unsigned)y < HW && (unsigned)x < HW){
          int q = b * L + y * HW + x;
          float s0 = 0.f;
          #pragma unroll
          for (int k = 0; k < 4; k++) s0 += psum[(size_t)(k * 3 + 0) * NP + q];
          ev += (float)(tw[oy + 2] * tw[ox + 2]) * s0;
        }
      }
    eps[idx] = 1e-7f * ev;
  } else {
    if (blk == 32) zpage[threadIdx.x] = 0;
    int idx = (blk - 32) * 256 + threadIdx.x;    // 589824
    int c = idx & 255;
    int rest = idx >> 8;
    int n = rest & 63;
    int sg = rest >> 6;
    int s = sg % 9, g = sg / 9;
    Wr[idx] = f2bf(conv_w[(((size_t)(g * 64 + n)) * C_IN + c) * 9 + s]);
  }
}

// ---------------- G1: D[b][u][v] = sum_c fgT[u][c]*mbgT[v][c]  (bf16 out) -------
__global__ __launch_bounds__(256) void gemm_d(const unsigned short* __restrict__ fgT,
                                              const unsigned short* __restrict__ mbgT,
                                              unsigned short* __restrict__ D){
  __shared__ unsigned short As[64][256];   // 32 KB
  __shared__ unsigned short Bs[64][256];   // 32 KB
  int bid = blockIdx.x;                // 2048 = 8 * 256: b = bid&7 (XCD-affine)
  int b = bid & 7, r = bid >> 3;
  int by = r >> 4, bx = r & 15;
  const unsigned short* Ab = fgT  + ((size_t)b * L + by * 64) * C_IN;
  const unsigned short* Bb = mbgT + ((size_t)b * L + bx * 64) * C_IN;
  int tid = threadIdx.x, lane = tid & 63, wv = tid >> 6;
  int row_off = lane >> 5, slot = lane & 31;
  int q = slot >> 3, sl = slot & 7;
  #pragma unroll
  for (int i = 0; i < 8; i++){
    int rr = wv * 16 + i * 2 + row_off;
    int srcs = q * 8 + (sl ^ (rr & 7));
    GLDS16(Ab + (size_t)rr * C_IN + srcs * 8, &As[wv * 16 + i * 2][0]);
    GLDS16(Bb + (size_t)rr * C_IN + srcs * 8, &Bs[wv * 16 + i * 2][0]);
  }
  __syncthreads();
  int wm = (wv & 1) * 32, wn = (wv >> 1) * 32;
  int rsel = lane & 15, sx = lane >> 4;
  f32x4 acc[2][2] = {};
  #pragma unroll
  for (int st = 0; st < 8; st++){
    int gs = st * 4 + sx, qq = gs >> 3, ss = gs & 7;
    short8 af[2], bf[2];
    #pragma unroll
    for (int i = 0; i < 2; i++){
      int ra = wm + i * 16 + rsel;
      af[i] = *(const short8*)&As[ra][(qq * 8 + (ss ^ (ra & 7))) * 8];
      int rb = wn + i * 16 + rsel;
      bf[i] = *(const short8*)&Bs[rb][(qq * 8 + (ss ^ (rb & 7))) * 8];
    }
    #pragma unroll
    for (int i = 0; i < 2; i++)
      #pragma unroll
      for (int j = 0; j < 2; j++)
        acc[i][j] = __builtin_amdgcn_mfma_f32_16x16x32_bf16(af[i], bf[j], acc[i][j], 0, 0, 0);
  }
  unsigned short* Db = D + ((size_t)b << 20);
  int rowb = (lane >> 4) * 4, col = lane & 15;
  #pragma unroll
  for (int i = 0; i < 2; i++)
    #pragma unroll
    for (int j = 0; j < 2; j++)
      #pragma unroll
      for (int r2 = 0; r2 < 4; r2++)
        Db[(size_t)(by * 64 + wm + i * 16 + rowb + r2) * L + bx * 64 + wn + j * 16 + col] = f2bf(acc[i][j][r2]);
}

// ---------------- S2: W[b][q][v] = 3x3 box of D over u (bf16 in/out) ------------
__global__ __launch_bounds__(256) void box3(const unsigned short* __restrict__ D,
                                            unsigned short* __restrict__ W){
  int bid = blockIdx.x;                // 9248 = 8*1156: b = bid&7
  int b = bid & 7, q2 = bid >> 3;
  int qy = q2 / 34 - 1, qx = q2 % 34 - 1;
  const unsigned short* Db = D + ((size_t)b << 20);
  int tid = threadIdx.x;
  float a0 = 0.f, a1 = 0.f, a2 = 0.f, a3 = 0.f;
  #pragma unroll
  for (int dy = -1; dy <= 1; dy++)
    #pragma unroll
    for (int dx = -1; dx <= 1; dx++){
      int y = qy + dy, x = qx + dx;
      if ((unsigned)y < HW && (unsigned)x < HW){
        ushort4 v = *(const ushort4*)(Db + ((size_t)(y * HW + x) << 10) + tid * 4);
        a0 += bf2f(v.x); a1 += bf2f(v.y); a2 += bf2f(v.z); a3 += bf2f(v.w);
      }
    }
  ushort4 o;
  o.x = f2bf(a0); o.y = f2bf(a1); o.z = f2bf(a2); o.w = f2bf(a3);
  *(ushort4*)(W + ((size_t)(b * NQ + q2) << 10) + tid * 4) = o;
}

// ------- vector tap read: 4 bf16 at idx..idx+3 from a 1024-elem LDS row ---------
static __device__ __forceinline__ void tap4(const unsigned* __restrict__ row32,
                                            int idx, int sh,
                                            unsigned &o0, unsigned &o1){
  int a0 = idx & ~3;
  const uint2* row = (const uint2*)row32;
  uint2 q0 = row[a0 >> 2];
  uint2 q1 = row[((a0 + 4) & 1023) >> 2];
  if (sh == 0){ o0 = q0.x; o1 = q0.y; }
  else if (sh == 1){ o0 = (q0.x >> 16) | (q0.y << 16); o1 = (q0.y >> 16) | (q1.x << 16); }
  else if (sh == 2){ o0 = q0.y; o1 = q1.x; }
  else { o0 = (q0.y >> 16) | (q1.x << 16); o1 = (q1.x >> 16) | (q1.y << 16); }
}

// ---------------- S3: diag 9-tap via LDS-staged W rows + softmax -> AR ----------
__global__ __launch_bounds__(256) void prop_softmax_diag(const unsigned short* __restrict__ W,
                                                         const float* __restrict__ eps,
                                                         const float* __restrict__ rn,
                                                         unsigned short* __restrict__ AR){
  __shared__ __align__(16) unsigned short Wl[9][1024];   // 18 KB
  __shared__ float redm[4], reds[4];
  int bid = blockIdx.x;                // 8192: b = bid&7
  int b = bid & 7, p = bid >> 3;
  int py = p >> 5, px = p & 31;
  const unsigned short* Wb = W + (size_t)b * NQ * L;
  int tid = threadIdx.x, lane = tid & 63, wv = tid >> 6;
  #pragma unroll
  for (int k = 0; k < 5; k++){
    int u = k * 4 + wv;
    if (u < 18){
      int s = u >> 1, half = u & 1;
      int qs = (py + s / 3) * 34 + (px + s % 3);
      GLDS16(Wb + (((size_t)qs) << 10) + half * 512 + lane * 8, &Wl[s][half * 512]);
    }
  }
  float epsv = eps[b * L + p];           // block-uniform scalar
  __syncthreads();
  int l0 = tid * 4;
  int ly = l0 >> 5, lx0 = l0 & 31;
  float4 rnl = *(const float4*)&rn[b * L + l0];
  float a[4] = {0.f, 0.f, 0.f, 0.f};
  #pragma unroll
  for (int s = 0; s < 9; s++){
    const int dy = s / 3 - 1, dx = s % 3 - 1;
    const int dlt = dy * 32 + dx;
    const int sh = dlt & 3;
    bool rok = (unsigned)(ly + dy) < HW;
    int idx = (l0 + dlt) & 1023;
    unsigned o0, o1;
    tap4((const unsigned*)&Wl[s][0], idx, sh, o0, o1);
    float f0 = __uint_as_float(o0 << 16), f1 = __uint_as_float(o0 & 0xffff0000u);
    float f2 = __uint_as_float(o1 << 16), f3 = __uint_as_float(o1 & 0xffff0000u);
    a[0] += (rok && (unsigned)(lx0 + 0 + dx) < HW) ? f0 : 0.f;
    a[1] += (rok && (unsigned)(lx0 + 1 + dx) < HW) ? f1 : 0.f;
    a[2] += (rok && (unsigned)(lx0 + 2 + dx) < HW) ? f2 : 0.f;
    a[3] += (rok && (unsigned)(lx0 + 3 + dx) < HW) ? f3 : 0.f;
  }
  float val[4];
  val[0] = rnl.x * (a[0] + epsv); val[1] = rnl.y * (a[1] + epsv);
  val[2] = rnl.z * (a[2] + epsv); val[3] = rnl.w * (a[3] + epsv);
  float m = fmaxf(fmaxf(val[0], val[1]), fmaxf(val[2], val[3]));
  #pragma unroll
  for (int off = 32; off; off >>= 1) m = fmaxf(m, __shfl_xor(m, off));
  if (lane == 0) redm[wv] = m;
  __syncthreads();
  m = fmaxf(fmaxf(redm[0], redm[1]), fmaxf(redm[2], redm[3]));
  float e[4], t = 0.f;
  #pragma unroll
  for (int j = 0; j < 4; j++){ e[j] = __expf(val[j] - m); t += e[j]; }
  #pragma unroll
  for (int off = 32; off; off >>= 1) t += __shfl_xor(t, off);
  if (lane == 0) reds[wv] = t;
  __syncthreads();
  t = reds[0] + reds[1] + reds[2] + reds[3];
  float inv = 1.f / t;
  unsigned short* O = AR + ((size_t)b << 20) + ((size_t)p << 10);
  ushort4 ov;
  ov.x = f2bf(e[0] * inv * rnl.x); ov.y = f2bf(e[1] * inv * rnl.y);
  ov.z = f2bf(e[2] * inv * rnl.z); ov.w = f2bf(e[3] * inv * rnl.w);
  *(ushort4*)&O[l0] = ov;
}

// ---------------- S4: U[p][v] = sum_s gated AR[p+ds][v+ds] via LDS staging ------
__global__ __launch_bounds__(256) void u_stencil(const unsigned short* __restrict__ AR,
                                                 unsigned short* __restrict__ U){
  __shared__ __align__(16) unsigned short Al[9][1024];   // 18 KB
  int bid = blockIdx.x;                // 8192: b = bid&7
  int b = bid & 7, p = bid >> 3;
  int py = p >> 5, px = p & 31;
  int tid = threadIdx.x, lane = tid & 63, wv = tid >> 6;
  const unsigned short* A = AR + ((size_t)b << 20);
  #pragma unroll
  for (int k = 0; k < 5; k++){
    int u = k * 4 + wv;
    if (u < 18){
      int s = u >> 1, half = u & 1;
      int yy = py + s / 3 - 1, xx = px + s % 3 - 1;
      bool rok = ((unsigned)yy < HW) && ((unsigned)xx < HW);
      int p2 = rok ? (yy * HW + xx) : 0;
      GLDS16(A + (((size_t)p2) << 10) + half * 512 + lane * 8, &Al[s][half * 512]);
    }
  }
  int rowmask = 0;
  #pragma unroll
  for (int s = 0; s < 9; s++){
    int yy = py + s / 3 - 1, xx = px + s % 3 - 1;
    if (((unsigned)yy < HW) && ((unsigned)xx < HW)) rowmask |= 1 << s;
  }
  __syncthreads();
  int v0 = tid * 4;
  int vy = v0 >> 5, vx0 = v0 & 31;
  float acc[4] = {0.f, 0.f, 0.f, 0.f};
  #pragma unroll
  for (int s = 0; s < 9; s++){
    const int dy = s / 3 - 1, dx = s % 3 - 1;
    const int dlt = dy * 32 + dx;
    const int sh = dlt & 3;
    bool rok = ((rowmask >> s) & 1) && ((unsigned)(vy + dy) < HW);
    int idx = (v0 + dlt) & 1023;
    unsigned o0, o1;
    tap4((const unsigned*)&Al[s][0], idx, sh, o0, o1);
    float f0 = __uint_as_float(o0 << 16), f1 = __uint_as_float(o0 & 0xffff0000u);
    float f2 = __uint_as_float(o1 << 16), f3 = __uint_as_float(o1 & 0xffff0000u);
    acc[0] += (rok && (unsigned)(vx0 + 0 + dx) < HW) ? f0 : 0.f;
    acc[1] += (rok && (unsigned)(vx0 + 1 + dx) < HW) ? f1 : 0.f;
    acc[2] += (rok && (unsigned)(vx0 + 2 + dx) < HW) ? f2 : 0.f;
    acc[3] += (rok && (unsigned)(vx0 + 3 + dx) < HW) ? f3 : 0.f;
  }
  unsigned short* O = U + ((size_t)b << 20) + ((size_t)p << 10);
  ushort4 ov;
  ov.x = f2bf(acc[0]); ov.y = f2bf(acc[1]); ov.z = f2bf(acc[2]); ov.w = f2bf(acc[3]);
  *(ushort4*)&O[v0] = ov;
}

// ---------------- G2: finalT[p][c] = mask? (U.mbgS)/9 : fgT  (32-row tiles) -----
__global__ __launch_bounds__(256) void gemm3_final(const unsigned short* __restrict__ U,
                                                   const unsigned short* __restrict__ mbgS,
                                                   const float* __restrict__ mask,
                                                   const unsigned short* __restrict__ fgT,
                                                   unsigned short* __restrict__ finalT){
  __shared__ unsigned short As[2][32][64];   // 8 KB
  __shared__ unsigned short Bs[2][64][64];   // 16 KB
  int bid = blockIdx.x;                // 1024: b = bid&7
  int b = bid & 7, r = bid >> 3;       // r in [0,128)
  int mt = r >> 2, ct = r & 3;         // mt 0..31
  int tid = threadIdx.x, lane = tid & 63, wv = tid >> 6;
  int wm = (wv & 1) * 16, wn = (wv >> 1) * 32;
  int rsel = lane & 15;
  int srow = lane >> 3, scol = ((lane & 7) ^ srow) * 8;
  const unsigned short* Ab = U    + ((size_t)b * L + mt * 32) * L;
  const unsigned short* Bb = mbgS + ((size_t)b * C_IN + ct * 64) * L;
  GLDS16(Ab + (size_t)(wv * 8 + srow) * L + scol, &As[0][wv * 8][0]);
  #pragma unroll
  for (int g8 = 0; g8 < 2; g8++)
    GLDS16(Bb + (size_t)(wv * 16 + g8 * 8 + srow) * L + scol, &Bs[0][wv * 16 + g8 * 8][0]);
  __syncthreads();
  f32x4 acc[2] = {};
  int cur = 0;
  for (int t = 0; t < 16; ++t){
    short8 af[2], bf[2][2];
    #pragma unroll
    for (int kk = 0; kk < 2; kk++){
      int s0 = kk * 4 + (lane >> 4);
      int col = ((s0 ^ (rsel & 7)) << 3);
      af[kk] = *(const short8*)&As[cur][wm + rsel][col];
      bf[kk][0] = *(const short8*)&Bs[cur][wn + rsel][col];
      bf[kk][1] = *(const short8*)&Bs[cur][wn + 16 + rsel][col];
    }
    if (t + 1 < 16){
      int nb = cur ^ 1;
      size_t kt = (size_t)(t + 1) * 64;
      GLDS16(Ab + (size_t)(wv * 8 + srow) * L + kt + scol, &As[nb][wv * 8][0]);
      #pragma unroll
      for (int g8 = 0; g8 < 2; g8++)
        GLDS16(Bb + (size_t)(wv * 16 + g8 * 8 + srow) * L + kt + scol, &Bs[nb][wv * 16 + g8 * 8][0]);
    }
    #pragma unroll
    for (int kk = 0; kk < 2; kk++)
      #pragma unroll
      for (int j = 0; j < 2; j++)
        acc[j] = __builtin_amdgcn_mfma_f32_16x16x32_bf16(af[kk], bf[kk][j], acc[j], 0, 0, 0);
    __syncthreads();
    cur ^= 1;
  }
  int rowb = (lane >> 4) * 4, col = lane & 15;
  #pragma unroll
  for (int j = 0; j < 2; j++)
    #pragma unroll
    for (int r2 = 0; r2 < 4; r2++){
      int p = mt * 32 + wm + rowb + r2;
      int c = ct * 64 + wn + j * 16 + col;
      unsigned short o;
      if (mask[p] != 0.f) o = f2bf(acc[j][r2] * (1.f / 9.f));
      else                o = fgT[((size_t)b * L + p) * C_IN + c];
      finalT[((size_t)b * L + p) * C_IN + c] = o;
    }
}

// ---------------- K4: branch convs as shifted GEMM (32-row tiles) ---------------
__global__ __launch_bounds__(256) void branch_gemm(const unsigned short* __restrict__ finalT,
                                                   const unsigned short* __restrict__ Wr,
                                                   const float* __restrict__ conv_b,
                                                   const unsigned short* __restrict__ zpage,
                                                   float* __restrict__ out){
  __shared__ unsigned short As[2][32][64];   // 8 KB
  __shared__ unsigned short Bs[2][64][64];   // 16 KB
  int nwg = gridDim.x, bid = blockIdx.x;     // 1024
  int nid = (bid & 7) * (nwg >> 3) + (bid >> 3);   // XCD-affine
  int bg = nid >> 5, pt = nid & 31;
  int b = bg >> 2, g = bg & 3;
  int rate = 1 << g;
  int p0 = pt * 32;
  int tid = threadIdx.x, lane = tid & 63, wv = tid >> 6;
  int wm = (wv & 1) * 16, wn = (wv >> 1) * 32;
  int rsel = lane & 15;
  int srow = lane >> 3;
  int scol = ((lane & 7) ^ srow) * 8;
  const unsigned short* FT = finalT + (size_t)b * L * C_IN;
  const unsigned short* WG = Wr + (size_t)(g * 9) * 64 * C_IN;

  int prow = p0 + wv * 8 + srow;
  int ayy = prow >> 5, axx = prow & 31;
  auto a_src = [&](int t) -> const unsigned short* {
    int s = t >> 2, q = t & 3;
    int dy = s / 3 - 1, dx = s - (s / 3) * 3 - 1;
    int iy = ayy + rate * dy, ix = axx + rate * dx;
    if ((unsigned)iy < HW && (unsigned)ix < HW)
      return FT + (size_t)(iy * HW + ix) * C_IN + q * 64 + scol;
    return zpage;
  };
  auto b_src = [&](int t, int g8) -> const unsigned short* {
    int s = t >> 2, q = t & 3;
    int n = wv * 16 + g8 * 8 + srow;
    return WG + (size_t)(s * 64 + n) * C_IN + q * 64 + scol;
  };

  f32x4 acc[2] = {};
  GLDS16(a_src(0), &As[0][wv * 8][0]);
  GLDS16(b_src(0, 0), &Bs[0][wv * 16][0]);
  GLDS16(b_src(0, 1), &Bs[0][wv * 16 + 8][0]);
  __syncthreads();
  int cur = 0;
  for (int t = 0; t < 36; ++t){
    short8 af[2], bf[2][2];
    #pragma unroll
    for (int kk = 0; kk < 2; kk++){
      int s0 = kk * 4 + (lane >> 4);
      int col = ((s0 ^ (rsel & 7)) << 3);
      af[kk] = *(const short8*)&As[cur][wm + rsel][col];
      bf[kk][0] = *(const short8*)&Bs[cur][wn + rsel][col];
      bf[kk][1] = *(const short8*)&Bs[cur][wn + 16 + rsel][col];
    }
    if (t + 1 < 36){
      int nb = cur ^ 1;
      GLDS16(a_src(t + 1), &As[nb][wv * 8][0]);
      GLDS16(b_src(t + 1, 0), &Bs[nb][wv * 16][0]);
      GLDS16(b_src(t + 1, 1), &Bs[nb][wv * 16 + 8][0]);
    }
    #pragma unroll
    for (int kk = 0; kk < 2; kk++)
      #pragma unroll
      for (int j = 0; j < 2; j++)
        acc[j] = __builtin_amdgcn_mfma_f32_16x16x32_bf16(af[kk], bf[kk][j], acc[j], 0, 0, 0);
    __syncthreads();
    cur ^= 1;
  }
  int rowb = (lane >> 4) * 4, col = lane & 15;
  float* O = out + (size_t)(b * 256 + g * 64) * L;
  #pragma unroll
  for (int j = 0; j < 2; j++){
    int n = wn + j * 16 + col;
    float bias = conv_b[g * 64 + n];
    #pragma unroll
    for (int r2 = 0; r2 < 4; r2++){
      int p = p0 + wm + rowb + r2;
      O[(size_t)n * L + p] = fmaxf(acc[j][r2] + bias, 0.f);
    }
  }
}

// ---------------- workspace layout (bytes) --------------------------------------
// [0,        16777216) : D    (8*1024*1024 bf16)
// [16777216, 35717120) : W    (8*1156*1024 bf16)
// [35717120, 52494336) : AR   (8*1024*1024 bf16)
// [52494336, 69271552) : U    (8*1024*1024 bf16)
// [69271552, 73465856) : mbgT (8*1024*256 bf16)
// [73465856, 77660160) : mbgS (8*256*1024 bf16)
// [77660160, 81854464) : finalT (8*1024*256 bf16)
// [81854464, 83034112) : Wr   (4*9*64*256 bf16)
// [83034112, 83427328) : psum (4*3*8192 f32, written unconditionally — no init)
// [83427328, 83460096) : rn   (8*1024 f32)
// [83460096, 83492864) : eps  (8*1024 f32)
// [83492864, 83493376) : zpage (512 B)
// fgT lives in d_out[0 .. 4.2MB) (d_out only written by branch_gemm at the end)

extern "C" void kernel_launch(void* const* d_in, const int* in_sizes, int n_in,
                              void* d_out, int out_size, void* d_ws, size_t ws_size,
                              hipStream_t stream){
  const float* fg     = (const float*)d_in[0];
  const float* mask   = (const float*)d_in[1];
  const float* bgd    = (const float*)d_in[2];
  const float* conv_w = (const float*)d_in[3];
  const float* conv_b = (const float*)d_in[4];

  char* ws = (char*)d_ws;
  unsigned short* D      = (unsigned short*)(ws + 0);
  unsigned short* W      = (unsigned short*)(ws + 16777216);
  unsigned short* AR     = (unsigned short*)(ws + 35717120);
  unsigned short* U      = (unsigned short*)(ws + 52494336);
  unsigned short* mbgT   = (unsigned short*)(ws + 69271552);
  unsigned short* mbgS   = (unsigned short*)(ws + 73465856);
  unsigned short* finalT = (unsigned short*)(ws + 77660160);
  unsigned short* Wr     = (unsigned short*)(ws + 81854464);
  float*          psum   = (float*)(ws + 83034112);
  float*          rn     = (float*)(ws + 83427328);
  float*          eps    = (float*)(ws + 83460096);
  unsigned short* zpage  = (unsigned short*)(ws + 83492864);
  unsigned short* fgT    = (unsigned short*)d_out;
  float* out = (float*)d_out;

  transpose_pack<<<dim3(16, 4, 8), 256, 0, stream>>>(fg, bgd, mask, fgT, mbgT, mbgS, psum);
  prep_misc<<<2336, 256, 0, stream>>>(psum, rn, eps, conv_w, Wr, zpage);

  gemm_d<<<2048, 256, 0, stream>>>(fgT, mbgT, D);
  box3<<<9248, 256, 0, stream>>>(D, W);
  prop_softmax_diag<<<8192, 256, 0, stream>>>(W, eps, rn, AR);
  u_stencil<<<8192, 256, 0, stream>>>(AR, U);
  gemm3_final<<<1024, 256, 0, stream>>>(U, mbgS, mask, fgT, finalT);
  branch_gemm<<<1024, 256, 0, stream>>>(finalT, Wr, conv_b, zpage, out);
}

// Round 10
// 118.931 us; speedup vs baseline: 3.3982x; 1.0070x over previous
//
#include <hip/hip_runtime.h>

typedef __attribute__((ext_vector_type(8))) short short8;
typedef __attribute__((ext_vector_type(4))) float f32x4;

#define HW 32
#define L 1024        // HW*HW
#define C_IN 256
#define BATCH 8
#define NQ 1156       // 34*34 extended grid

static __device__ __forceinline__ unsigned short f2bf(float f){
  unsigned int u = __float_as_uint(f);
  unsigned int r = (u + 0x7FFFu + ((u >> 16) & 1u)) >> 16;   // RNE (no NaN inputs)
  return (unsigned short)r;
}
static __device__ __forceinline__ float bf2f(unsigned short h){
  return __uint_as_float(((unsigned int)h) << 16);
}

#define GLDS16(g, l) __builtin_amdgcn_global_load_lds(                          \
    (const __attribute__((address_space(1))) void*)(g),                         \
    (__attribute__((address_space(3))) void*)(l), 16, 0, 0)

// ---------------- D1: transposes + moment partials (blocks 0..511)  +  Wr prep --
// psum layout: [cb 0..3][j 0..2][b*L+p]  (j: 0=rsum_fg, 1=S1_mbg, 2=S2_mbg)
__global__ __launch_bounds__(256) void fused_prep(const float* __restrict__ fg,
                                                  const float* __restrict__ bgd,
                                                  const float* __restrict__ mask,
                                                  unsigned short* __restrict__ fgT,
                                                  unsigned short* __restrict__ mbgT,
                                                  unsigned short* __restrict__ mbgS,
                                                  float* __restrict__ psum,
                                                  const float* __restrict__ conv_w,
                                                  unsigned short* __restrict__ Wr,
                                                  unsigned short* __restrict__ zpage){
  __shared__ float T[64][65];
  __shared__ float ps[3][4][64];
  int blk = blockIdx.x;
  if (blk >= 512){
    if (blk == 512) zpage[threadIdx.x] = 0;    // 512 B zero page
    int idx = (blk - 512) * 256 + threadIdx.x; // 589824 Wr elements
    int c = idx & 255;
    int rest = idx >> 8;
    int n = rest & 63;
    int sg = rest >> 6;
    int s = sg % 9, g = sg / 9;
    Wr[idx] = f2bf(conv_w[(((size_t)(g * 64 + n)) * C_IN + c) * 9 + s]);
    return;
  }
  int bx = blk & 15, cb = (blk >> 4) & 3, b = blk >> 6;
  int p0 = bx * 64, c0 = cb * 64;
  int tx = threadIdx.x & 63, ty = threadIdx.x >> 6;
  const float* F = fg  + ((size_t)b * C_IN + c0) * L + p0;
  const float* G = bgd + ((size_t)b * C_IN + c0) * L + p0;
  float sf = 0.f;
  for (int cc = ty; cc < 64; cc += 4){
    float v = F[(size_t)cc * L + tx];
    T[cc][tx] = v; sf += v;
  }
  ps[0][ty][tx] = sf;
  __syncthreads();
  for (int pp = ty; pp < 64; pp += 4)
    fgT[(size_t)(b * L + p0 + pp) * C_IN + c0 + tx] = f2bf(T[tx][pp]);
  if (ty == 0)
    psum[(size_t)(cb * 3 + 0) * (BATCH * L) + b * L + p0 + tx] =
        ps[0][0][tx] + ps[0][1][tx] + ps[0][2][tx] + ps[0][3][tx];
  __syncthreads();
  float mm = 1.f - mask[p0 + tx];
  float s1 = 0.f, s2 = 0.f;
  for (int cc = ty; cc < 64; cc += 4){
    float v = G[(size_t)cc * L + tx] * mm;
    T[cc][tx] = v; s1 += v; s2 += v * v;
    mbgS[((size_t)b * C_IN + c0 + cc) * L + p0 + tx] = f2bf(v);
  }
  ps[1][ty][tx] = s1; ps[2][ty][tx] = s2;
  __syncthreads();
  for (int pp = ty; pp < 64; pp += 4)
    mbgT[(size_t)(b * L + p0 + pp) * C_IN + c0 + tx] = f2bf(T[tx][pp]);
  if (ty == 0){
    psum[(size_t)(cb * 3 + 1) * (BATCH * L) + b * L + p0 + tx] =
        ps[1][0][tx] + ps[1][1][tx] + ps[1][2][tx] + ps[1][3][tx];
    psum[(size_t)(cb * 3 + 2) * (BATCH * L) + b * L + p0 + tx] =
        ps[2][0][tx] + ps[2][1][tx] + ps[2][2][tx] + ps[2][3][tx];
  }
}

// ---------------- D2: gemm_d (blocks 0..2047) + rn/eps (blocks 2048..2079) ------
__global__ __launch_bounds__(256) void gemm_d_rn(const unsigned short* __restrict__ fgT,
                                                 const unsigned short* __restrict__ mbgT,
                                                 unsigned short* __restrict__ D,
                                                 const float* __restrict__ psum,
                                                 float* __restrict__ rn,
                                                 float* __restrict__ eps){
  __shared__ unsigned short As[64][256];   // 32 KB
  __shared__ unsigned short Bs[64][256];   // 32 KB
  int bid = blockIdx.x;
  if (bid >= 2048){
    int idx = (bid - 2048) * 256 + threadIdx.x;  // 8192
    int b = idx >> 10, l = idx & 1023;
    int ly = l >> 5, lx = l & 31;
    const int NP = BATCH * L;
    float n2 = 2.304e-11f;                       // 2304 * 1e-14
    #pragma unroll
    for (int s = 0; s < 9; s++){
      int y = ly + s / 3 - 1, x = lx + s % 3 - 1;
      if ((unsigned)y < HW && (unsigned)x < HW){
        int q = b * L + y * HW + x;
        float s1 = 0.f, s2 = 0.f;
        #pragma unroll
        for (int k = 0; k < 4; k++){
          s1 += psum[(size_t)(k * 3 + 1) * NP + q];
          s2 += psum[(size_t)(k * 3 + 2) * NP + q];
        }
        n2 += s2 + 2e-7f * s1;
      }
    }
    rn[idx] = 1.f / sqrtf(n2);
    float ev = 0.f;
    const int tw[5] = {1, 2, 3, 2, 1};
    #pragma unroll
    for (int oy = -2; oy <= 2; oy++)
      #pragma unroll
      for (int ox = -2; ox <= 2; ox++){
        int y = ly + oy, x = lx + ox;
        if ((unsigned)y < HW && (unsigned)x < HW){
          int q = b * L + y * HW + x;
          float s0 = 0.f;
          #pragma unroll
          for (int k = 0; k < 4; k++) s0 += psum[(size_t)(k * 3 + 0) * NP + q];
          ev += (float)(tw[oy + 2] * tw[ox + 2]) * s0;
        }
      }
    eps[idx] = 1e-7f * ev;
    return;
  }
  int b = bid & 7, r = bid >> 3;       // XCD-affine
  int by = r >> 4, bx = r & 15;
  const unsigned short* Ab = fgT  + ((size_t)b * L + by * 64) * C_IN;
  const unsigned short* Bb = mbgT + ((size_t)b * L + bx * 64) * C_IN;
  int tid = threadIdx.x, lane = tid & 63, wv = tid >> 6;
  int row_off = lane >> 5, slot = lane & 31;
  int q = slot >> 3, sl = slot & 7;
  #pragma unroll
  for (int i = 0; i < 8; i++){
    int rr = wv * 16 + i * 2 + row_off;
    int srcs = q * 8 + (sl ^ (rr & 7));
    GLDS16(Ab + (size_t)rr * C_IN + srcs * 8, &As[wv * 16 + i * 2][0]);
    GLDS16(Bb + (size_t)rr * C_IN + srcs * 8, &Bs[wv * 16 + i * 2][0]);
  }
  __syncthreads();
  int wm = (wv & 1) * 32, wn = (wv >> 1) * 32;
  int rsel = lane & 15, sx = lane >> 4;
  f32x4 acc[2][2] = {};
  #pragma unroll
  for (int st = 0; st < 8; st++){
    int gs = st * 4 + sx, qq = gs >> 3, ss = gs & 7;
    short8 af[2], bf[2];
    #pragma unroll
    for (int i = 0; i < 2; i++){
      int ra = wm + i * 16 + rsel;
      af[i] = *(const short8*)&As[ra][(qq * 8 + (ss ^ (ra & 7))) * 8];
      int rb = wn + i * 16 + rsel;
      bf[i] = *(const short8*)&Bs[rb][(qq * 8 + (ss ^ (rb & 7))) * 8];
    }
    #pragma unroll
    for (int i = 0; i < 2; i++)
      #pragma unroll
      for (int j = 0; j < 2; j++)
        acc[i][j] = __builtin_amdgcn_mfma_f32_16x16x32_bf16(af[i], bf[j], acc[i][j], 0, 0, 0);
  }
  unsigned short* Db = D + ((size_t)b << 20);
  int rowb = (lane >> 4) * 4, col = lane & 15;
  #pragma unroll
  for (int i = 0; i < 2; i++)
    #pragma unroll
    for (int j = 0; j < 2; j++)
      #pragma unroll
      for (int r2 = 0; r2 < 4; r2++)
        Db[(size_t)(by * 64 + wm + i * 16 + rowb + r2) * L + bx * 64 + wn + j * 16 + col] = f2bf(acc[i][j][r2]);
}

// ---------------- S2: W[b][q][v] = 3x3 box of D over u (bf16 in/out) ------------
__global__ __launch_bounds__(256) void box3(const unsigned short* __restrict__ D,
                                            unsigned short* __restrict__ W){
  int bid = blockIdx.x;                // 9248 = 8*1156: b = bid&7
  int b = bid & 7, q2 = bid >> 3;
  int qy = q2 / 34 - 1, qx = q2 % 34 - 1;
  const unsigned short* Db = D + ((size_t)b << 20);
  int tid = threadIdx.x;
  float a0 = 0.f, a1 = 0.f, a2 = 0.f, a3 = 0.f;
  #pragma unroll
  for (int dy = -1; dy <= 1; dy++)
    #pragma unroll
    for (int dx = -1; dx <= 1; dx++){
      int y = qy + dy, x = qx + dx;
      if ((unsigned)y < HW && (unsigned)x < HW){
        ushort4 v = *(const ushort4*)(Db + ((size_t)(y * HW + x) << 10) + tid * 4);
        a0 += bf2f(v.x); a1 += bf2f(v.y); a2 += bf2f(v.z); a3 += bf2f(v.w);
      }
    }
  ushort4 o;
  o.x = f2bf(a0); o.y = f2bf(a1); o.z = f2bf(a2); o.w = f2bf(a3);
  *(ushort4*)(W + ((size_t)(b * NQ + q2) << 10) + tid * 4) = o;
}

// ------- vector tap read: 4 bf16 at idx..idx+3 from a 1024-elem LDS row ---------
static __device__ __forceinline__ void tap4(const unsigned* __restrict__ row32,
                                            int idx, int sh,
                                            unsigned &o0, unsigned &o1){
  int a0 = idx & ~3;
  const uint2* row = (const uint2*)row32;
  uint2 q0 = row[a0 >> 2];
  uint2 q1 = row[((a0 + 4) & 1023) >> 2];
  if (sh == 0){ o0 = q0.x; o1 = q0.y; }
  else if (sh == 1){ o0 = (q0.x >> 16) | (q0.y << 16); o1 = (q0.y >> 16) | (q1.x << 16); }
  else if (sh == 2){ o0 = q0.y; o1 = q1.x; }
  else { o0 = (q0.y >> 16) | (q1.x << 16); o1 = (q1.x >> 16) | (q1.y << 16); }
}

// ---------------- S3: 2x2 p-tile: diag 9-tap + softmax -> AR --------------------
__global__ __launch_bounds__(256) void prop_softmax_diag(const unsigned short* __restrict__ W,
                                                         const float* __restrict__ eps,
                                                         const float* __restrict__ rn,
                                                         unsigned short* __restrict__ AR){
  __shared__ __align__(16) unsigned short Wl[16][1024];   // 32 KB
  __shared__ float redm[4][4], reds[4][4];
  int bid = blockIdx.x;                // 2048: b = bid&7
  int b = bid & 7, tile = bid >> 3;    // 256 tiles of 2x2
  int py0 = (tile >> 4) * 2, px0 = (tile & 15) * 2;
  const unsigned short* Wb = W + (size_t)b * NQ * L;
  int tid = threadIdx.x, lane = tid & 63, wv = tid >> 6;
  // stage 16 W rows: q_ext = (py0+ryi, px0+rxi), ryi,rxi in 0..3 (always valid ext rows)
  #pragma unroll
  for (int k = 0; k < 8; k++){
    int u = k * 4 + wv;                // 0..31 half-row units
    int rr = u >> 1, half = u & 1;
    int qs = (py0 + (rr >> 2)) * 34 + (px0 + (rr & 3));
    GLDS16(Wb + (((size_t)qs) << 10) + half * 512 + lane * 8, &Wl[rr][half * 512]);
  }
  int l0 = tid * 4;
  int ly = l0 >> 5, lx0 = l0 & 31;
  float4 rnl = *(const float4*)&rn[b * L + l0];
  float ev[4];
  #pragma unroll
  for (int o = 0; o < 4; o++)
    ev[o] = eps[b * L + (py0 + (o >> 1)) * HW + (px0 + (o & 1))];
  __syncthreads();
  float val[4][4];
  #pragma unroll
  for (int o = 0; o < 4; o++){
    int oy = o >> 1, ox = o & 1;
    float a[4] = {0.f, 0.f, 0.f, 0.f};
    #pragma unroll
    for (int s = 0; s < 9; s++){
      const int dy = s / 3 - 1, dx = s % 3 - 1;
      const int dlt = dy * 32 + dx;
      const int sh = dlt & 3;
      bool rok = (unsigned)(ly + dy) < HW;
      int idx = (l0 + dlt) & 1023;
      unsigned o0, o1;
      tap4((const unsigned*)&Wl[(oy + dy + 1) * 4 + (ox + dx + 1)][0], idx, sh, o0, o1);
      float f0 = __uint_as_float(o0 << 16), f1 = __uint_as_float(o0 & 0xffff0000u);
      float f2 = __uint_as_float(o1 << 16), f3 = __uint_as_float(o1 & 0xffff0000u);
      a[0] += (rok && (unsigned)(lx0 + 0 + dx) < HW) ? f0 : 0.f;
      a[1] += (rok && (unsigned)(lx0 + 1 + dx) < HW) ? f1 : 0.f;
      a[2] += (rok && (unsigned)(lx0 + 2 + dx) < HW) ? f2 : 0.f;
      a[3] += (rok && (unsigned)(lx0 + 3 + dx) < HW) ? f3 : 0.f;
    }
    val[o][0] = rnl.x * (a[0] + ev[o]); val[o][1] = rnl.y * (a[1] + ev[o]);
    val[o][2] = rnl.z * (a[2] + ev[o]); val[o][3] = rnl.w * (a[3] + ev[o]);
  }
  #pragma unroll
  for (int o = 0; o < 4; o++){
    float m = fmaxf(fmaxf(val[o][0], val[o][1]), fmaxf(val[o][2], val[o][3]));
    #pragma unroll
    for (int off = 32; off; off >>= 1) m = fmaxf(m, __shfl_xor(m, off));
    if (lane == 0) redm[wv][o] = m;
  }
  __syncthreads();
  float mf[4];
  #pragma unroll
  for (int o = 0; o < 4; o++)
    mf[o] = fmaxf(fmaxf(redm[0][o], redm[1][o]), fmaxf(redm[2][o], redm[3][o]));
  float e[4][4];
  #pragma unroll
  for (int o = 0; o < 4; o++){
    float t = 0.f;
    #pragma unroll
    for (int j = 0; j < 4; j++){ e[o][j] = __expf(val[o][j] - mf[o]); t += e[o][j]; }
    #pragma unroll
    for (int off = 32; off; off >>= 1) t += __shfl_xor(t, off);
    if (lane == 0) reds[wv][o] = t;
  }
  __syncthreads();
  #pragma unroll
  for (int o = 0; o < 4; o++){
    float inv = 1.f / (reds[0][o] + reds[1][o] + reds[2][o] + reds[3][o]);
    int p = (py0 + (o >> 1)) * HW + (px0 + (o & 1));
    unsigned short* O = AR + ((size_t)b << 20) + ((size_t)p << 10);
    ushort4 ov;
    ov.x = f2bf(e[o][0] * inv * rnl.x); ov.y = f2bf(e[o][1] * inv * rnl.y);
    ov.z = f2bf(e[o][2] * inv * rnl.z); ov.w = f2bf(e[o][3] * inv * rnl.w);
    *(ushort4*)&O[l0] = ov;
  }
}

// ---------------- S4: 2x2 p-tile: U[p][v] = sum_s gated AR[p+ds][v+ds] ----------
__global__ __launch_bounds__(256) void u_stencil(const unsigned short* __restrict__ AR,
                                                 unsigned short* __restrict__ U){
  __shared__ __align__(16) unsigned short Al[16][1024];   // 32 KB
  int bid = blockIdx.x;                // 2048: b = bid&7
  int b = bid & 7, tile = bid >> 3;
  int py0 = (tile >> 4) * 2, px0 = (tile & 15) * 2;
  int tid = threadIdx.x, lane = tid & 63, wv = tid >> 6;
  const unsigned short* A = AR + ((size_t)b << 20);
  // stage 16 AR rows: p' = (py0+ryi-1, px0+rxi-1); OOB rows staged from 0, masked
  #pragma unroll
  for (int k = 0; k < 8; k++){
    int u = k * 4 + wv;
    int rr = u >> 1, half = u & 1;
    int yy = py0 + (rr >> 2) - 1, xx = px0 + (rr & 3) - 1;
    bool rok = ((unsigned)yy < HW) && ((unsigned)xx < HW);
    int p2 = rok ? (yy * HW + xx) : 0;
    GLDS16(A + (((size_t)p2) << 10) + half * 512 + lane * 8, &Al[rr][half * 512]);
  }
  int vmask = 0;
  #pragma unroll
  for (int rr = 0; rr < 16; rr++){
    int yy = py0 + (rr >> 2) - 1, xx = px0 + (rr & 3) - 1;
    if (((unsigned)yy < HW) && ((unsigned)xx < HW)) vmask |= 1 << rr;
  }
  __syncthreads();
  int v0 = tid * 4;
  int vy = v0 >> 5, vx0 = v0 & 31;
  #pragma unroll
  for (int o = 0; o < 4; o++){
    int oy = o >> 1, ox = o & 1;
    float acc[4] = {0.f, 0.f, 0.f, 0.f};
    #pragma unroll
    for (int s = 0; s < 9; s++){
      const int dy = s / 3 - 1, dx = s % 3 - 1;
      const int dlt = dy * 32 + dx;
      const int sh = dlt & 3;
      const int rr = (oy + dy + 1) * 4 + (ox + dx + 1);
      bool rok = ((vmask >> rr) & 1) && ((unsigned)(vy + dy) < HW);
      int idx = (v0 + dlt) & 1023;
      unsigned o0, o1;
      tap4((const unsigned*)&Al[rr][0], idx, sh, o0, o1);
      float f0 = __uint_as_float(o0 << 16), f1 = __uint_as_float(o0 & 0xffff0000u);
      float f2 = __uint_as_float(o1 << 16), f3 = __uint_as_float(o1 & 0xffff0000u);
      acc[0] += (rok && (unsigned)(vx0 + 0 + dx) < HW) ? f0 : 0.f;
      acc[1] += (rok && (unsigned)(vx0 + 1 + dx) < HW) ? f1 : 0.f;
      acc[2] += (rok && (unsigned)(vx0 + 2 + dx) < HW) ? f2 : 0.f;
      acc[3] += (rok && (unsigned)(vx0 + 3 + dx) < HW) ? f3 : 0.f;
    }
    int p = (py0 + oy) * HW + (px0 + ox);
    unsigned short* O = U + ((size_t)b << 20) + ((size_t)p << 10);
    ushort4 ov;
    ov.x = f2bf(acc[0]); ov.y = f2bf(acc[1]); ov.z = f2bf(acc[2]); ov.w = f2bf(acc[3]);
    *(ushort4*)&O[v0] = ov;
  }
}

// ---------------- G2: finalT[p][c] = mask? (U.mbgS)/9 : fgT  (64-row tiles) -----
__global__ __launch_bounds__(256) void gemm3_final(const unsigned short* __restrict__ U,
                                                   const unsigned short* __restrict__ mbgS,
                                                   const float* __restrict__ mask,
                                                   const unsigned short* __restrict__ fgT,
                                                   unsigned short* __restrict__ finalT){
  __shared__ unsigned short As[2][64][64];
  __shared__ unsigned short Bs[2][64][64];
  int bid = blockIdx.x;                // 512: b = bid&7
  int b = bid & 7, r = bid >> 3;       // r in [0,64)
  int mt = r >> 2, ct = r & 3;
  int tid = threadIdx.x, lane = tid & 63, wv = tid >> 6;
  int wm = (wv & 1) * 32, wn = (wv >> 1) * 32;
  int rsel = lane & 15;
  int srow = lane >> 3, scol = ((lane & 7) ^ srow) * 8;
  const unsigned short* Ab = U    + ((size_t)b * L + mt * 64) * L;
  const unsigned short* Bb = mbgS + ((size_t)b * C_IN + ct * 64) * L;
  #pragma unroll
  for (int g8 = 0; g8 < 2; g8++){
    GLDS16(Ab + (size_t)(wv * 16 + g8 * 8 + srow) * L + scol, &As[0][wv * 16 + g8 * 8][0]);
    GLDS16(Bb + (size_t)(wv * 16 + g8 * 8 + srow) * L + scol, &Bs[0][wv * 16 + g8 * 8][0]);
  }
  __syncthreads();
  f32x4 acc[2][2] = {};
  int cur = 0;
  for (int t = 0; t < 16; ++t){
    short8 af[2][2], bf[2][2];
    #pragma unroll
    for (int kk = 0; kk < 2; kk++){
      int s0 = kk * 4 + (lane >> 4);
      int col = ((s0 ^ (rsel & 7)) << 3);
      #pragma unroll
      for (int i = 0; i < 2; i++){
        af[kk][i] = *(const short8*)&As[cur][wm + i * 16 + rsel][col];
        bf[kk][i] = *(const short8*)&Bs[cur][wn + i * 16 + rsel][col];
      }
    }
    if (t + 1 < 16){
      int nb = cur ^ 1;
      size_t kt = (size_t)(t + 1) * 64;
      #pragma unroll
      for (int g8 = 0; g8 < 2; g8++){
        GLDS16(Ab + (size_t)(wv * 16 + g8 * 8 + srow) * L + kt + scol, &As[nb][wv * 16 + g8 * 8][0]);
        GLDS16(Bb + (size_t)(wv * 16 + g8 * 8 + srow) * L + kt + scol, &Bs[nb][wv * 16 + g8 * 8][0]);
      }
    }
    #pragma unroll
    for (int kk = 0; kk < 2; kk++)
      #pragma unroll
      for (int i = 0; i < 2; i++)
        #pragma unroll
        for (int j = 0; j < 2; j++)
          acc[i][j] = __builtin_amdgcn_mfma_f32_16x16x32_bf16(af[kk][i], bf[kk][j], acc[i][j], 0, 0, 0);
    __syncthreads();
    cur ^= 1;
  }
  int rowb = (lane >> 4) * 4, col = lane & 15;
  #pragma unroll
  for (int i = 0; i < 2; i++)
    #pragma unroll
    for (int j = 0; j < 2; j++)
      #pragma unroll
      for (int r2 = 0; r2 < 4; r2++){
        int p = mt * 64 + wm + i * 16 + rowb + r2;
        int c = ct * 64 + wn + j * 16 + col;
        unsigned short o;
        if (mask[p] != 0.f) o = f2bf(acc[i][j][r2] * (1.f / 9.f));
        else                o = fgT[((size_t)b * L + p) * C_IN + c];
        finalT[((size_t)b * L + p) * C_IN + c] = o;
      }
}

// ---------------- K4: branch convs as shifted GEMM (64-row tiles) ---------------
__global__ __launch_bounds__(256) void branch_gemm(const unsigned short* __restrict__ finalT,
                                                   const unsigned short* __restrict__ Wr,
                                                   const float* __restrict__ conv_b,
                                                   const unsigned short* __restrict__ zpage,
                                                   float* __restrict__ out){
  __shared__ unsigned short As[2][64][64];
  __shared__ unsigned short Bs[2][64][64];
  int nwg = gridDim.x, bid = blockIdx.x;     // 512
  int nid = (bid & 7) * (nwg >> 3) + (bid >> 3);   // XCD-affine
  int bg = nid >> 4, pt = nid & 15;
  int b = bg >> 2, g = bg & 3;
  int rate = 1 << g;
  int p0 = pt * 64;
  int tid = threadIdx.x, lane = tid & 63, wv = tid >> 6;
  int wm = (wv & 1) * 32, wn = (wv >> 1) * 32;
  int rsel = lane & 15;
  int srow = lane >> 3;
  int scol = ((lane & 7) ^ srow) * 8;
  const unsigned short* FT = finalT + (size_t)b * L * C_IN;
  const unsigned short* WG = Wr + (size_t)(g * 9) * 64 * C_IN;

  int ay[2], ax[2];
  #pragma unroll
  for (int g8 = 0; g8 < 2; g8++){
    int p = p0 + wv * 16 + g8 * 8 + srow;
    ay[g8] = p >> 5; ax[g8] = p & 31;
  }
  auto a_src = [&](int t, int g8) -> const unsigned short* {
    int s = t >> 2, q = t & 3;
    int dy = s / 3 - 1, dx = s - (s / 3) * 3 - 1;
    int iy = ay[g8] + rate * dy, ix = ax[g8] + rate * dx;
    if ((unsigned)iy < HW && (unsigned)ix < HW)
      return FT + (size_t)(iy * HW + ix) * C_IN + q * 64 + scol;
    return zpage;
  };
  auto b_src = [&](int t, int g8) -> const unsigned short* {
    int s = t >> 2, q = t & 3;
    int n = wv * 16 + g8 * 8 + srow;
    return WG + (size_t)(s * 64 + n) * C_IN + q * 64 + scol;
  };

  f32x4 acc[2][2] = {};
  #pragma unroll
  for (int g8 = 0; g8 < 2; g8++){
    GLDS16(a_src(0, g8), &As[0][wv * 16 + g8 * 8][0]);
    GLDS16(b_src(0, g8), &Bs[0][wv * 16 + g8 * 8][0]);
  }
  __syncthreads();
  int cur = 0;
  for (int t = 0; t < 36; ++t){
    short8 af[2][2], bf[2][2];
    #pragma unroll
    for (int kk = 0; kk < 2; kk++){
      int s0 = kk * 4 + (lane >> 4);
      int col = ((s0 ^ (rsel & 7)) << 3);
      #pragma unroll
      for (int i = 0; i < 2; i++){
        af[kk][i] = *(const short8*)&As[cur][wm + i * 16 + rsel][col];
        bf[kk][i] = *(const short8*)&Bs[cur][wn + i * 16 + rsel][col];
      }
    }
    if (t + 1 < 36){
      int nb = cur ^ 1;
      #pragma unroll
      for (int g8 = 0; g8 < 2; g8++){
        GLDS16(a_src(t + 1, g8), &As[nb][wv * 16 + g8 * 8][0]);
        GLDS16(b_src(t + 1, g8), &Bs[nb][wv * 16 + g8 * 8][0]);
      }
    }
    #pragma unroll
    for (int kk = 0; kk < 2; kk++)
      #pragma unroll
      for (int i = 0; i < 2; i++)
        #pragma unroll
        for (int j = 0; j < 2; j++)
          acc[i][j] = __builtin_amdgcn_mfma_f32_16x16x32_bf16(af[kk][i], bf[kk][j], acc[i][j], 0, 0, 0);
    __syncthreads();
    cur ^= 1;
  }
  int rowb = (lane >> 4) * 4, col = lane & 15;
  float* O = out + (size_t)(b * 256 + g * 64) * L;
  #pragma unroll
  for (int i = 0; i < 2; i++)
    #pragma unroll
    for (int j = 0; j < 2; j++){
      int n = wn + j * 16 + col;
      float bias = conv_b[g * 64 + n];
      #pragma unroll
      for (int r2 = 0; r2 < 4; r2++){
        int p = p0 + wm + i * 16 + rowb + r2;
        O[(size_t)n * L + p] = fmaxf(acc[i][j][r2] + bias, 0.f);
      }
    }
}

// ---------------- workspace layout (bytes) --------------------------------------
// [0,        16777216) : D    (8*1024*1024 bf16)
// [16777216, 35717120) : W    (8*1156*1024 bf16)
// [35717120, 52494336) : AR   (8*1024*1024 bf16)
// [52494336, 69271552) : U    (8*1024*1024 bf16)
// [69271552, 73465856) : mbgT (8*1024*256 bf16)
// [73465856, 77660160) : mbgS (8*256*1024 bf16)
// [77660160, 81854464) : finalT (8*1024*256 bf16)
// [81854464, 83034112) : Wr   (4*9*64*256 bf16)
// [83034112, 83427328) : psum (4*3*8192 f32, written unconditionally — no init)
// [83427328, 83460096) : rn   (8*1024 f32)
// [83460096, 83492864) : eps  (8*1024 f32)
// [83492864, 83493376) : zpage (512 B)
// fgT lives in d_out[0 .. 4.2MB) (d_out only written by branch_gemm at the end)

extern "C" void kernel_launch(void* const* d_in, const int* in_sizes, int n_in,
                              void* d_out, int out_size, void* d_ws, size_t ws_size,
                              hipStream_t stream){
  const float* fg     = (const float*)d_in[0];
  const float* mask   = (const float*)d_in[1];
  const float* bgd    = (const float*)d_in[2];
  const float* conv_w = (const float*)d_in[3];
  const float* conv_b = (const float*)d_in[4];

  char* ws = (char*)d_ws;
  unsigned short* D      = (unsigned short*)(ws + 0);
  unsigned short* W      = (unsigned short*)(ws + 16777216);
  unsigned short* AR     = (unsigned short*)(ws + 35717120);
  unsigned short* U      = (unsigned short*)(ws + 52494336);
  unsigned short* mbgT   = (unsigned short*)(ws + 69271552);
  unsigned short* mbgS   = (unsigned short*)(ws + 73465856);
  unsigned short* finalT = (unsigned short*)(ws + 77660160);
  unsigned short* Wr     = (unsigned short*)(ws + 81854464);
  float*          psum   = (float*)(ws + 83034112);
  float*          rn     = (float*)(ws + 83427328);
  float*          eps    = (float*)(ws + 83460096);
  unsigned short* zpage  = (unsigned short*)(ws + 83492864);
  unsigned short* fgT    = (unsigned short*)d_out;
  float* out = (float*)d_out;

  fused_prep<<<2816, 256, 0, stream>>>(fg, bgd, mask, fgT, mbgT, mbgS, psum,
                                       conv_w, Wr, zpage);
  gemm_d_rn<<<2080, 256, 0, stream>>>(fgT, mbgT, D, psum, rn, eps);
  box3<<<9248, 256, 0, stream>>>(D, W);
  prop_softmax_diag<<<2048, 256, 0, stream>>>(W, eps, rn, AR);
  u_stencil<<<2048, 256, 0, stream>>>(AR, U);
  gemm3_final<<<512, 256, 0, stream>>>(U, mbgS, mask, fgT, finalT);
  branch_gemm<<<512, 256, 0, stream>>>(finalT, Wr, conv_b, zpage, out);
}

// Round 11
// 108.764 us; speedup vs baseline: 3.7158x; 1.0935x over previous
//
#include <hip/hip_runtime.h>

typedef __attribute__((ext_vector_type(8))) short short8;
typedef __attribute__((ext_vector_type(4))) float f32x4;
typedef __attribute__((ext_vector_type(4))) unsigned int uint4v;

#define HW 32
#define L 1024        // HW*HW
#define C_IN 256
#define BATCH 8
#define NQ 1156       // 34*34 extended grid

static __device__ __forceinline__ unsigned short f2bf(float f){
  unsigned int u = __float_as_uint(f);
  unsigned int r = (u + 0x7FFFu + ((u >> 16) & 1u)) >> 16;   // RNE (no NaN inputs)
  return (unsigned short)r;
}
static __device__ __forceinline__ float bf2f(unsigned short h){
  return __uint_as_float(((unsigned int)h) << 16);
}

#define GLDS16(g, l) __builtin_amdgcn_global_load_lds(                          \
    (const __attribute__((address_space(1))) void*)(g),                         \
    (__attribute__((address_space(3))) void*)(l), 16, 0, 0)

// ---------------- D1: vectorized transposes + moment partials + Wr prep ---------
// psum layout: [cb 0..3][j 0..2][b*L+p]  (j: 0=rsum_fg, 1=S1_mbg, 2=S2_mbg)
__global__ __launch_bounds__(256) void fused_prep(const float* __restrict__ fg,
                                                  const float* __restrict__ bgd,
                                                  const float* __restrict__ mask,
                                                  unsigned short* __restrict__ fgT,
                                                  unsigned short* __restrict__ mbgT,
                                                  unsigned short* __restrict__ mbgS,
                                                  float* __restrict__ psum,
                                                  const float* __restrict__ conv_w,
                                                  unsigned short* __restrict__ Wr,
                                                  unsigned short* __restrict__ zpage){
  __shared__ float T[64][65];
  int blk = blockIdx.x;
  if (blk >= 512){
    if (blk == 512) zpage[threadIdx.x] = 0;    // 512 B zero page
    int idx = (blk - 512) * 256 + threadIdx.x; // 589824 Wr elements
    int c = idx & 255;
    int rest = idx >> 8;
    int n = rest & 63;
    int sg = rest >> 6;
    int s = sg % 9, g = sg / 9;
    Wr[idx] = f2bf(conv_w[(((size_t)(g * 64 + n)) * C_IN + c) * 9 + s]);
    return;
  }
  const int NP = BATCH * L;
  int bx = blk & 15, cb = (blk >> 4) & 3, b = blk >> 6;
  int p0 = bx * 64, c0 = cb * 64;
  int tid = threadIdx.x;
  int rr = tid >> 4, px = (tid & 15) * 4;      // read-phase coords
  int cx = tid & 15, ppb = tid >> 4;           // write-phase coords
  const float* F = fg  + ((size_t)b * C_IN + c0) * L + p0;
  const float* G = bgd + ((size_t)b * C_IN + c0) * L + p0;

  // ---- pass 1: fg ----
  #pragma unroll
  for (int it = 0; it < 4; it++){
    int cc = it * 16 + rr;
    float4 v = *(const float4*)(F + (size_t)cc * L + px);
    T[cc][px] = v.x; T[cc][px + 1] = v.y; T[cc][px + 2] = v.z; T[cc][px + 3] = v.w;
  }
  __syncthreads();
  #pragma unroll
  for (int it = 0; it < 4; it++){
    int pp = it * 16 + ppb;
    float t0 = T[cx * 4][pp], t1 = T[cx * 4 + 1][pp], t2 = T[cx * 4 + 2][pp], t3 = T[cx * 4 + 3][pp];
    ushort4 o; o.x = f2bf(t0); o.y = f2bf(t1); o.z = f2bf(t2); o.w = f2bf(t3);
    *(ushort4*)&fgT[(size_t)(b * L + p0 + pp) * C_IN + c0 + cx * 4] = o;
    float s = t0 + t1 + t2 + t3;
    #pragma unroll
    for (int off = 8; off; off >>= 1) s += __shfl_xor(s, off, 16);
    if (cx == 0) psum[(size_t)(cb * 3 + 0) * NP + b * L + p0 + pp] = s;
  }
  __syncthreads();

  // ---- pass 2: bg * (1-mask) ----
  float4 mv = *(const float4*)(mask + p0 + px);
  mv.x = 1.f - mv.x; mv.y = 1.f - mv.y; mv.z = 1.f - mv.z; mv.w = 1.f - mv.w;
  #pragma unroll
  for (int it = 0; it < 4; it++){
    int cc = it * 16 + rr;
    float4 v = *(const float4*)(G + (size_t)cc * L + px);
    v.x *= mv.x; v.y *= mv.y; v.z *= mv.z; v.w *= mv.w;
    T[cc][px] = v.x; T[cc][px + 1] = v.y; T[cc][px + 2] = v.z; T[cc][px + 3] = v.w;
    ushort4 o; o.x = f2bf(v.x); o.y = f2bf(v.y); o.z = f2bf(v.z); o.w = f2bf(v.w);
    *(ushort4*)&mbgS[((size_t)b * C_IN + c0 + cc) * L + p0 + px] = o;
  }
  __syncthreads();
  #pragma unroll
  for (int it = 0; it < 4; it++){
    int pp = it * 16 + ppb;
    float t0 = T[cx * 4][pp], t1 = T[cx * 4 + 1][pp], t2 = T[cx * 4 + 2][pp], t3 = T[cx * 4 + 3][pp];
    ushort4 o; o.x = f2bf(t0); o.y = f2bf(t1); o.z = f2bf(t2); o.w = f2bf(t3);
    *(ushort4*)&mbgT[(size_t)(b * L + p0 + pp) * C_IN + c0 + cx * 4] = o;
    float s1 = t0 + t1 + t2 + t3;
    float s2 = t0 * t0 + t1 * t1 + t2 * t2 + t3 * t3;
    #pragma unroll
    for (int off = 8; off; off >>= 1){
      s1 += __shfl_xor(s1, off, 16);
      s2 += __shfl_xor(s2, off, 16);
    }
    if (cx == 0){
      psum[(size_t)(cb * 3 + 1) * NP + b * L + p0 + pp] = s1;
      psum[(size_t)(cb * 3 + 2) * NP + b * L + p0 + pp] = s2;
    }
  }
}

// ---------------- D2: gemm_d (blocks 0..2047) + rn/eps (blocks 2048..2079) ------
__global__ __launch_bounds__(256) void gemm_d_rn(const unsigned short* __restrict__ fgT,
                                                 const unsigned short* __restrict__ mbgT,
                                                 unsigned short* __restrict__ D,
                                                 const float* __restrict__ psum,
                                                 float* __restrict__ rn,
                                                 float* __restrict__ eps){
  __shared__ unsigned short As[64][256];   // 32 KB
  __shared__ unsigned short Bs[64][256];   // 32 KB
  int bid = blockIdx.x;
  if (bid >= 2048){
    int idx = (bid - 2048) * 256 + threadIdx.x;  // 8192
    int b = idx >> 10, l = idx & 1023;
    int ly = l >> 5, lx = l & 31;
    const int NP = BATCH * L;
    float n2 = 2.304e-11f;                       // 2304 * 1e-14
    #pragma unroll
    for (int s = 0; s < 9; s++){
      int y = ly + s / 3 - 1, x = lx + s % 3 - 1;
      if ((unsigned)y < HW && (unsigned)x < HW){
        int q = b * L + y * HW + x;
        float s1 = 0.f, s2 = 0.f;
        #pragma unroll
        for (int k = 0; k < 4; k++){
          s1 += psum[(size_t)(k * 3 + 1) * NP + q];
          s2 += psum[(size_t)(k * 3 + 2) * NP + q];
        }
        n2 += s2 + 2e-7f * s1;
      }
    }
    rn[idx] = 1.f / sqrtf(n2);
    float ev = 0.f;
    const int tw[5] = {1, 2, 3, 2, 1};
    #pragma unroll
    for (int oy = -2; oy <= 2; oy++)
      #pragma unroll
      for (int ox = -2; ox <= 2; ox++){
        int y = ly + oy, x = lx + ox;
        if ((unsigned)y < HW && (unsigned)x < HW){
          int q = b * L + y * HW + x;
          float s0 = 0.f;
          #pragma unroll
          for (int k = 0; k < 4; k++) s0 += psum[(size_t)(k * 3 + 0) * NP + q];
          ev += (float)(tw[oy + 2] * tw[ox + 2]) * s0;
        }
      }
    eps[idx] = 1e-7f * ev;
    return;
  }
  int b = bid & 7, r = bid >> 3;       // XCD-affine
  int by = r >> 4, bx = r & 15;
  const unsigned short* Ab = fgT  + ((size_t)b * L + by * 64) * C_IN;
  const unsigned short* Bb = mbgT + ((size_t)b * L + bx * 64) * C_IN;
  int tid = threadIdx.x, lane = tid & 63, wv = tid >> 6;
  int row_off = lane >> 5, slot = lane & 31;
  int q = slot >> 3, sl = slot & 7;
  #pragma unroll
  for (int i = 0; i < 8; i++){
    int rr = wv * 16 + i * 2 + row_off;
    int srcs = q * 8 + (sl ^ (rr & 7));
    GLDS16(Ab + (size_t)rr * C_IN + srcs * 8, &As[wv * 16 + i * 2][0]);
    GLDS16(Bb + (size_t)rr * C_IN + srcs * 8, &Bs[wv * 16 + i * 2][0]);
  }
  __syncthreads();
  int wm = (wv & 1) * 32, wn = (wv >> 1) * 32;
  int rsel = lane & 15, sx = lane >> 4;
  f32x4 acc[2][2] = {};
  #pragma unroll
  for (int st = 0; st < 8; st++){
    int gs = st * 4 + sx, qq = gs >> 3, ss = gs & 7;
    short8 af[2], bf[2];
    #pragma unroll
    for (int i = 0; i < 2; i++){
      int ra = wm + i * 16 + rsel;
      af[i] = *(const short8*)&As[ra][(qq * 8 + (ss ^ (ra & 7))) * 8];
      int rb = wn + i * 16 + rsel;
      bf[i] = *(const short8*)&Bs[rb][(qq * 8 + (ss ^ (rb & 7))) * 8];
    }
    #pragma unroll
    for (int i = 0; i < 2; i++)
      #pragma unroll
      for (int j = 0; j < 2; j++)
        acc[i][j] = __builtin_amdgcn_mfma_f32_16x16x32_bf16(af[i], bf[j], acc[i][j], 0, 0, 0);
  }
  unsigned short* Db = D + ((size_t)b << 20);
  int rowb = (lane >> 4) * 4, col = lane & 15;
  #pragma unroll
  for (int i = 0; i < 2; i++)
    #pragma unroll
    for (int j = 0; j < 2; j++)
      #pragma unroll
      for (int r2 = 0; r2 < 4; r2++)
        Db[(size_t)(by * 64 + wm + i * 16 + rowb + r2) * L + bx * 64 + wn + j * 16 + col] = f2bf(acc[i][j][r2]);
}

// ---------------- S2: W = 3x3 box of D, 2 q-rows/block, ushort8 I/O -------------
__global__ __launch_bounds__(256) void box3(const unsigned short* __restrict__ D,
                                            unsigned short* __restrict__ W){
  int bid = blockIdx.x;                // 4624 = 8 * 578: b = bid&7
  int b = bid & 7;
  int q2 = (bid >> 3) * 2 + (threadIdx.x >> 7);   // 0..1155
  int v0 = (threadIdx.x & 127) * 8;
  int qy = q2 / 34 - 1, qx = q2 % 34 - 1;
  const unsigned short* Db = D + ((size_t)b << 20);
  float a[8] = {0.f, 0.f, 0.f, 0.f, 0.f, 0.f, 0.f, 0.f};
  #pragma unroll
  for (int dy = -1; dy <= 1; dy++)
    #pragma unroll
    for (int dx = -1; dx <= 1; dx++){
      int y = qy + dy, x = qx + dx;
      if ((unsigned)y < HW && (unsigned)x < HW){
        uint4v v = *(const uint4v*)(Db + ((size_t)(y * HW + x) << 10) + v0);
        #pragma unroll
        for (int j = 0; j < 4; j++){
          a[j * 2]     += __uint_as_float(v[j] << 16);
          a[j * 2 + 1] += __uint_as_float(v[j] & 0xffff0000u);
        }
      }
    }
  uint4v o;
  #pragma unroll
  for (int j = 0; j < 4; j++)
    o[j] = (unsigned)f2bf(a[j * 2]) | ((unsigned)f2bf(a[j * 2 + 1]) << 16);
  *(uint4v*)(W + ((size_t)(b * NQ + q2) << 10) + v0) = o;
}

// ------- vector tap read: 4 bf16 at idx..idx+3 from a 1024-elem LDS row ---------
static __device__ __forceinline__ void tap4(const unsigned* __restrict__ row32,
                                            int idx, int sh,
                                            unsigned &o0, unsigned &o1){
  int a0 = idx & ~3;
  const uint2* row = (const uint2*)row32;
  uint2 q0 = row[a0 >> 2];
  uint2 q1 = row[((a0 + 4) & 1023) >> 2];
  if (sh == 0){ o0 = q0.x; o1 = q0.y; }
  else if (sh == 1){ o0 = (q0.x >> 16) | (q0.y << 16); o1 = (q0.y >> 16) | (q1.x << 16); }
  else if (sh == 2){ o0 = q0.y; o1 = q1.x; }
  else { o0 = (q0.y >> 16) | (q1.x << 16); o1 = (q1.x >> 16) | (q1.y << 16); }
}

// ---------------- S3: 2x2 p-tile: diag 9-tap + softmax -> AR --------------------
__global__ __launch_bounds__(256) void prop_softmax_diag(const unsigned short* __restrict__ W,
                                                         const float* __restrict__ eps,
                                                         const float* __restrict__ rn,
                                                         unsigned short* __restrict__ AR){
  __shared__ __align__(16) unsigned short Wl[16][1024];   // 32 KB
  __shared__ float redm[4][4], reds[4][4];
  int bid = blockIdx.x;                // 2048: b = bid&7
  int b = bid & 7, tile = bid >> 3;    // 256 tiles of 2x2
  int py0 = (tile >> 4) * 2, px0 = (tile & 15) * 2;
  const unsigned short* Wb = W + (size_t)b * NQ * L;
  int tid = threadIdx.x, lane = tid & 63, wv = tid >> 6;
  #pragma unroll
  for (int k = 0; k < 8; k++){
    int u = k * 4 + wv;                // 0..31 half-row units
    int rr = u >> 1, half = u & 1;
    int qs = (py0 + (rr >> 2)) * 34 + (px0 + (rr & 3));
    GLDS16(Wb + (((size_t)qs) << 10) + half * 512 + lane * 8, &Wl[rr][half * 512]);
  }
  int l0 = tid * 4;
  int ly = l0 >> 5, lx0 = l0 & 31;
  float4 rnl = *(const float4*)&rn[b * L + l0];
  float ev[4];
  #pragma unroll
  for (int o = 0; o < 4; o++)
    ev[o] = eps[b * L + (py0 + (o >> 1)) * HW + (px0 + (o & 1))];
  __syncthreads();
  float val[4][4];
  #pragma unroll
  for (int o = 0; o < 4; o++){
    int oy = o >> 1, ox = o & 1;
    float a[4] = {0.f, 0.f, 0.f, 0.f};
    #pragma unroll
    for (int s = 0; s < 9; s++){
      const int dy = s / 3 - 1, dx = s % 3 - 1;
      const int dlt = dy * 32 + dx;
      const int sh = dlt & 3;
      bool rok = (unsigned)(ly + dy) < HW;
      int idx = (l0 + dlt) & 1023;
      unsigned o0, o1;
      tap4((const unsigned*)&Wl[(oy + dy + 1) * 4 + (ox + dx + 1)][0], idx, sh, o0, o1);
      float f0 = __uint_as_float(o0 << 16), f1 = __uint_as_float(o0 & 0xffff0000u);
      float f2 = __uint_as_float(o1 << 16), f3 = __uint_as_float(o1 & 0xffff0000u);
      a[0] += (rok && (unsigned)(lx0 + 0 + dx) < HW) ? f0 : 0.f;
      a[1] += (rok && (unsigned)(lx0 + 1 + dx) < HW) ? f1 : 0.f;
      a[2] += (rok && (unsigned)(lx0 + 2 + dx) < HW) ? f2 : 0.f;
      a[3] += (rok && (unsigned)(lx0 + 3 + dx) < HW) ? f3 : 0.f;
    }
    val[o][0] = rnl.x * (a[0] + ev[o]); val[o][1] = rnl.y * (a[1] + ev[o]);
    val[o][2] = rnl.z * (a[2] + ev[o]); val[o][3] = rnl.w * (a[3] + ev[o]);
  }
  #pragma unroll
  for (int o = 0; o < 4; o++){
    float m = fmaxf(fmaxf(val[o][0], val[o][1]), fmaxf(val[o][2], val[o][3]));
    #pragma unroll
    for (int off = 32; off; off >>= 1) m = fmaxf(m, __shfl_xor(m, off));
    if (lane == 0) redm[wv][o] = m;
  }
  __syncthreads();
  float mf[4];
  #pragma unroll
  for (int o = 0; o < 4; o++)
    mf[o] = fmaxf(fmaxf(redm[0][o], redm[1][o]), fmaxf(redm[2][o], redm[3][o]));
  float e[4][4];
  #pragma unroll
  for (int o = 0; o < 4; o++){
    float t = 0.f;
    #pragma unroll
    for (int j = 0; j < 4; j++){ e[o][j] = __expf(val[o][j] - mf[o]); t += e[o][j]; }
    #pragma unroll
    for (int off = 32; off; off >>= 1) t += __shfl_xor(t, off);
    if (lane == 0) reds[wv][o] = t;
  }
  __syncthreads();
  #pragma unroll
  for (int o = 0; o < 4; o++){
    float inv = 1.f / (reds[0][o] + reds[1][o] + reds[2][o] + reds[3][o]);
    int p = (py0 + (o >> 1)) * HW + (px0 + (o & 1));
    unsigned short* O = AR + ((size_t)b << 20) + ((size_t)p << 10);
    ushort4 ov;
    ov.x = f2bf(e[o][0] * inv * rnl.x); ov.y = f2bf(e[o][1] * inv * rnl.y);
    ov.z = f2bf(e[o][2] * inv * rnl.z); ov.w = f2bf(e[o][3] * inv * rnl.w);
    *(ushort4*)&O[l0] = ov;
  }
}

// ---------------- S4: 2x2 p-tile: U[p][v] = sum_s gated AR[p+ds][v+ds] ----------
__global__ __launch_bounds__(256) void u_stencil(const unsigned short* __restrict__ AR,
                                                 unsigned short* __restrict__ U){
  __shared__ __align__(16) unsigned short Al[16][1024];   // 32 KB
  int bid = blockIdx.x;                // 2048: b = bid&7
  int b = bid & 7, tile = bid >> 3;
  int py0 = (tile >> 4) * 2, px0 = (tile & 15) * 2;
  int tid = threadIdx.x, lane = tid & 63, wv = tid >> 6;
  const unsigned short* A = AR + ((size_t)b << 20);
  #pragma unroll
  for (int k = 0; k < 8; k++){
    int u = k * 4 + wv;
    int rr = u >> 1, half = u & 1;
    int yy = py0 + (rr >> 2) - 1, xx = px0 + (rr & 3) - 1;
    bool rok = ((unsigned)yy < HW) && ((unsigned)xx < HW);
    int p2 = rok ? (yy * HW + xx) : 0;
    GLDS16(A + (((size_t)p2) << 10) + half * 512 + lane * 8, &Al[rr][half * 512]);
  }
  int vmask = 0;
  #pragma unroll
  for (int rr = 0; rr < 16; rr++){
    int yy = py0 + (rr >> 2) - 1, xx = px0 + (rr & 3) - 1;
    if (((unsigned)yy < HW) && ((unsigned)xx < HW)) vmask |= 1 << rr;
  }
  __syncthreads();
  int v0 = tid * 4;
  int vy = v0 >> 5, vx0 = v0 & 31;
  #pragma unroll
  for (int o = 0; o < 4; o++){
    int oy = o >> 1, ox = o & 1;
    float acc[4] = {0.f, 0.f, 0.f, 0.f};
    #pragma unroll
    for (int s = 0; s < 9; s++){
      const int dy = s / 3 - 1, dx = s % 3 - 1;
      const int dlt = dy * 32 + dx;
      const int sh = dlt & 3;
      const int rr = (oy + dy + 1) * 4 + (ox + dx + 1);
      bool rok = ((vmask >> rr) & 1) && ((unsigned)(vy + dy) < HW);
      int idx = (v0 + dlt) & 1023;
      unsigned o0, o1;
      tap4((const unsigned*)&Al[rr][0], idx, sh, o0, o1);
      float f0 = __uint_as_float(o0 << 16), f1 = __uint_as_float(o0 & 0xffff0000u);
      float f2 = __uint_as_float(o1 << 16), f3 = __uint_as_float(o1 & 0xffff0000u);
      acc[0] += (rok && (unsigned)(vx0 + 0 + dx) < HW) ? f0 : 0.f;
      acc[1] += (rok && (unsigned)(vx0 + 1 + dx) < HW) ? f1 : 0.f;
      acc[2] += (rok && (unsigned)(vx0 + 2 + dx) < HW) ? f2 : 0.f;
      acc[3] += (rok && (unsigned)(vx0 + 3 + dx) < HW) ? f3 : 0.f;
    }
    int p = (py0 + oy) * HW + (px0 + ox);
    unsigned short* O = U + ((size_t)b << 20) + ((size_t)p << 10);
    ushort4 ov;
    ov.x = f2bf(acc[0]); ov.y = f2bf(acc[1]); ov.z = f2bf(acc[2]); ov.w = f2bf(acc[3]);
    *(ushort4*)&O[v0] = ov;
  }
}

// ---------------- G2: finalT[p][c] = mask? (U.mbgS)/9 : fgT  (64-row tiles) -----
__global__ __launch_bounds__(256) void gemm3_final(const unsigned short* __restrict__ U,
                                                   const unsigned short* __restrict__ mbgS,
                                                   const float* __restrict__ mask,
                                                   const unsigned short* __restrict__ fgT,
                                                   unsigned short* __restrict__ finalT){
  __shared__ unsigned short As[2][64][64];
  __shared__ unsigned short Bs[2][64][64];
  int bid = blockIdx.x;                // 512: b = bid&7
  int b = bid & 7, r = bid >> 3;       // r in [0,64)
  int mt = r >> 2, ct = r & 3;
  int tid = threadIdx.x, lane = tid & 63, wv = tid >> 6;
  int wm = (wv & 1) * 32, wn = (wv >> 1) * 32;
  int rsel = lane & 15;
  int srow = lane >> 3, scol = ((lane & 7) ^ srow) * 8;
  const unsigned short* Ab = U    + ((size_t)b * L + mt * 64) * L;
  const unsigned short* Bb = mbgS + ((size_t)b * C_IN + ct * 64) * L;
  #pragma unroll
  for (int g8 = 0; g8 < 2; g8++){
    GLDS16(Ab + (size_t)(wv * 16 + g8 * 8 + srow) * L + scol, &As[0][wv * 16 + g8 * 8][0]);
    GLDS16(Bb + (size_t)(wv * 16 + g8 * 8 + srow) * L + scol, &Bs[0][wv * 16 + g8 * 8][0]);
  }
  __syncthreads();
  f32x4 acc[2][2] = {};
  int cur = 0;
  for (int t = 0; t < 16; ++t){
    short8 af[2][2], bf[2][2];
    #pragma unroll
    for (int kk = 0; kk < 2; kk++){
      int s0 = kk * 4 + (lane >> 4);
      int col = ((s0 ^ (rsel & 7)) << 3);
      #pragma unroll
      for (int i = 0; i < 2; i++){
        af[kk][i] = *(const short8*)&As[cur][wm + i * 16 + rsel][col];
        bf[kk][i] = *(const short8*)&Bs[cur][wn + i * 16 + rsel][col];
      }
    }
    if (t + 1 < 16){
      int nb = cur ^ 1;
      size_t kt = (size_t)(t + 1) * 64;
      #pragma unroll
      for (int g8 = 0; g8 < 2; g8++){
        GLDS16(Ab + (size_t)(wv * 16 + g8 * 8 + srow) * L + kt + scol, &As[nb][wv * 16 + g8 * 8][0]);
        GLDS16(Bb + (size_t)(wv * 16 + g8 * 8 + srow) * L + kt + scol, &Bs[nb][wv * 16 + g8 * 8][0]);
      }
    }
    #pragma unroll
    for (int kk = 0; kk < 2; kk++)
      #pragma unroll
      for (int i = 0; i < 2; i++)
        #pragma unroll
        for (int j = 0; j < 2; j++)
          acc[i][j] = __builtin_amdgcn_mfma_f32_16x16x32_bf16(af[kk][i], bf[kk][j], acc[i][j], 0, 0, 0);
    __syncthreads();
    cur ^= 1;
  }
  int rowb = (lane >> 4) * 4, col = lane & 15;
  #pragma unroll
  for (int i = 0; i < 2; i++)
    #pragma unroll
    for (int j = 0; j < 2; j++)
      #pragma unroll
      for (int r2 = 0; r2 < 4; r2++){
        int p = mt * 64 + wm + i * 16 + rowb + r2;
        int c = ct * 64 + wn + j * 16 + col;
        unsigned short o;
        if (mask[p] != 0.f) o = f2bf(acc[i][j][r2] * (1.f / 9.f));
        else                o = fgT[((size_t)b * L + p) * C_IN + c];
        finalT[((size_t)b * L + p) * C_IN + c] = o;
      }
}

// ---------------- K4: branch convs as shifted GEMM (64-row tiles) ---------------
__global__ __launch_bounds__(256) void branch_gemm(const unsigned short* __restrict__ finalT,
                                                   const unsigned short* __restrict__ Wr,
                                                   const float* __restrict__ conv_b,
                                                   const unsigned short* __restrict__ zpage,
                                                   float* __restrict__ out){
  __shared__ unsigned short As[2][64][64];
  __shared__ unsigned short Bs[2][64][64];
  int nwg = gridDim.x, bid = blockIdx.x;     // 512
  int nid = (bid & 7) * (nwg >> 3) + (bid >> 3);   // XCD-affine
  int bg = nid >> 4, pt = nid & 15;
  int b = bg >> 2, g = bg & 3;
  int rate = 1 << g;
  int p0 = pt * 64;
  int tid = threadIdx.x, lane = tid & 63, wv = tid >> 6;
  int wm = (wv & 1) * 32, wn = (wv >> 1) * 32;
  int rsel = lane & 15;
  int srow = lane >> 3;
  int scol = ((lane & 7) ^ srow) * 8;
  const unsigned short* FT = finalT + (size_t)b * L * C_IN;
  const unsigned short* WG = Wr + (size_t)(g * 9) * 64 * C_IN;

  int ay[2], ax[2];
  #pragma unroll
  for (int g8 = 0; g8 < 2; g8++){
    int p = p0 + wv * 16 + g8 * 8 + srow;
    ay[g8] = p >> 5; ax[g8] = p & 31;
  }
  auto a_src = [&](int t, int g8) -> const unsigned short* {
    int s = t >> 2, q = t & 3;
    int dy = s / 3 - 1, dx = s - (s / 3) * 3 - 1;
    int iy = ay[g8] + rate * dy, ix = ax[g8] + rate * dx;
    if ((unsigned)iy < HW && (unsigned)ix < HW)
      return FT + (size_t)(iy * HW + ix) * C_IN + q * 64 + scol;
    return zpage;
  };
  auto b_src = [&](int t, int g8) -> const unsigned short* {
    int s = t >> 2, q = t & 3;
    int n = wv * 16 + g8 * 8 + srow;
    return WG + (size_t)(s * 64 + n) * C_IN + q * 64 + scol;
  };

  f32x4 acc[2][2] = {};
  #pragma unroll
  for (int g8 = 0; g8 < 2; g8++){
    GLDS16(a_src(0, g8), &As[0][wv * 16 + g8 * 8][0]);
    GLDS16(b_src(0, g8), &Bs[0][wv * 16 + g8 * 8][0]);
  }
  __syncthreads();
  int cur = 0;
  for (int t = 0; t < 36; ++t){
    short8 af[2][2], bf[2][2];
    #pragma unroll
    for (int kk = 0; kk < 2; kk++){
      int s0 = kk * 4 + (lane >> 4);
      int col = ((s0 ^ (rsel & 7)) << 3);
      #pragma unroll
      for (int i = 0; i < 2; i++){
        af[kk][i] = *(const short8*)&As[cur][wm + i * 16 + rsel][col];
        bf[kk][i] = *(const short8*)&Bs[cur][wn + i * 16 + rsel][col];
      }
    }
    if (t + 1 < 36){
      int nb = cur ^ 1;
      #pragma unroll
      for (int g8 = 0; g8 < 2; g8++){
        GLDS16(a_src(t + 1, g8), &As[nb][wv * 16 + g8 * 8][0]);
        GLDS16(b_src(t + 1, g8), &Bs[nb][wv * 16 + g8 * 8][0]);
      }
    }
    #pragma unroll
    for (int kk = 0; kk < 2; kk++)
      #pragma unroll
      for (int i = 0; i < 2; i++)
        #pragma unroll
        for (int j = 0; j < 2; j++)
          acc[i][j] = __builtin_amdgcn_mfma_f32_16x16x32_bf16(af[kk][i], bf[kk][j], acc[i][j], 0, 0, 0);
    __syncthreads();
    cur ^= 1;
  }
  int rowb = (lane >> 4) * 4, col = lane & 15;
  float* O = out + (size_t)(b * 256 + g * 64) * L;
  #pragma unroll
  for (int i = 0; i < 2; i++)
    #pragma unroll
    for (int j = 0; j < 2; j++){
      int n = wn + j * 16 + col;
      float bias = conv_b[g * 64 + n];
      #pragma unroll
      for (int r2 = 0; r2 < 4; r2++){
        int p = p0 + wm + i * 16 + rowb + r2;
        O[(size_t)n * L + p] = fmaxf(acc[i][j][r2] + bias, 0.f);
      }
    }
}

// ---------------- workspace layout (bytes) --------------------------------------
// [0,        16777216) : D    (8*1024*1024 bf16)
// [16777216, 35717120) : W    (8*1156*1024 bf16)
// [35717120, 52494336) : AR   (8*1024*1024 bf16)
// [52494336, 69271552) : U    (8*1024*1024 bf16)
// [69271552, 73465856) : mbgT (8*1024*256 bf16)
// [73465856, 77660160) : mbgS (8*256*1024 bf16)
// [77660160, 81854464) : finalT (8*1024*256 bf16)
// [81854464, 83034112) : Wr   (4*9*64*256 bf16)
// [83034112, 83427328) : psum (4*3*8192 f32, written unconditionally — no init)
// [83427328, 83460096) : rn   (8*1024 f32)
// [83460096, 83492864) : eps  (8*1024 f32)
// [83492864, 83493376) : zpage (512 B)
// fgT lives in d_out[0 .. 4.2MB) (d_out only written by branch_gemm at the end)

extern "C" void kernel_launch(void* const* d_in, const int* in_sizes, int n_in,
                              void* d_out, int out_size, void* d_ws, size_t ws_size,
                              hipStream_t stream){
  const float* fg     = (const float*)d_in[0];
  const float* mask   = (const float*)d_in[1];
  const float* bgd    = (const float*)d_in[2];
  const float* conv_w = (const float*)d_in[3];
  const float* conv_b = (const float*)d_in[4];

  char* ws = (char*)d_ws;
  unsigned short* D      = (unsigned short*)(ws + 0);
  unsigned short* W      = (unsigned short*)(ws + 16777216);
  unsigned short* AR     = (unsigned short*)(ws + 35717120);
  unsigned short* U      = (unsigned short*)(ws + 52494336);
  unsigned short* mbgT   = (unsigned short*)(ws + 69271552);
  unsigned short* mbgS   = (unsigned short*)(ws + 73465856);
  unsigned short* finalT = (unsigned short*)(ws + 77660160);
  unsigned short* Wr     = (unsigned short*)(ws + 81854464);
  float*          psum   = (float*)(ws + 83034112);
  float*          rn     = (float*)(ws + 83427328);
  float*          eps    = (float*)(ws + 83460096);
  unsigned short* zpage  = (unsigned short*)(ws + 83492864);
  unsigned short* fgT    = (unsigned short*)d_out;
  float* out = (float*)d_out;

  fused_prep<<<2816, 256, 0, stream>>>(fg, bgd, mask, fgT, mbgT, mbgS, psum,
                                       conv_w, Wr, zpage);
  gemm_d_rn<<<2080, 256, 0, stream>>>(fgT, mbgT, D, psum, rn, eps);
  box3<<<4624, 256, 0, stream>>>(D, W);
  prop_softmax_diag<<<2048, 256, 0, stream>>>(W, eps, rn, AR);
  u_stencil<<<2048, 256, 0, stream>>>(AR, U);
  gemm3_final<<<512, 256, 0, stream>>>(U, mbgS, mask, fgT, finalT);
  branch_gemm<<<512, 256, 0, stream>>>(finalT, Wr, conv_b, zpage, out);
}